// Round 1
// baseline (521.267 us; speedup 1.0000x reference)
//
#include <hip/hip_runtime.h>

// GNN_79937931313503: dynamic-graph SAGE GNN on MI355X.
// N=8192 nodes, D_IN=128, H=256, out 1. All inputs fp32; internal bf16 MFMA.
//
// Pipeline:
//  prep_x: row norms -> xn (bf16 normalized), xb (bf16 raw)
//  prep_w: transpose+convert weight matrices to bf16 [N][K] ("BT") layout
//  sim<0>: Xn@XnT MFMA, |.|, 1024-bin histogram of fp32-bit prefix (bits>>20)
//  scan<1024,0>: find prefix bin + rank within
//  sim<1>: refine histogram (bits>>7)&8191 within prefix bin
//  scan<8192,1>: reconstruct eps bits (26-bit prefix, <=128ulp low)
//  sim<2>: A-bitmask build via __ballot (8192x8192 bits = 8MB)
//  deg: popcount rows -> 1/deg
//  lin: h0 = relu(xb@w_in + b)
//  [transpose h -> hT; aggA: (A@h)*deg_inv via bit->bf16 LDS expansion MFMA;
//   lin: h_next = relu(agg@wl + h@wr + b [+res])] x2
//  vec3: u=h2@o1_wl, v=h2@o1_wr, sc=h2@osc_w+osc_b
//  aggv1: o1 = relu((A@u)/deg + o1_bl + v)
//  aggv2: out = sigmoid((A@o1)/deg*o2_wl + o2_bl + o1*o2_wr + sc)

typedef __attribute__((ext_vector_type(8))) short s8v;   // 8 x bf16 (4 VGPR)
typedef __attribute__((ext_vector_type(4))) float f4v;   // MFMA C/D frag

__device__ __forceinline__ f4v MFMA(s8v a, s8v b, f4v c) {
  return __builtin_amdgcn_mfma_f32_16x16x32_bf16(a, b, c, 0, 0, 0);
}
__device__ __forceinline__ short f2bf(float f) {  // RNE float->bf16 bits
  unsigned u = __float_as_uint(f);
  return (short)((u + 0x7FFFu + ((u >> 16) & 1u)) >> 16);
}
__device__ __forceinline__ float bf2f(short s) {
  return __uint_as_float(((unsigned)(unsigned short)s) << 16);
}

// ---------------- prep ----------------
__global__ __launch_bounds__(256) void prep_x_kernel(const float* __restrict__ x,
                                                     short* __restrict__ xb,
                                                     short* __restrict__ xn) {
  int row = blockIdx.x * 4 + (threadIdx.x >> 6);
  int lane = threadIdx.x & 63;
  float v0 = x[row * 128 + lane];
  float v1 = x[row * 128 + 64 + lane];
  float ss = v0 * v0 + v1 * v1;
  for (int o = 1; o < 64; o <<= 1) ss += __shfl_xor(ss, o);
  float inv = 1.0f / fmaxf(sqrtf(ss), 1e-8f);
  xb[row * 128 + lane] = f2bf(v0);
  xb[row * 128 + 64 + lane] = f2bf(v1);
  xn[row * 128 + lane] = f2bf(v0 * inv);
  xn[row * 128 + 64 + lane] = f2bf(v1 * inv);
}

__global__ __launch_bounds__(256) void prep_w_kernel(
    const float* __restrict__ w_in, const float* __restrict__ w1l,
    const float* __restrict__ w1r, const float* __restrict__ w2l,
    const float* __restrict__ w2r, short* __restrict__ w_inT,
    short* __restrict__ w1lT, short* __restrict__ w1rT,
    short* __restrict__ w2lT, short* __restrict__ w2rT) {
  int idx = blockIdx.x * 256 + threadIdx.x;
  if (idx >= 294912) return;
  if (idx < 32768) {                       // w_in [128][256] -> [256][128]
    int n = idx >> 7, k = idx & 127;
    w_inT[idx] = f2bf(w_in[k * 256 + n]);
  } else {                                 // 4x [256][256] transposed
    int j = idx - 32768;
    int m = j >> 16, r = j & 65535;
    int n = r >> 8, k = r & 255;
    const float* src = (m == 0) ? w1l : (m == 1) ? w1r : (m == 2) ? w2l : w2r;
    short* dst = (m == 0) ? w1lT : (m == 1) ? w1rT : (m == 2) ? w2lT : w2rT;
    dst[r] = f2bf(src[k * 256 + n]);
  }
}

// ---------------- sim: Xn @ XnT, 128x128 tile, 4 waves of 64x64 ----------------
// MODE 0: coarse histogram (bits>>20, 1024 bins)
// MODE 1: refine histogram within prefix ((bits>>7)&8191)
// MODE 2: build adjacency bitmask via ballot
template <int MODE>
__global__ __launch_bounds__(256) void sim_kernel(
    const short* __restrict__ xn, unsigned int* __restrict__ hist,
    unsigned int* __restrict__ sel, unsigned long long* __restrict__ Awords) {
  __shared__ __align__(16) short As[128][72];
  __shared__ __align__(16) short Bs[128][72];
  __shared__ unsigned int lh[1024];
  const int tid = threadIdx.x;
  const int j0 = blockIdx.x * 128;
  const int i0 = blockIdx.y * 128;
  if (MODE == 0)
    for (int b = tid; b < 1024; b += 256) lh[b] = 0;

  const int w = tid >> 6, lane = tid & 63;
  const int wy = (w >> 1) * 64, wx = (w & 1) * 64;
  const int lr = lane & 15, lk = (lane >> 4) * 8;
  f4v acc[4][4];
#pragma unroll
  for (int a = 0; a < 4; ++a)
#pragma unroll
    for (int b = 0; b < 4; ++b) acc[a][b] = (f4v){0.f, 0.f, 0.f, 0.f};

  for (int kb = 0; kb < 128; kb += 64) {
    __syncthreads();
#pragma unroll
    for (int u = 0; u < 4; ++u) {  // 128 rows x 64k: 1024 units of 8 elems
      int unit = tid + u * 256;
      int r = unit >> 3, sg = (unit & 7) * 8;
      *(s8v*)&As[r][sg] = *(const s8v*)(xn + (i0 + r) * 128 + kb + sg);
      *(s8v*)&Bs[r][sg] = *(const s8v*)(xn + (j0 + r) * 128 + kb + sg);
    }
    __syncthreads();
#pragma unroll
    for (int kc = 0; kc < 2; ++kc) {
      s8v af[4], bf[4];
#pragma unroll
      for (int mt = 0; mt < 4; ++mt) af[mt] = *(const s8v*)&As[wy + mt * 16 + lr][kc * 32 + lk];
#pragma unroll
      for (int nt = 0; nt < 4; ++nt) bf[nt] = *(const s8v*)&Bs[wx + nt * 16 + lr][kc * 32 + lk];
#pragma unroll
      for (int mt = 0; mt < 4; ++mt)
#pragma unroll
        for (int nt = 0; nt < 4; ++nt) acc[mt][nt] = MFMA(af[mt], bf[nt], acc[mt][nt]);
    }
  }

  if (MODE == 0) {
#pragma unroll
    for (int mt = 0; mt < 4; ++mt)
      for (int nt = 0; nt < 4; ++nt)
        for (int r = 0; r < 4; ++r) {
          unsigned bits = __float_as_uint(fabsf(acc[mt][nt][r]));
          unsigned bin = bits >> 20;
          if (bin > 1023u) bin = 1023u;
          atomicAdd(&lh[bin], 1u);
        }
    __syncthreads();
    for (int b = tid; b < 1024; b += 256)
      if (lh[b]) atomicAdd(&hist[b], lh[b]);
  } else if (MODE == 1) {
    unsigned pref = sel[0];
#pragma unroll
    for (int mt = 0; mt < 4; ++mt)
      for (int nt = 0; nt < 4; ++nt)
        for (int r = 0; r < 4; ++r) {
          unsigned bits = __float_as_uint(fabsf(acc[mt][nt][r]));
          if ((bits >> 20) == pref) atomicAdd(&hist[(bits >> 7) & 0x1FFFu], 1u);
        }
  } else {
    float eps = __uint_as_float(sel[2]);
#pragma unroll
    for (int mt = 0; mt < 4; ++mt)
#pragma unroll
      for (int r = 0; r < 4; ++r) {
        unsigned long long b0 = __ballot(fabsf(acc[mt][0][r]) >= eps);
        unsigned long long b1 = __ballot(fabsf(acc[mt][1][r]) >= eps);
        unsigned long long b2 = __ballot(fabsf(acc[mt][2][r]) >= eps);
        unsigned long long b3 = __ballot(fabsf(acc[mt][3][r]) >= eps);
        if (lane < 4) {
          int g = lane;  // row-group within the 16x16 C tiles
          unsigned long long word = ((b0 >> (16 * g)) & 0xFFFFull) |
                                    (((b1 >> (16 * g)) & 0xFFFFull) << 16) |
                                    (((b2 >> (16 * g)) & 0xFFFFull) << 32) |
                                    (((b3 >> (16 * g)) & 0xFFFFull) << 48);
          int row = i0 + wy + mt * 16 + g * 4 + r;
          Awords[row * 128 + ((j0 + wx) >> 6)] = word;
        }
      }
  }
}

// ---------------- histogram selection scan ----------------
template <int NB, int MODE>
__global__ __launch_bounds__(256) void scan_kernel(const unsigned int* __restrict__ hist,
                                                   unsigned int* __restrict__ sel) {
  __shared__ unsigned long long csum[256];
  const int t = threadIdx.x;
  const int PER = NB / 256;
  unsigned int vals[NB / 256];
  unsigned long long s = 0;
  for (int i = 0; i < PER; ++i) {
    vals[i] = hist[t * PER + i];
    s += vals[i];
  }
  csum[t] = s;
  __syncthreads();
  for (int o = 1; o < 256; o <<= 1) {
    unsigned long long prev = (t >= o) ? csum[t - o] : 0ull;
    __syncthreads();
    csum[t] += prev;
    __syncthreads();
  }
  // target rank (1-indexed): round(0.95*(8192^2-1)) + 1 = 63753421
  unsigned long long K = (MODE == 0) ? 63753421ull : (unsigned long long)sel[1];
  unsigned long long inc = csum[t], exc = inc - s;
  if (K > exc && K <= inc) {
    unsigned long long c = exc;
    for (int i = 0; i < PER; ++i) {
      c += vals[i];
      if (c >= K) {
        if (MODE == 0) {
          sel[0] = (unsigned)(t * PER + i);
          sel[1] = (unsigned)(K - (c - vals[i]));
        } else {
          sel[2] = (sel[0] << 20) | ((unsigned)(t * PER + i) << 7);
        }
        break;
      }
    }
  }
}

// ---------------- degree ----------------
__global__ __launch_bounds__(256) void deg_kernel(const unsigned long long* __restrict__ Awords,
                                                  float* __restrict__ deg_inv) {
  int row = blockIdx.x * 4 + (threadIdx.x >> 6);
  int lane = threadIdx.x & 63;
  int c = __popcll(Awords[row * 128 + lane]) + __popcll(Awords[row * 128 + 64 + lane]);
  for (int o = 32; o; o >>= 1) c += __shfl_down(c, o);
  if (lane == 0) deg_inv[row] = 1.0f / (float)max(c, 1);
}

// ---------------- small NT linears: out = act(A1@B1' [+A2@B2'] + bias [+res]) ----------------
template <bool TWO, bool RELU, bool RES>
__global__ __launch_bounds__(256) void lin_kernel(
    const short* __restrict__ A1, const short* __restrict__ B1, int K1,
    const short* __restrict__ A2, const short* __restrict__ B2, int K2,
    const float* __restrict__ bias, const short* __restrict__ res,
    short* __restrict__ out) {
  const int i0 = blockIdx.x * 64, n0 = blockIdx.y * 64;
  const int tid = threadIdx.x, w = tid >> 6, lane = tid & 63;
  const int wy = (w >> 1) * 32, wx = (w & 1) * 32;
  const int lr = lane & 15, lk = (lane >> 4) * 8;
  f4v acc[2][2];
#pragma unroll
  for (int a = 0; a < 2; ++a)
#pragma unroll
    for (int b = 0; b < 2; ++b) acc[a][b] = (f4v){0.f, 0.f, 0.f, 0.f};

  for (int kc = 0; kc < K1; kc += 32) {
    s8v a0 = *(const s8v*)(A1 + (i0 + wy + lr) * K1 + kc + lk);
    s8v a1 = *(const s8v*)(A1 + (i0 + wy + 16 + lr) * K1 + kc + lk);
    s8v b0 = *(const s8v*)(B1 + (n0 + wx + lr) * K1 + kc + lk);
    s8v b1 = *(const s8v*)(B1 + (n0 + wx + 16 + lr) * K1 + kc + lk);
    acc[0][0] = MFMA(a0, b0, acc[0][0]);
    acc[0][1] = MFMA(a0, b1, acc[0][1]);
    acc[1][0] = MFMA(a1, b0, acc[1][0]);
    acc[1][1] = MFMA(a1, b1, acc[1][1]);
  }
  if constexpr (TWO) {
    for (int kc = 0; kc < K2; kc += 32) {
      s8v a0 = *(const s8v*)(A2 + (i0 + wy + lr) * K2 + kc + lk);
      s8v a1 = *(const s8v*)(A2 + (i0 + wy + 16 + lr) * K2 + kc + lk);
      s8v b0 = *(const s8v*)(B2 + (n0 + wx + lr) * K2 + kc + lk);
      s8v b1 = *(const s8v*)(B2 + (n0 + wx + 16 + lr) * K2 + kc + lk);
      acc[0][0] = MFMA(a0, b0, acc[0][0]);
      acc[0][1] = MFMA(a0, b1, acc[0][1]);
      acc[1][0] = MFMA(a1, b0, acc[1][0]);
      acc[1][1] = MFMA(a1, b1, acc[1][1]);
    }
  }
#pragma unroll
  for (int mt = 0; mt < 2; ++mt)
#pragma unroll
    for (int nt = 0; nt < 2; ++nt)
#pragma unroll
      for (int r = 0; r < 4; ++r) {
        int row = i0 + wy + mt * 16 + (lane >> 4) * 4 + r;
        int col = n0 + wx + nt * 16 + (lane & 15);
        float v = acc[mt][nt][r] + bias[col];
        if constexpr (RES) v += bf2f(res[row * 256 + col]);
        if constexpr (RELU) v = fmaxf(v, 0.f);
        out[row * 256 + col] = f2bf(v);
      }
}

// ---------------- transpose [8192][256] -> [256][8192] ----------------
__global__ __launch_bounds__(256) void transpose_kernel(const short* __restrict__ in,
                                                        short* __restrict__ out) {
  __shared__ __align__(16) short T[64][72];
  const int i0 = blockIdx.x * 64, f0 = blockIdx.y * 64;
  const int t = threadIdx.x;
  const int r = t >> 2, c0 = (t & 3) * 16;
  s8v v0 = *(const s8v*)(in + (i0 + r) * 256 + f0 + c0);
  s8v v1 = *(const s8v*)(in + (i0 + r) * 256 + f0 + c0 + 8);
#pragma unroll
  for (int e = 0; e < 8; ++e) {
    T[c0 + e][r] = v0[e];
    T[c0 + 8 + e][r] = v1[e];
  }
  __syncthreads();
  s8v o0, o1;
#pragma unroll
  for (int e = 0; e < 8; ++e) {
    o0[e] = T[r][c0 + e];
    o1[e] = T[r][c0 + 8 + e];
  }
  *(s8v*)(out + (f0 + r) * 8192 + i0 + c0) = o0;
  *(s8v*)(out + (f0 + r) * 8192 + i0 + c0 + 8) = o1;
}

// ---------------- agg = (A@h)*deg_inv via bitmask->bf16 expansion ----------------
__global__ __launch_bounds__(256) void aggA_kernel(const unsigned long long* __restrict__ Awords,
                                                   const short* __restrict__ hT,
                                                   const float* __restrict__ deg_inv,
                                                   short* __restrict__ agg) {
  __shared__ __align__(16) short As[64][136];
  __shared__ __align__(16) short Bs[64][136];
  const int i0 = blockIdx.x * 64;  // node rows
  const int f0 = blockIdx.y * 64;  // features
  const int tid = threadIdx.x, w = tid >> 6, lane = tid & 63;
  const int wy = (w >> 1) * 32, wx = (w & 1) * 32;
  const int lr = lane & 15, lk = (lane >> 4) * 8;
  f4v acc[2][2];
#pragma unroll
  for (int a = 0; a < 2; ++a)
#pragma unroll
    for (int b = 0; b < 2; ++b) acc[a][b] = (f4v){0.f, 0.f, 0.f, 0.f};

  for (int kb = 0; kb < 8192; kb += 128) {
    __syncthreads();
    {  // expand 64 rows x 128 bits -> bf16 LDS
      int r = tid >> 2, k0 = (tid & 3) * 32;
      int gk = kb + k0;
      unsigned long long wordv = Awords[(i0 + r) * 128 + (gk >> 6)];
      unsigned bits32 = (unsigned)(wordv >> (gk & 63));
#pragma unroll
      for (int j = 0; j < 4; ++j) {
        s8v v;
#pragma unroll
        for (int e = 0; e < 8; ++e)
          v[e] = ((bits32 >> (j * 8 + e)) & 1u) ? (short)0x3F80 : (short)0;
        *(s8v*)&As[r][k0 + j * 8] = v;
      }
    }
#pragma unroll
    for (int u = 0; u < 4; ++u) {  // hT tile: 64 rows x 128 k
      int unit = tid + u * 256;
      int rr = unit >> 4, sg = (unit & 15) * 8;
      *(s8v*)&Bs[rr][sg] = *(const s8v*)(hT + (f0 + rr) * 8192 + kb + sg);
    }
    __syncthreads();
#pragma unroll
    for (int kc = 0; kc < 4; ++kc) {
      s8v a0 = *(const s8v*)&As[wy + lr][kc * 32 + lk];
      s8v a1 = *(const s8v*)&As[wy + 16 + lr][kc * 32 + lk];
      s8v b0 = *(const s8v*)&Bs[wx + lr][kc * 32 + lk];
      s8v b1 = *(const s8v*)&Bs[wx + 16 + lr][kc * 32 + lk];
      acc[0][0] = MFMA(a0, b0, acc[0][0]);
      acc[0][1] = MFMA(a0, b1, acc[0][1]);
      acc[1][0] = MFMA(a1, b0, acc[1][0]);
      acc[1][1] = MFMA(a1, b1, acc[1][1]);
    }
  }
#pragma unroll
  for (int mt = 0; mt < 2; ++mt)
#pragma unroll
    for (int nt = 0; nt < 2; ++nt)
#pragma unroll
      for (int r = 0; r < 4; ++r) {
        int row = i0 + wy + mt * 16 + (lane >> 4) * 4 + r;
        int col = f0 + wx + nt * 16 + (lane & 15);
        agg[row * 256 + col] = f2bf(acc[mt][nt][r] * deg_inv[row]);
      }
}

// ---------------- tail: H->1 projections and bitmask-vector aggs ----------------
__global__ __launch_bounds__(256) void vec3_kernel(const short* __restrict__ h2,
                                                   const float* __restrict__ o1wl,
                                                   const float* __restrict__ o1wr,
                                                   const float* __restrict__ oscw,
                                                   const float* __restrict__ oscb,
                                                   float* __restrict__ u, float* __restrict__ v,
                                                   float* __restrict__ sc) {
  int row = blockIdx.x * 4 + (threadIdx.x >> 6);
  int lane = threadIdx.x & 63;
  float su = 0.f, sv = 0.f, ss = 0.f;
#pragma unroll
  for (int e = 0; e < 4; ++e) {
    int k = lane * 4 + e;
    float hv = bf2f(h2[row * 256 + k]);
    su += hv * o1wl[k];
    sv += hv * o1wr[k];
    ss += hv * oscw[k];
  }
  for (int o = 1; o < 64; o <<= 1) {
    su += __shfl_xor(su, o);
    sv += __shfl_xor(sv, o);
    ss += __shfl_xor(ss, o);
  }
  if (lane == 0) {
    u[row] = su;
    v[row] = sv;
    sc[row] = ss + oscb[0];
  }
}

__global__ __launch_bounds__(256) void aggv1_kernel(const unsigned long long* __restrict__ Awords,
                                                    const float* __restrict__ u,
                                                    const float* __restrict__ deg_inv,
                                                    const float* __restrict__ v,
                                                    const float* __restrict__ o1bl,
                                                    float* __restrict__ o1) {
  int row = blockIdx.x * 4 + (threadIdx.x >> 6);
  int lane = threadIdx.x & 63;
  float s = 0.f;
#pragma unroll
  for (int wi = 0; wi < 2; ++wi) {
    unsigned long long bits = Awords[row * 128 + wi * 64 + lane];
    int base = (wi * 64 + lane) * 64;
    while (bits) {
      int b = __ffsll(bits) - 1;
      s += u[base + b];
      bits &= bits - 1;
    }
  }
  for (int o = 1; o < 64; o <<= 1) s += __shfl_xor(s, o);
  if (lane == 0) o1[row] = fmaxf(s * deg_inv[row] + o1bl[0] + v[row], 0.f);
}

__global__ __launch_bounds__(256) void aggv2_kernel(const unsigned long long* __restrict__ Awords,
                                                    const float* __restrict__ o1,
                                                    const float* __restrict__ deg_inv,
                                                    const float* __restrict__ o2wl,
                                                    const float* __restrict__ o2bl,
                                                    const float* __restrict__ o2wr,
                                                    const float* __restrict__ sc,
                                                    float* __restrict__ out) {
  int row = blockIdx.x * 4 + (threadIdx.x >> 6);
  int lane = threadIdx.x & 63;
  float s = 0.f;
#pragma unroll
  for (int wi = 0; wi < 2; ++wi) {
    unsigned long long bits = Awords[row * 128 + wi * 64 + lane];
    int base = (wi * 64 + lane) * 64;
    while (bits) {
      int b = __ffsll(bits) - 1;
      s += o1[base + b];
      bits &= bits - 1;
    }
  }
  for (int o = 1; o < 64; o <<= 1) s += __shfl_xor(s, o);
  if (lane == 0) {
    float z = s * deg_inv[row] * o2wl[0] + o2bl[0] + o1[row] * o2wr[0] + sc[row];
    out[row] = 1.f / (1.f + expf(-z));
  }
}

// ---------------- launch ----------------
extern "C" void kernel_launch(void* const* d_in, const int* in_sizes, int n_in,
                              void* d_out, int out_size, void* d_ws, size_t ws_size,
                              hipStream_t stream) {
  (void)in_sizes; (void)n_in; (void)out_size; (void)ws_size;
  const float* x     = (const float*)d_in[0];
  const float* w_in  = (const float*)d_in[1];
  const float* b_in  = (const float*)d_in[2];
  const float* h1_wl = (const float*)d_in[3];
  const float* h1_bl = (const float*)d_in[4];
  const float* h1_wr = (const float*)d_in[5];
  const float* h2_wl = (const float*)d_in[6];
  const float* h2_bl = (const float*)d_in[7];
  const float* h2_wr = (const float*)d_in[8];
  const float* o1_wl = (const float*)d_in[9];
  const float* o1_bl = (const float*)d_in[10];
  const float* o1_wr = (const float*)d_in[11];
  const float* o2_wl = (const float*)d_in[12];
  const float* o2_bl = (const float*)d_in[13];
  const float* o2_wr = (const float*)d_in[14];
  const float* osc_w = (const float*)d_in[15];
  const float* osc_b = (const float*)d_in[16];
  float* out = (float*)d_out;

  char* ws = (char*)d_ws;
  size_t off = 0;
  auto alloc = [&](size_t bytes) -> char* {
    char* p = ws + off;
    off += (bytes + 255) & ~(size_t)255;
    return p;
  };
  short* xn    = (short*)alloc(8192 * 128 * 2);
  short* xb    = (short*)alloc(8192 * 128 * 2);
  short* w_inT = (short*)alloc(256 * 128 * 2);
  short* w1lT  = (short*)alloc(256 * 256 * 2);
  short* w1rT  = (short*)alloc(256 * 256 * 2);
  short* w2lT  = (short*)alloc(256 * 256 * 2);
  short* w2rT  = (short*)alloc(256 * 256 * 2);
  unsigned int* hist1 = (unsigned int*)alloc(1024 * 4);
  unsigned int* hist2 = (unsigned int*)alloc(8192 * 4);
  unsigned int* sel   = (unsigned int*)alloc(256);
  float* deg_inv = (float*)alloc(8192 * 4);
  float* ubuf  = (float*)alloc(8192 * 4);
  float* vbuf  = (float*)alloc(8192 * 4);
  float* scbuf = (float*)alloc(8192 * 4);
  float* o1buf = (float*)alloc(8192 * 4);
  unsigned long long* Awords = (unsigned long long*)alloc((size_t)8192 * 128 * 8);
  short* h0  = (short*)alloc((size_t)8192 * 256 * 2);
  short* h1  = (short*)alloc((size_t)8192 * 256 * 2);
  short* h2  = (short*)alloc((size_t)8192 * 256 * 2);
  short* hT  = (short*)alloc((size_t)8192 * 256 * 2);
  short* agg = (short*)alloc((size_t)8192 * 256 * 2);

  hipMemsetAsync(hist1, 0, (1024 + 8192) * 4, stream);  // hist1+hist2 contiguous
  prep_x_kernel<<<2048, 256, 0, stream>>>(x, xb, xn);
  prep_w_kernel<<<1152, 256, 0, stream>>>(w_in, h1_wl, h1_wr, h2_wl, h2_wr,
                                          w_inT, w1lT, w1rT, w2lT, w2rT);
  sim_kernel<0><<<dim3(64, 64), 256, 0, stream>>>(xn, hist1, sel, nullptr);
  scan_kernel<1024, 0><<<1, 256, 0, stream>>>(hist1, sel);
  sim_kernel<1><<<dim3(64, 64), 256, 0, stream>>>(xn, hist2, sel, nullptr);
  scan_kernel<8192, 1><<<1, 256, 0, stream>>>(hist2, sel);
  sim_kernel<2><<<dim3(64, 64), 256, 0, stream>>>(xn, nullptr, sel, Awords);
  deg_kernel<<<2048, 256, 0, stream>>>(Awords, deg_inv);

  // h0 = relu(x @ w_in + b_in)
  lin_kernel<false, true, false><<<dim3(128, 4), 256, 0, stream>>>(
      xb, w_inT, 128, nullptr, nullptr, 0, b_in, nullptr, h0);
  // h1 = relu(agg(h0)@h1_wl + h1_bl + h0@h1_wr)
  transpose_kernel<<<dim3(128, 4), 256, 0, stream>>>(h0, hT);
  aggA_kernel<<<dim3(128, 4), 256, 0, stream>>>(Awords, hT, deg_inv, agg);
  lin_kernel<true, true, false><<<dim3(128, 4), 256, 0, stream>>>(
      agg, w1lT, 256, h0, w1rT, 256, h1_bl, nullptr, h1);
  // h2 = relu(agg(h1)@h2_wl + h2_bl + h1@h2_wr + h0)
  transpose_kernel<<<dim3(128, 4), 256, 0, stream>>>(h1, hT);
  aggA_kernel<<<dim3(128, 4), 256, 0, stream>>>(Awords, hT, deg_inv, agg);
  lin_kernel<true, true, true><<<dim3(128, 4), 256, 0, stream>>>(
      agg, w2lT, 256, h1, w2rT, 256, h2_bl, h0, h2);
  // output block
  vec3_kernel<<<2048, 256, 0, stream>>>(h2, o1_wl, o1_wr, osc_w, osc_b, ubuf, vbuf, scbuf);
  aggv1_kernel<<<2048, 256, 0, stream>>>(Awords, ubuf, deg_inv, vbuf, o1_bl, o1buf);
  aggv2_kernel<<<2048, 256, 0, stream>>>(Awords, o1buf, deg_inv, o2_wl, o2_bl, o2_wr, scbuf, out);
}

// Round 2
// 469.566 us; speedup vs baseline: 1.1101x; 1.1101x over previous
//
#include <hip/hip_runtime.h>

// GNN_79937931313503: dynamic-graph SAGE GNN on MI355X.
// R2: aggA restructured — 128x128 block tile, 4 waves of 64x64 (4x4 frags),
// split-K=4 with fp32 partials + combine kernel, XOR-swizzled LDS (no pad).

typedef __attribute__((ext_vector_type(8))) short s8v;   // 8 x bf16 (4 VGPR)
typedef __attribute__((ext_vector_type(4))) short s4v;   // 4 x bf16
typedef __attribute__((ext_vector_type(4))) float f4v;   // MFMA C/D frag

__device__ __forceinline__ f4v MFMA(s8v a, s8v b, f4v c) {
  return __builtin_amdgcn_mfma_f32_16x16x32_bf16(a, b, c, 0, 0, 0);
}
__device__ __forceinline__ short f2bf(float f) {  // RNE float->bf16 bits
  unsigned u = __float_as_uint(f);
  return (short)((u + 0x7FFFu + ((u >> 16) & 1u)) >> 16);
}
__device__ __forceinline__ float bf2f(short s) {
  return __uint_as_float(((unsigned)(unsigned short)s) << 16);
}

// ---------------- prep ----------------
__global__ __launch_bounds__(256) void prep_x_kernel(const float* __restrict__ x,
                                                     short* __restrict__ xb,
                                                     short* __restrict__ xn) {
  int row = blockIdx.x * 4 + (threadIdx.x >> 6);
  int lane = threadIdx.x & 63;
  float v0 = x[row * 128 + lane];
  float v1 = x[row * 128 + 64 + lane];
  float ss = v0 * v0 + v1 * v1;
  for (int o = 1; o < 64; o <<= 1) ss += __shfl_xor(ss, o);
  float inv = 1.0f / fmaxf(sqrtf(ss), 1e-8f);
  xb[row * 128 + lane] = f2bf(v0);
  xb[row * 128 + 64 + lane] = f2bf(v1);
  xn[row * 128 + lane] = f2bf(v0 * inv);
  xn[row * 128 + 64 + lane] = f2bf(v1 * inv);
}

__global__ __launch_bounds__(256) void prep_w_kernel(
    const float* __restrict__ w_in, const float* __restrict__ w1l,
    const float* __restrict__ w1r, const float* __restrict__ w2l,
    const float* __restrict__ w2r, short* __restrict__ w_inT,
    short* __restrict__ w1lT, short* __restrict__ w1rT,
    short* __restrict__ w2lT, short* __restrict__ w2rT) {
  int idx = blockIdx.x * 256 + threadIdx.x;
  if (idx >= 294912) return;
  if (idx < 32768) {                       // w_in [128][256] -> [256][128]
    int n = idx >> 7, k = idx & 127;
    w_inT[idx] = f2bf(w_in[k * 256 + n]);
  } else {                                 // 4x [256][256] transposed
    int j = idx - 32768;
    int m = j >> 16, r = j & 65535;
    int n = r >> 8, k = r & 255;
    const float* src = (m == 0) ? w1l : (m == 1) ? w1r : (m == 2) ? w2l : w2r;
    short* dst = (m == 0) ? w1lT : (m == 1) ? w1rT : (m == 2) ? w2lT : w2rT;
    dst[r] = f2bf(src[k * 256 + n]);
  }
}

// ---------------- sim: Xn @ XnT, 128x128 tile, 4 waves of 64x64 ----------------
template <int MODE>
__global__ __launch_bounds__(256) void sim_kernel(
    const short* __restrict__ xn, unsigned int* __restrict__ hist,
    unsigned int* __restrict__ sel, unsigned long long* __restrict__ Awords) {
  __shared__ __align__(16) short As[128][72];
  __shared__ __align__(16) short Bs[128][72];
  __shared__ unsigned int lh[1024];
  const int tid = threadIdx.x;
  const int j0 = blockIdx.x * 128;
  const int i0 = blockIdx.y * 128;
  if (MODE == 0)
    for (int b = tid; b < 1024; b += 256) lh[b] = 0;

  const int w = tid >> 6, lane = tid & 63;
  const int wy = (w >> 1) * 64, wx = (w & 1) * 64;
  const int lr = lane & 15, lk = (lane >> 4) * 8;
  f4v acc[4][4];
#pragma unroll
  for (int a = 0; a < 4; ++a)
#pragma unroll
    for (int b = 0; b < 4; ++b) acc[a][b] = (f4v){0.f, 0.f, 0.f, 0.f};

  for (int kb = 0; kb < 128; kb += 64) {
    __syncthreads();
#pragma unroll
    for (int u = 0; u < 4; ++u) {
      int unit = tid + u * 256;
      int r = unit >> 3, sg = (unit & 7) * 8;
      *(s8v*)&As[r][sg] = *(const s8v*)(xn + (i0 + r) * 128 + kb + sg);
      *(s8v*)&Bs[r][sg] = *(const s8v*)(xn + (j0 + r) * 128 + kb + sg);
    }
    __syncthreads();
#pragma unroll
    for (int kc = 0; kc < 2; ++kc) {
      s8v af[4], bf[4];
#pragma unroll
      for (int mt = 0; mt < 4; ++mt) af[mt] = *(const s8v*)&As[wy + mt * 16 + lr][kc * 32 + lk];
#pragma unroll
      for (int nt = 0; nt < 4; ++nt) bf[nt] = *(const s8v*)&Bs[wx + nt * 16 + lr][kc * 32 + lk];
#pragma unroll
      for (int mt = 0; mt < 4; ++mt)
#pragma unroll
        for (int nt = 0; nt < 4; ++nt) acc[mt][nt] = MFMA(af[mt], bf[nt], acc[mt][nt]);
    }
  }

  if (MODE == 0) {
#pragma unroll
    for (int mt = 0; mt < 4; ++mt)
      for (int nt = 0; nt < 4; ++nt)
        for (int r = 0; r < 4; ++r) {
          unsigned bits = __float_as_uint(fabsf(acc[mt][nt][r]));
          unsigned bin = bits >> 20;
          if (bin > 1023u) bin = 1023u;
          atomicAdd(&lh[bin], 1u);
        }
    __syncthreads();
    for (int b = tid; b < 1024; b += 256)
      if (lh[b]) atomicAdd(&hist[b], lh[b]);
  } else if (MODE == 1) {
    unsigned pref = sel[0];
#pragma unroll
    for (int mt = 0; mt < 4; ++mt)
      for (int nt = 0; nt < 4; ++nt)
        for (int r = 0; r < 4; ++r) {
          unsigned bits = __float_as_uint(fabsf(acc[mt][nt][r]));
          if ((bits >> 20) == pref) atomicAdd(&hist[(bits >> 7) & 0x1FFFu], 1u);
        }
  } else {
    float eps = __uint_as_float(sel[2]);
#pragma unroll
    for (int mt = 0; mt < 4; ++mt)
#pragma unroll
      for (int r = 0; r < 4; ++r) {
        unsigned long long b0 = __ballot(fabsf(acc[mt][0][r]) >= eps);
        unsigned long long b1 = __ballot(fabsf(acc[mt][1][r]) >= eps);
        unsigned long long b2 = __ballot(fabsf(acc[mt][2][r]) >= eps);
        unsigned long long b3 = __ballot(fabsf(acc[mt][3][r]) >= eps);
        if (lane < 4) {
          int g = lane;
          unsigned long long word = ((b0 >> (16 * g)) & 0xFFFFull) |
                                    (((b1 >> (16 * g)) & 0xFFFFull) << 16) |
                                    (((b2 >> (16 * g)) & 0xFFFFull) << 32) |
                                    (((b3 >> (16 * g)) & 0xFFFFull) << 48);
          int row = i0 + wy + mt * 16 + g * 4 + r;
          Awords[row * 128 + ((j0 + wx) >> 6)] = word;
        }
      }
  }
}

// ---------------- histogram selection scan ----------------
template <int NB, int MODE>
__global__ __launch_bounds__(256) void scan_kernel(const unsigned int* __restrict__ hist,
                                                   unsigned int* __restrict__ sel) {
  __shared__ unsigned long long csum[256];
  const int t = threadIdx.x;
  const int PER = NB / 256;
  unsigned int vals[NB / 256];
  unsigned long long s = 0;
  for (int i = 0; i < PER; ++i) {
    vals[i] = hist[t * PER + i];
    s += vals[i];
  }
  csum[t] = s;
  __syncthreads();
  for (int o = 1; o < 256; o <<= 1) {
    unsigned long long prev = (t >= o) ? csum[t - o] : 0ull;
    __syncthreads();
    csum[t] += prev;
    __syncthreads();
  }
  unsigned long long K = (MODE == 0) ? 63753421ull : (unsigned long long)sel[1];
  unsigned long long inc = csum[t], exc = inc - s;
  if (K > exc && K <= inc) {
    unsigned long long c = exc;
    for (int i = 0; i < PER; ++i) {
      c += vals[i];
      if (c >= K) {
        if (MODE == 0) {
          sel[0] = (unsigned)(t * PER + i);
          sel[1] = (unsigned)(K - (c - vals[i]));
        } else {
          sel[2] = (sel[0] << 20) | ((unsigned)(t * PER + i) << 7);
        }
        break;
      }
    }
  }
}

// ---------------- degree ----------------
__global__ __launch_bounds__(256) void deg_kernel(const unsigned long long* __restrict__ Awords,
                                                  float* __restrict__ deg_inv) {
  int row = blockIdx.x * 4 + (threadIdx.x >> 6);
  int lane = threadIdx.x & 63;
  int c = __popcll(Awords[row * 128 + lane]) + __popcll(Awords[row * 128 + 64 + lane]);
  for (int o = 32; o; o >>= 1) c += __shfl_down(c, o);
  if (lane == 0) deg_inv[row] = 1.0f / (float)max(c, 1);
}

// ---------------- small NT linears ----------------
template <bool TWO, bool RELU, bool RES>
__global__ __launch_bounds__(256) void lin_kernel(
    const short* __restrict__ A1, const short* __restrict__ B1, int K1,
    const short* __restrict__ A2, const short* __restrict__ B2, int K2,
    const float* __restrict__ bias, const short* __restrict__ res,
    short* __restrict__ out) {
  const int i0 = blockIdx.x * 64, n0 = blockIdx.y * 64;
  const int tid = threadIdx.x, w = tid >> 6, lane = tid & 63;
  const int wy = (w >> 1) * 32, wx = (w & 1) * 32;
  const int lr = lane & 15, lk = (lane >> 4) * 8;
  f4v acc[2][2];
#pragma unroll
  for (int a = 0; a < 2; ++a)
#pragma unroll
    for (int b = 0; b < 2; ++b) acc[a][b] = (f4v){0.f, 0.f, 0.f, 0.f};

  for (int kc = 0; kc < K1; kc += 32) {
    s8v a0 = *(const s8v*)(A1 + (i0 + wy + lr) * K1 + kc + lk);
    s8v a1 = *(const s8v*)(A1 + (i0 + wy + 16 + lr) * K1 + kc + lk);
    s8v b0 = *(const s8v*)(B1 + (n0 + wx + lr) * K1 + kc + lk);
    s8v b1 = *(const s8v*)(B1 + (n0 + wx + 16 + lr) * K1 + kc + lk);
    acc[0][0] = MFMA(a0, b0, acc[0][0]);
    acc[0][1] = MFMA(a0, b1, acc[0][1]);
    acc[1][0] = MFMA(a1, b0, acc[1][0]);
    acc[1][1] = MFMA(a1, b1, acc[1][1]);
  }
  if constexpr (TWO) {
    for (int kc = 0; kc < K2; kc += 32) {
      s8v a0 = *(const s8v*)(A2 + (i0 + wy + lr) * K2 + kc + lk);
      s8v a1 = *(const s8v*)(A2 + (i0 + wy + 16 + lr) * K2 + kc + lk);
      s8v b0 = *(const s8v*)(B2 + (n0 + wx + lr) * K2 + kc + lk);
      s8v b1 = *(const s8v*)(B2 + (n0 + wx + 16 + lr) * K2 + kc + lk);
      acc[0][0] = MFMA(a0, b0, acc[0][0]);
      acc[0][1] = MFMA(a0, b1, acc[0][1]);
      acc[1][0] = MFMA(a1, b0, acc[1][0]);
      acc[1][1] = MFMA(a1, b1, acc[1][1]);
    }
  }
#pragma unroll
  for (int mt = 0; mt < 2; ++mt)
#pragma unroll
    for (int nt = 0; nt < 2; ++nt)
#pragma unroll
      for (int r = 0; r < 4; ++r) {
        int row = i0 + wy + mt * 16 + (lane >> 4) * 4 + r;
        int col = n0 + wx + nt * 16 + (lane & 15);
        float v = acc[mt][nt][r] + bias[col];
        if constexpr (RES) v += bf2f(res[row * 256 + col]);
        if constexpr (RELU) v = fmaxf(v, 0.f);
        out[row * 256 + col] = f2bf(v);
      }
}

// ---------------- transpose [8192][256] -> [256][8192] ----------------
__global__ __launch_bounds__(256) void transpose_kernel(const short* __restrict__ in,
                                                        short* __restrict__ out) {
  __shared__ __align__(16) short T[64][72];
  const int i0 = blockIdx.x * 64, f0 = blockIdx.y * 64;
  const int t = threadIdx.x;
  const int r = t >> 2, c0 = (t & 3) * 16;
  s8v v0 = *(const s8v*)(in + (i0 + r) * 256 + f0 + c0);
  s8v v1 = *(const s8v*)(in + (i0 + r) * 256 + f0 + c0 + 8);
#pragma unroll
  for (int e = 0; e < 8; ++e) {
    T[c0 + e][r] = v0[e];
    T[c0 + 8 + e][r] = v1[e];
  }
  __syncthreads();
  s8v o0, o1;
#pragma unroll
  for (int e = 0; e < 8; ++e) {
    o0[e] = T[r][c0 + e];
    o1[e] = T[r][c0 + 8 + e];
  }
  *(s8v*)(out + (f0 + r) * 8192 + i0 + c0) = o0;
  *(s8v*)(out + (f0 + r) * 8192 + i0 + c0 + 8) = o1;
}

// ---------------- aggA: partial[z] = A[:, kslice] @ h[kslice, :] ----------------
// 128x128 block tile, 4 waves of 64x64 (4x4 frags). XOR-swizzled LDS, no pad.
// swizzle: elem (row, unit[16B], e) stored at row*128 + ((unit^(row&7))<<3) + e
__global__ __launch_bounds__(256) void aggA_kernel(const unsigned long long* __restrict__ Awords,
                                                   const short* __restrict__ hT,
                                                   float* __restrict__ partial,
                                                   int ksplit) {
  __shared__ __align__(16) short As[128 * 128];
  __shared__ __align__(16) short Bs[128 * 128];
  const int i0 = blockIdx.x * 128;  // node rows
  const int f0 = blockIdx.y * 128;  // features
  const int k0 = blockIdx.z * ksplit;
  const int tid = threadIdx.x, w = tid >> 6, lane = tid & 63;
  const int wy = (w >> 1) * 64, wx = (w & 1) * 64;
  const int lr = lane & 15, g = lane >> 4;
  const int srow = tid >> 1, shalf = tid & 1;  // staging assignment

  f4v acc[4][4];
#pragma unroll
  for (int a = 0; a < 4; ++a)
#pragma unroll
    for (int b = 0; b < 4; ++b) acc[a][b] = (f4v){0.f, 0.f, 0.f, 0.f};

  for (int kb = k0; kb < k0 + ksplit; kb += 128) {
    __syncthreads();
    {  // A: expand 128 rows x 128 bits -> bf16 (64 bits per thread)
      unsigned long long wv = Awords[(size_t)(i0 + srow) * 128 + (kb >> 6) + shalf];
#pragma unroll
      for (int j = 0; j < 8; ++j) {
        int unit = shalf * 8 + j;
        unsigned byte = (unsigned)(wv >> (j * 8)) & 0xFFu;
        s8v v;
#pragma unroll
        for (int e = 0; e < 8; ++e) v[e] = ((byte >> e) & 1u) ? (short)0x3F80 : (short)0;
        *(s8v*)&As[srow * 128 + ((unit ^ (srow & 7)) << 3)] = v;
      }
    }
    {  // B: 128 feats x 128 k from hT (8 units per thread)
      const short* src = hT + (size_t)(f0 + srow) * 8192 + kb + shalf * 64;
#pragma unroll
      for (int j = 0; j < 8; ++j) {
        s8v v = *(const s8v*)(src + j * 8);
        int unit = shalf * 8 + j;
        *(s8v*)&Bs[srow * 128 + ((unit ^ (srow & 7)) << 3)] = v;
      }
    }
    __syncthreads();
#pragma unroll
    for (int kc = 0; kc < 4; ++kc) {
      s8v af[4], bf[4];
#pragma unroll
      for (int mt = 0; mt < 4; ++mt) {
        int row = wy + mt * 16 + lr;
        af[mt] = *(const s8v*)&As[row * 128 + (((kc * 4 + g) ^ (row & 7)) << 3)];
      }
#pragma unroll
      for (int nt = 0; nt < 4; ++nt) {
        int col = wx + nt * 16 + lr;
        bf[nt] = *(const s8v*)&Bs[col * 128 + (((kc * 4 + g) ^ (col & 7)) << 3)];
      }
#pragma unroll
      for (int mt = 0; mt < 4; ++mt)
#pragma unroll
        for (int nt = 0; nt < 4; ++nt) acc[mt][nt] = MFMA(af[mt], bf[nt], acc[mt][nt]);
    }
  }
  float* P = partial + (size_t)blockIdx.z * (8192 * 256);
#pragma unroll
  for (int mt = 0; mt < 4; ++mt)
#pragma unroll
    for (int nt = 0; nt < 4; ++nt)
#pragma unroll
      for (int r = 0; r < 4; ++r) {
        int row = i0 + wy + mt * 16 + g * 4 + r;
        int col = f0 + wx + nt * 16 + lr;
        P[(size_t)row * 256 + col] = acc[mt][nt][r];
      }
}

// combine: agg = bf16(sum_z partial[z] * deg_inv[row])
__global__ __launch_bounds__(256) void combine_kernel(const float* __restrict__ p, int nsplit,
                                                      const float* __restrict__ deg_inv,
                                                      short* __restrict__ agg) {
  int idx = blockIdx.x * 256 + threadIdx.x;  // group of 4 elems
  const float4* pv = (const float4*)p;
  float4 s = pv[idx];
  for (int k = 1; k < nsplit; ++k) {
    float4 v = pv[(size_t)k * 524288 + idx];
    s.x += v.x; s.y += v.y; s.z += v.z; s.w += v.w;
  }
  float di = deg_inv[idx >> 6];
  s4v o;
  o[0] = f2bf(s.x * di); o[1] = f2bf(s.y * di);
  o[2] = f2bf(s.z * di); o[3] = f2bf(s.w * di);
  *(s4v*)&agg[idx * 4] = o;
}

// ---------------- tail ----------------
__global__ __launch_bounds__(256) void vec3_kernel(const short* __restrict__ h2,
                                                   const float* __restrict__ o1wl,
                                                   const float* __restrict__ o1wr,
                                                   const float* __restrict__ oscw,
                                                   const float* __restrict__ oscb,
                                                   float* __restrict__ u, float* __restrict__ v,
                                                   float* __restrict__ sc) {
  int row = blockIdx.x * 4 + (threadIdx.x >> 6);
  int lane = threadIdx.x & 63;
  float su = 0.f, sv = 0.f, ss = 0.f;
#pragma unroll
  for (int e = 0; e < 4; ++e) {
    int k = lane * 4 + e;
    float hv = bf2f(h2[row * 256 + k]);
    su += hv * o1wl[k];
    sv += hv * o1wr[k];
    ss += hv * oscw[k];
  }
  for (int o = 1; o < 64; o <<= 1) {
    su += __shfl_xor(su, o);
    sv += __shfl_xor(sv, o);
    ss += __shfl_xor(ss, o);
  }
  if (lane == 0) {
    u[row] = su;
    v[row] = sv;
    sc[row] = ss + oscb[0];
  }
}

__global__ __launch_bounds__(256) void aggv1_kernel(const unsigned long long* __restrict__ Awords,
                                                    const float* __restrict__ u,
                                                    const float* __restrict__ deg_inv,
                                                    const float* __restrict__ v,
                                                    const float* __restrict__ o1bl,
                                                    float* __restrict__ o1) {
  int row = blockIdx.x * 4 + (threadIdx.x >> 6);
  int lane = threadIdx.x & 63;
  float s = 0.f;
#pragma unroll
  for (int wi = 0; wi < 2; ++wi) {
    unsigned long long bits = Awords[row * 128 + wi * 64 + lane];
    int base = (wi * 64 + lane) * 64;
    while (bits) {
      int b = __ffsll(bits) - 1;
      s += u[base + b];
      bits &= bits - 1;
    }
  }
  for (int o = 1; o < 64; o <<= 1) s += __shfl_xor(s, o);
  if (lane == 0) o1[row] = fmaxf(s * deg_inv[row] + o1bl[0] + v[row], 0.f);
}

__global__ __launch_bounds__(256) void aggv2_kernel(const unsigned long long* __restrict__ Awords,
                                                    const float* __restrict__ o1,
                                                    const float* __restrict__ deg_inv,
                                                    const float* __restrict__ o2wl,
                                                    const float* __restrict__ o2bl,
                                                    const float* __restrict__ o2wr,
                                                    const float* __restrict__ sc,
                                                    float* __restrict__ out) {
  int row = blockIdx.x * 4 + (threadIdx.x >> 6);
  int lane = threadIdx.x & 63;
  float s = 0.f;
#pragma unroll
  for (int wi = 0; wi < 2; ++wi) {
    unsigned long long bits = Awords[row * 128 + wi * 64 + lane];
    int base = (wi * 64 + lane) * 64;
    while (bits) {
      int b = __ffsll(bits) - 1;
      s += o1[base + b];
      bits &= bits - 1;
    }
  }
  for (int o = 1; o < 64; o <<= 1) s += __shfl_xor(s, o);
  if (lane == 0) {
    float z = s * deg_inv[row] * o2wl[0] + o2bl[0] + o1[row] * o2wr[0] + sc[row];
    out[row] = 1.f / (1.f + expf(-z));
  }
}

// ---------------- launch ----------------
extern "C" void kernel_launch(void* const* d_in, const int* in_sizes, int n_in,
                              void* d_out, int out_size, void* d_ws, size_t ws_size,
                              hipStream_t stream) {
  (void)in_sizes; (void)n_in; (void)out_size;
  const float* x     = (const float*)d_in[0];
  const float* w_in  = (const float*)d_in[1];
  const float* b_in  = (const float*)d_in[2];
  const float* h1_wl = (const float*)d_in[3];
  const float* h1_bl = (const float*)d_in[4];
  const float* h1_wr = (const float*)d_in[5];
  const float* h2_wl = (const float*)d_in[6];
  const float* h2_bl = (const float*)d_in[7];
  const float* h2_wr = (const float*)d_in[8];
  const float* o1_wl = (const float*)d_in[9];
  const float* o1_bl = (const float*)d_in[10];
  const float* o1_wr = (const float*)d_in[11];
  const float* o2_wl = (const float*)d_in[12];
  const float* o2_bl = (const float*)d_in[13];
  const float* o2_wr = (const float*)d_in[14];
  const float* osc_w = (const float*)d_in[15];
  const float* osc_b = (const float*)d_in[16];
  float* out = (float*)d_out;

  char* ws = (char*)d_ws;
  size_t off = 0;
  auto alloc = [&](size_t bytes) -> char* {
    char* p = ws + off;
    off += (bytes + 255) & ~(size_t)255;
    return p;
  };
  short* xn    = (short*)alloc(8192 * 128 * 2);
  short* xb    = (short*)alloc(8192 * 128 * 2);
  short* w_inT = (short*)alloc(256 * 128 * 2);
  short* w1lT  = (short*)alloc(256 * 256 * 2);
  short* w1rT  = (short*)alloc(256 * 256 * 2);
  short* w2lT  = (short*)alloc(256 * 256 * 2);
  short* w2rT  = (short*)alloc(256 * 256 * 2);
  unsigned int* hist1 = (unsigned int*)alloc(1024 * 4);
  unsigned int* hist2 = (unsigned int*)alloc(8192 * 4);
  unsigned int* sel   = (unsigned int*)alloc(256);
  float* deg_inv = (float*)alloc(8192 * 4);
  float* ubuf  = (float*)alloc(8192 * 4);
  float* vbuf  = (float*)alloc(8192 * 4);
  float* scbuf = (float*)alloc(8192 * 4);
  float* o1buf = (float*)alloc(8192 * 4);
  unsigned long long* Awords = (unsigned long long*)alloc((size_t)8192 * 128 * 8);
  short* h0  = (short*)alloc((size_t)8192 * 256 * 2);
  short* h1  = (short*)alloc((size_t)8192 * 256 * 2);
  short* h2  = (short*)alloc((size_t)8192 * 256 * 2);
  short* hT  = (short*)alloc((size_t)8192 * 256 * 2);
  short* agg = (short*)alloc((size_t)8192 * 256 * 2);
  // split-K partials: prefer 4, fall back to 2 if workspace is tight
  int nsplit = (ws_size >= off + 4 * (size_t)8192 * 256 * 4 + 4096) ? 4 : 2;
  float* partials = (float*)alloc((size_t)nsplit * 8192 * 256 * 4);
  const int ksplit = 8192 / nsplit;

  hipMemsetAsync(hist1, 0, (1024 + 8192) * 4, stream);
  prep_x_kernel<<<2048, 256, 0, stream>>>(x, xb, xn);
  prep_w_kernel<<<1152, 256, 0, stream>>>(w_in, h1_wl, h1_wr, h2_wl, h2_wr,
                                          w_inT, w1lT, w1rT, w2lT, w2rT);
  sim_kernel<0><<<dim3(64, 64), 256, 0, stream>>>(xn, hist1, sel, nullptr);
  scan_kernel<1024, 0><<<1, 256, 0, stream>>>(hist1, sel);
  sim_kernel<1><<<dim3(64, 64), 256, 0, stream>>>(xn, hist2, sel, nullptr);
  scan_kernel<8192, 1><<<1, 256, 0, stream>>>(hist2, sel);
  sim_kernel<2><<<dim3(64, 64), 256, 0, stream>>>(xn, nullptr, sel, Awords);
  deg_kernel<<<2048, 256, 0, stream>>>(Awords, deg_inv);

  // h0 = relu(x @ w_in + b_in)
  lin_kernel<false, true, false><<<dim3(128, 4), 256, 0, stream>>>(
      xb, w_inT, 128, nullptr, nullptr, 0, b_in, nullptr, h0);
  // h1 = relu(agg(h0)@h1_wl + h1_bl + h0@h1_wr)
  transpose_kernel<<<dim3(128, 4), 256, 0, stream>>>(h0, hT);
  aggA_kernel<<<dim3(64, 2, nsplit), 256, 0, stream>>>(Awords, hT, partials, ksplit);
  combine_kernel<<<2048, 256, 0, stream>>>(partials, nsplit, deg_inv, agg);
  lin_kernel<true, true, false><<<dim3(128, 4), 256, 0, stream>>>(
      agg, w1lT, 256, h0, w1rT, 256, h1_bl, nullptr, h1);
  // h2 = relu(agg(h1)@h2_wl + h2_bl + h1@h2_wr + h0)
  transpose_kernel<<<dim3(128, 4), 256, 0, stream>>>(h1, hT);
  aggA_kernel<<<dim3(64, 2, nsplit), 256, 0, stream>>>(Awords, hT, partials, ksplit);
  combine_kernel<<<2048, 256, 0, stream>>>(partials, nsplit, deg_inv, agg);
  lin_kernel<true, true, true><<<dim3(128, 4), 256, 0, stream>>>(
      agg, w2lT, 256, h1, w2rT, 256, h2_bl, h0, h2);
  // output block
  vec3_kernel<<<2048, 256, 0, stream>>>(h2, o1_wl, o1_wr, osc_w, osc_b, ubuf, vbuf, scbuf);
  aggv1_kernel<<<2048, 256, 0, stream>>>(Awords, ubuf, deg_inv, vbuf, o1_bl, o1buf);
  aggv2_kernel<<<2048, 256, 0, stream>>>(Awords, o1buf, deg_inv, o2_wl, o2_bl, o2_wr, scbuf, out);
}

// Round 3
// 437.165 us; speedup vs baseline: 1.1924x; 1.0741x over previous
//
#include <hip/hip_runtime.h>

// GNN_79937931313503: dynamic-graph SAGE GNN on MI355X.
// R3: sim rebuilt — per-wave 64x64 tiles, fragments loaded DIRECTLY from
// global (no LDS, no barriers), upper-triangle only (symmetric sim), weight-2
// histogram, ballot bit-transpose for the mirrored adjacency tile.

typedef __attribute__((ext_vector_type(8))) short s8v;   // 8 x bf16 (4 VGPR)
typedef __attribute__((ext_vector_type(4))) short s4v;   // 4 x bf16
typedef __attribute__((ext_vector_type(4))) float f4v;   // MFMA C/D frag

__device__ __forceinline__ f4v MFMA(s8v a, s8v b, f4v c) {
  return __builtin_amdgcn_mfma_f32_16x16x32_bf16(a, b, c, 0, 0, 0);
}
__device__ __forceinline__ short f2bf(float f) {  // RNE float->bf16 bits
  unsigned u = __float_as_uint(f);
  return (short)((u + 0x7FFFu + ((u >> 16) & 1u)) >> 16);
}
__device__ __forceinline__ float bf2f(short s) {
  return __uint_as_float(((unsigned)(unsigned short)s) << 16);
}

// ---------------- prep ----------------
__global__ __launch_bounds__(256) void prep_x_kernel(const float* __restrict__ x,
                                                     short* __restrict__ xb,
                                                     short* __restrict__ xn) {
  int row = blockIdx.x * 4 + (threadIdx.x >> 6);
  int lane = threadIdx.x & 63;
  float v0 = x[row * 128 + lane];
  float v1 = x[row * 128 + 64 + lane];
  float ss = v0 * v0 + v1 * v1;
  for (int o = 1; o < 64; o <<= 1) ss += __shfl_xor(ss, o);
  float inv = 1.0f / fmaxf(sqrtf(ss), 1e-8f);
  xb[row * 128 + lane] = f2bf(v0);
  xb[row * 128 + 64 + lane] = f2bf(v1);
  xn[row * 128 + lane] = f2bf(v0 * inv);
  xn[row * 128 + 64 + lane] = f2bf(v1 * inv);
}

__global__ __launch_bounds__(256) void prep_w_kernel(
    const float* __restrict__ w_in, const float* __restrict__ w1l,
    const float* __restrict__ w1r, const float* __restrict__ w2l,
    const float* __restrict__ w2r, short* __restrict__ w_inT,
    short* __restrict__ w1lT, short* __restrict__ w1rT,
    short* __restrict__ w2lT, short* __restrict__ w2rT) {
  int idx = blockIdx.x * 256 + threadIdx.x;
  if (idx >= 294912) return;
  if (idx < 32768) {                       // w_in [128][256] -> [256][128]
    int n = idx >> 7, k = idx & 127;
    w_inT[idx] = f2bf(w_in[k * 256 + n]);
  } else {                                 // 4x [256][256] transposed
    int j = idx - 32768;
    int m = j >> 16, r = j & 65535;
    int n = r >> 8, k = r & 255;
    const float* src = (m == 0) ? w1l : (m == 1) ? w1r : (m == 2) ? w2l : w2r;
    short* dst = (m == 0) ? w1lT : (m == 1) ? w1rT : (m == 2) ? w2lT : w2rT;
    dst[r] = f2bf(src[k * 256 + n]);
  }
}

// ---------------- sim: per-wave 64x64 tiles, upper triangle only ----------------
// MODE 0: weighted 1024-bin histogram (bits>>20). MODE 1: refine within prefix.
// MODE 2: build symmetric adjacency bitmask (tile + ballot bit-transposed mirror).
// Tile index t in [0, 8256): triangular (r<=c) over 128x128 grid of 64-tiles.
#define NT64 128
#define NTRI 8256  // 128*129/2
template <int MODE>
__global__ __launch_bounds__(256) void sim_kernel(
    const short* __restrict__ xn, unsigned int* __restrict__ hist,
    unsigned int* __restrict__ sel, unsigned long long* __restrict__ Awords) {
  __shared__ unsigned int lh[4096];  // 4-way lane-split sub-histograms (MODE 0)
  const int tid = threadIdx.x, w = tid >> 6, lane = tid & 63;
  if (MODE == 0) {
    for (int b = tid; b < 4096; b += 256) lh[b] = 0;
    __syncthreads();
  }
  int t = blockIdx.x * 4 + w;
  // invert triangular index: cum(r) = r*128 - r*(r-1)/2
  int r = (int)((257.0f - sqrtf((float)(257 * 257 - 8 * t))) * 0.5f);
  if (r < 0) r = 0;
  if (r > 127) r = 127;
  while (r < 127 && ((r + 1) * NT64 - (r + 1) * r / 2) <= t) ++r;
  while (r > 0 && (r * NT64 - r * (r - 1) / 2) > t) --r;
  const int c = r + (t - (r * NT64 - r * (r - 1) / 2));
  const int i0 = r * 64, j0 = c * 64;
  const bool diag = (r == c);

  const int lr = lane & 15, g = lane >> 4;
  f4v acc[4][4];
#pragma unroll
  for (int a = 0; a < 4; ++a)
#pragma unroll
    for (int b = 0; b < 4; ++b) acc[a][b] = (f4v){0.f, 0.f, 0.f, 0.f};

#pragma unroll
  for (int kc = 0; kc < 4; ++kc) {
    s8v af[4], bf[4];
#pragma unroll
    for (int mt = 0; mt < 4; ++mt)
      af[mt] = *(const s8v*)(xn + (i0 + mt * 16 + lr) * 128 + kc * 32 + g * 8);
#pragma unroll
    for (int nt = 0; nt < 4; ++nt)
      bf[nt] = *(const s8v*)(xn + (j0 + nt * 16 + lr) * 128 + kc * 32 + g * 8);
#pragma unroll
    for (int mt = 0; mt < 4; ++mt)
#pragma unroll
      for (int nt = 0; nt < 4; ++nt) acc[mt][nt] = MFMA(af[mt], bf[nt], acc[mt][nt]);
  }

  if (MODE == 0) {
    unsigned wgt = diag ? 1u : 2u;
#pragma unroll
    for (int mt = 0; mt < 4; ++mt)
      for (int nt = 0; nt < 4; ++nt)
        for (int rr = 0; rr < 4; ++rr) {
          unsigned bits = __float_as_uint(fabsf(acc[mt][nt][rr]));
          unsigned bin = bits >> 20;
          if (bin > 1023u) bin = 1023u;
          atomicAdd(&lh[bin * 4 + (lane & 3)], wgt);
        }
    __syncthreads();
    for (int b = tid; b < 1024; b += 256) {
      unsigned s = lh[b * 4] + lh[b * 4 + 1] + lh[b * 4 + 2] + lh[b * 4 + 3];
      if (s) atomicAdd(&hist[b], s);
    }
  } else if (MODE == 1) {
    unsigned pref = sel[0];
    unsigned wgt = diag ? 1u : 2u;
#pragma unroll
    for (int mt = 0; mt < 4; ++mt)
      for (int nt = 0; nt < 4; ++nt)
        for (int rr = 0; rr < 4; ++rr) {
          unsigned bits = __float_as_uint(fabsf(acc[mt][nt][rr]));
          if ((bits >> 20) == pref) atomicAdd(&hist[(bits >> 7) & 0x1FFFu], wgt);
        }
  } else {
    float eps = __uint_as_float(sel[2]);
    unsigned long long myword = 0;  // lane j holds row (i0+j)'s 64 bits [j0..j0+64)
#pragma unroll
    for (int mt = 0; mt < 4; ++mt)
#pragma unroll
      for (int rr = 0; rr < 4; ++rr) {
        unsigned long long b0 = __ballot(fabsf(acc[mt][0][rr]) >= eps);
        unsigned long long b1 = __ballot(fabsf(acc[mt][1][rr]) >= eps);
        unsigned long long b2 = __ballot(fabsf(acc[mt][2][rr]) >= eps);
        unsigned long long b3 = __ballot(fabsf(acc[mt][3][rr]) >= eps);
        // row within tile = mt*16 + gj*4 + rr; my gj = (lane>>2)&3
        if ((lane >> 4) == mt && (lane & 3) == rr) {
          int gj = (lane >> 2) & 3;
          myword = ((b0 >> (16 * gj)) & 0xFFFFull) |
                   (((b1 >> (16 * gj)) & 0xFFFFull) << 16) |
                   (((b2 >> (16 * gj)) & 0xFFFFull) << 32) |
                   (((b3 >> (16 * gj)) & 0xFFFFull) << 48);
        }
      }
    Awords[(size_t)(i0 + lane) * 128 + (j0 >> 6)] = myword;
    if (!diag) {  // mirrored tile via 64x64 bit transpose (ballot per column)
      unsigned long long tw = 0;
#pragma unroll
      for (int c2 = 0; c2 < 64; ++c2) {
        unsigned long long bc = __ballot((myword >> c2) & 1ull);
        if (lane == c2) tw = bc;
      }
      Awords[(size_t)(j0 + lane) * 128 + (i0 >> 6)] = tw;
    }
  }
}

// ---------------- histogram selection scan ----------------
template <int NB, int MODE>
__global__ __launch_bounds__(256) void scan_kernel(const unsigned int* __restrict__ hist,
                                                   unsigned int* __restrict__ sel) {
  __shared__ unsigned long long csum[256];
  const int t = threadIdx.x;
  const int PER = NB / 256;
  unsigned int vals[NB / 256];
  unsigned long long s = 0;
  for (int i = 0; i < PER; ++i) {
    vals[i] = hist[t * PER + i];
    s += vals[i];
  }
  csum[t] = s;
  __syncthreads();
  for (int o = 1; o < 256; o <<= 1) {
    unsigned long long prev = (t >= o) ? csum[t - o] : 0ull;
    __syncthreads();
    csum[t] += prev;
    __syncthreads();
  }
  unsigned long long K = (MODE == 0) ? 63753421ull : (unsigned long long)sel[1];
  unsigned long long inc = csum[t], exc = inc - s;
  if (K > exc && K <= inc) {
    unsigned long long c = exc;
    for (int i = 0; i < PER; ++i) {
      c += vals[i];
      if (c >= K) {
        if (MODE == 0) {
          sel[0] = (unsigned)(t * PER + i);
          sel[1] = (unsigned)(K - (c - vals[i]));
        } else {
          sel[2] = (sel[0] << 20) | ((unsigned)(t * PER + i) << 7);
        }
        break;
      }
    }
  }
}

// ---------------- degree ----------------
__global__ __launch_bounds__(256) void deg_kernel(const unsigned long long* __restrict__ Awords,
                                                  float* __restrict__ deg_inv) {
  int row = blockIdx.x * 4 + (threadIdx.x >> 6);
  int lane = threadIdx.x & 63;
  int c = __popcll(Awords[row * 128 + lane]) + __popcll(Awords[row * 128 + 64 + lane]);
  for (int o = 32; o; o >>= 1) c += __shfl_down(c, o);
  if (lane == 0) deg_inv[row] = 1.0f / (float)max(c, 1);
}

// ---------------- small NT linears ----------------
template <bool TWO, bool RELU, bool RES>
__global__ __launch_bounds__(256) void lin_kernel(
    const short* __restrict__ A1, const short* __restrict__ B1, int K1,
    const short* __restrict__ A2, const short* __restrict__ B2, int K2,
    const float* __restrict__ bias, const short* __restrict__ res,
    short* __restrict__ out) {
  const int i0 = blockIdx.x * 64, n0 = blockIdx.y * 64;
  const int tid = threadIdx.x, w = tid >> 6, lane = tid & 63;
  const int wy = (w >> 1) * 32, wx = (w & 1) * 32;
  const int lr = lane & 15, lk = (lane >> 4) * 8;
  f4v acc[2][2];
#pragma unroll
  for (int a = 0; a < 2; ++a)
#pragma unroll
    for (int b = 0; b < 2; ++b) acc[a][b] = (f4v){0.f, 0.f, 0.f, 0.f};

  for (int kc = 0; kc < K1; kc += 32) {
    s8v a0 = *(const s8v*)(A1 + (i0 + wy + lr) * K1 + kc + lk);
    s8v a1 = *(const s8v*)(A1 + (i0 + wy + 16 + lr) * K1 + kc + lk);
    s8v b0 = *(const s8v*)(B1 + (n0 + wx + lr) * K1 + kc + lk);
    s8v b1 = *(const s8v*)(B1 + (n0 + wx + 16 + lr) * K1 + kc + lk);
    acc[0][0] = MFMA(a0, b0, acc[0][0]);
    acc[0][1] = MFMA(a0, b1, acc[0][1]);
    acc[1][0] = MFMA(a1, b0, acc[1][0]);
    acc[1][1] = MFMA(a1, b1, acc[1][1]);
  }
  if constexpr (TWO) {
    for (int kc = 0; kc < K2; kc += 32) {
      s8v a0 = *(const s8v*)(A2 + (i0 + wy + lr) * K2 + kc + lk);
      s8v a1 = *(const s8v*)(A2 + (i0 + wy + 16 + lr) * K2 + kc + lk);
      s8v b0 = *(const s8v*)(B2 + (n0 + wx + lr) * K2 + kc + lk);
      s8v b1 = *(const s8v*)(B2 + (n0 + wx + 16 + lr) * K2 + kc + lk);
      acc[0][0] = MFMA(a0, b0, acc[0][0]);
      acc[0][1] = MFMA(a0, b1, acc[0][1]);
      acc[1][0] = MFMA(a1, b0, acc[1][0]);
      acc[1][1] = MFMA(a1, b1, acc[1][1]);
    }
  }
#pragma unroll
  for (int mt = 0; mt < 2; ++mt)
#pragma unroll
    for (int nt = 0; nt < 2; ++nt)
#pragma unroll
      for (int rr = 0; rr < 4; ++rr) {
        int row = i0 + wy + mt * 16 + (lane >> 4) * 4 + rr;
        int col = n0 + wx + nt * 16 + (lane & 15);
        float v = acc[mt][nt][rr] + bias[col];
        if constexpr (RES) v += bf2f(res[row * 256 + col]);
        if constexpr (RELU) v = fmaxf(v, 0.f);
        out[row * 256 + col] = f2bf(v);
      }
}

// ---------------- transpose [8192][256] -> [256][8192] ----------------
__global__ __launch_bounds__(256) void transpose_kernel(const short* __restrict__ in,
                                                        short* __restrict__ out) {
  __shared__ __align__(16) short T[64][72];
  const int i0 = blockIdx.x * 64, f0 = blockIdx.y * 64;
  const int t = threadIdx.x;
  const int r = t >> 2, c0 = (t & 3) * 16;
  s8v v0 = *(const s8v*)(in + (i0 + r) * 256 + f0 + c0);
  s8v v1 = *(const s8v*)(in + (i0 + r) * 256 + f0 + c0 + 8);
#pragma unroll
  for (int e = 0; e < 8; ++e) {
    T[c0 + e][r] = v0[e];
    T[c0 + 8 + e][r] = v1[e];
  }
  __syncthreads();
  s8v o0, o1;
#pragma unroll
  for (int e = 0; e < 8; ++e) {
    o0[e] = T[r][c0 + e];
    o1[e] = T[r][c0 + 8 + e];
  }
  *(s8v*)(out + (f0 + r) * 8192 + i0 + c0) = o0;
  *(s8v*)(out + (f0 + r) * 8192 + i0 + c0 + 8) = o1;
}

// ---------------- aggA: partial[z] = A[:, kslice] @ h[kslice, :] ----------------
// 128x128 block tile, 4 waves of 64x64 (4x4 frags). XOR-swizzled LDS, no pad.
__global__ __launch_bounds__(256) void aggA_kernel(const unsigned long long* __restrict__ Awords,
                                                   const short* __restrict__ hT,
                                                   float* __restrict__ partial,
                                                   int ksplit) {
  __shared__ __align__(16) short As[128 * 128];
  __shared__ __align__(16) short Bs[128 * 128];
  const int i0 = blockIdx.x * 128;  // node rows
  const int f0 = blockIdx.y * 128;  // features
  const int k0 = blockIdx.z * ksplit;
  const int tid = threadIdx.x, w = tid >> 6, lane = tid & 63;
  const int wy = (w >> 1) * 64, wx = (w & 1) * 64;
  const int lr = lane & 15, g = lane >> 4;
  const int srow = tid >> 1, shalf = tid & 1;  // staging assignment

  f4v acc[4][4];
#pragma unroll
  for (int a = 0; a < 4; ++a)
#pragma unroll
    for (int b = 0; b < 4; ++b) acc[a][b] = (f4v){0.f, 0.f, 0.f, 0.f};

  for (int kb = k0; kb < k0 + ksplit; kb += 128) {
    __syncthreads();
    {  // A: expand 128 rows x 128 bits -> bf16 (64 bits per thread)
      unsigned long long wv = Awords[(size_t)(i0 + srow) * 128 + (kb >> 6) + shalf];
#pragma unroll
      for (int j = 0; j < 8; ++j) {
        int unit = shalf * 8 + j;
        unsigned byte = (unsigned)(wv >> (j * 8)) & 0xFFu;
        s8v v;
#pragma unroll
        for (int e = 0; e < 8; ++e) v[e] = ((byte >> e) & 1u) ? (short)0x3F80 : (short)0;
        *(s8v*)&As[srow * 128 + ((unit ^ (srow & 7)) << 3)] = v;
      }
    }
    {  // B: 128 feats x 128 k from hT
      const short* src = hT + (size_t)(f0 + srow) * 8192 + kb + shalf * 64;
#pragma unroll
      for (int j = 0; j < 8; ++j) {
        s8v v = *(const s8v*)(src + j * 8);
        int unit = shalf * 8 + j;
        *(s8v*)&Bs[srow * 128 + ((unit ^ (srow & 7)) << 3)] = v;
      }
    }
    __syncthreads();
#pragma unroll
    for (int kc = 0; kc < 4; ++kc) {
      s8v af[4], bf[4];
#pragma unroll
      for (int mt = 0; mt < 4; ++mt) {
        int row = wy + mt * 16 + lr;
        af[mt] = *(const s8v*)&As[row * 128 + (((kc * 4 + g) ^ (row & 7)) << 3)];
      }
#pragma unroll
      for (int nt = 0; nt < 4; ++nt) {
        int col = wx + nt * 16 + lr;
        bf[nt] = *(const s8v*)&Bs[col * 128 + (((kc * 4 + g) ^ (col & 7)) << 3)];
      }
#pragma unroll
      for (int mt = 0; mt < 4; ++mt)
#pragma unroll
        for (int nt = 0; nt < 4; ++nt) acc[mt][nt] = MFMA(af[mt], bf[nt], acc[mt][nt]);
    }
  }
  float* P = partial + (size_t)blockIdx.z * (8192 * 256);
#pragma unroll
  for (int mt = 0; mt < 4; ++mt)
#pragma unroll
    for (int nt = 0; nt < 4; ++nt)
#pragma unroll
      for (int rr = 0; rr < 4; ++rr) {
        int row = i0 + wy + mt * 16 + g * 4 + rr;
        int col = f0 + wx + nt * 16 + lr;
        P[(size_t)row * 256 + col] = acc[mt][nt][rr];
      }
}

// combine: agg = bf16(sum_z partial[z] * deg_inv[row])
__global__ __launch_bounds__(256) void combine_kernel(const float* __restrict__ p, int nsplit,
                                                      const float* __restrict__ deg_inv,
                                                      short* __restrict__ agg) {
  int idx = blockIdx.x * 256 + threadIdx.x;  // group of 4 elems
  const float4* pv = (const float4*)p;
  float4 s = pv[idx];
  for (int k = 1; k < nsplit; ++k) {
    float4 v = pv[(size_t)k * 524288 + idx];
    s.x += v.x; s.y += v.y; s.z += v.z; s.w += v.w;
  }
  float di = deg_inv[idx >> 6];
  s4v o;
  o[0] = f2bf(s.x * di); o[1] = f2bf(s.y * di);
  o[2] = f2bf(s.z * di); o[3] = f2bf(s.w * di);
  *(s4v*)&agg[idx * 4] = o;
}

// ---------------- tail ----------------
__global__ __launch_bounds__(256) void vec3_kernel(const short* __restrict__ h2,
                                                   const float* __restrict__ o1wl,
                                                   const float* __restrict__ o1wr,
                                                   const float* __restrict__ oscw,
                                                   const float* __restrict__ oscb,
                                                   float* __restrict__ u, float* __restrict__ v,
                                                   float* __restrict__ sc) {
  int row = blockIdx.x * 4 + (threadIdx.x >> 6);
  int lane = threadIdx.x & 63;
  float su = 0.f, sv = 0.f, ss = 0.f;
#pragma unroll
  for (int e = 0; e < 4; ++e) {
    int k = lane * 4 + e;
    float hv = bf2f(h2[row * 256 + k]);
    su += hv * o1wl[k];
    sv += hv * o1wr[k];
    ss += hv * oscw[k];
  }
  for (int o = 1; o < 64; o <<= 1) {
    su += __shfl_xor(su, o);
    sv += __shfl_xor(sv, o);
    ss += __shfl_xor(ss, o);
  }
  if (lane == 0) {
    u[row] = su;
    v[row] = sv;
    sc[row] = ss + oscb[0];
  }
}

__global__ __launch_bounds__(256) void aggv1_kernel(const unsigned long long* __restrict__ Awords,
                                                    const float* __restrict__ u,
                                                    const float* __restrict__ deg_inv,
                                                    const float* __restrict__ v,
                                                    const float* __restrict__ o1bl,
                                                    float* __restrict__ o1) {
  int row = blockIdx.x * 4 + (threadIdx.x >> 6);
  int lane = threadIdx.x & 63;
  float s = 0.f;
#pragma unroll
  for (int wi = 0; wi < 2; ++wi) {
    unsigned long long bits = Awords[row * 128 + wi * 64 + lane];
    int base = (wi * 64 + lane) * 64;
    while (bits) {
      int b = __ffsll(bits) - 1;
      s += u[base + b];
      bits &= bits - 1;
    }
  }
  for (int o = 1; o < 64; o <<= 1) s += __shfl_xor(s, o);
  if (lane == 0) o1[row] = fmaxf(s * deg_inv[row] + o1bl[0] + v[row], 0.f);
}

__global__ __launch_bounds__(256) void aggv2_kernel(const unsigned long long* __restrict__ Awords,
                                                    const float* __restrict__ o1,
                                                    const float* __restrict__ deg_inv,
                                                    const float* __restrict__ o2wl,
                                                    const float* __restrict__ o2bl,
                                                    const float* __restrict__ o2wr,
                                                    const float* __restrict__ sc,
                                                    float* __restrict__ out) {
  int row = blockIdx.x * 4 + (threadIdx.x >> 6);
  int lane = threadIdx.x & 63;
  float s = 0.f;
#pragma unroll
  for (int wi = 0; wi < 2; ++wi) {
    unsigned long long bits = Awords[row * 128 + wi * 64 + lane];
    int base = (wi * 64 + lane) * 64;
    while (bits) {
      int b = __ffsll(bits) - 1;
      s += o1[base + b];
      bits &= bits - 1;
    }
  }
  for (int o = 1; o < 64; o <<= 1) s += __shfl_xor(s, o);
  if (lane == 0) {
    float z = s * deg_inv[row] * o2wl[0] + o2bl[0] + o1[row] * o2wr[0] + sc[row];
    out[row] = 1.f / (1.f + expf(-z));
  }
}

// ---------------- launch ----------------
extern "C" void kernel_launch(void* const* d_in, const int* in_sizes, int n_in,
                              void* d_out, int out_size, void* d_ws, size_t ws_size,
                              hipStream_t stream) {
  (void)in_sizes; (void)n_in; (void)out_size;
  const float* x     = (const float*)d_in[0];
  const float* w_in  = (const float*)d_in[1];
  const float* b_in  = (const float*)d_in[2];
  const float* h1_wl = (const float*)d_in[3];
  const float* h1_bl = (const float*)d_in[4];
  const float* h1_wr = (const float*)d_in[5];
  const float* h2_wl = (const float*)d_in[6];
  const float* h2_bl = (const float*)d_in[7];
  const float* h2_wr = (const float*)d_in[8];
  const float* o1_wl = (const float*)d_in[9];
  const float* o1_bl = (const float*)d_in[10];
  const float* o1_wr = (const float*)d_in[11];
  const float* o2_wl = (const float*)d_in[12];
  const float* o2_bl = (const float*)d_in[13];
  const float* o2_wr = (const float*)d_in[14];
  const float* osc_w = (const float*)d_in[15];
  const float* osc_b = (const float*)d_in[16];
  float* out = (float*)d_out;

  char* ws = (char*)d_ws;
  size_t off = 0;
  auto alloc = [&](size_t bytes) -> char* {
    char* p = ws + off;
    off += (bytes + 255) & ~(size_t)255;
    return p;
  };
  short* xn    = (short*)alloc(8192 * 128 * 2);
  short* xb    = (short*)alloc(8192 * 128 * 2);
  short* w_inT = (short*)alloc(256 * 128 * 2);
  short* w1lT  = (short*)alloc(256 * 256 * 2);
  short* w1rT  = (short*)alloc(256 * 256 * 2);
  short* w2lT  = (short*)alloc(256 * 256 * 2);
  short* w2rT  = (short*)alloc(256 * 256 * 2);
  unsigned int* hist1 = (unsigned int*)alloc(1024 * 4);
  unsigned int* hist2 = (unsigned int*)alloc(8192 * 4);
  unsigned int* sel   = (unsigned int*)alloc(256);
  float* deg_inv = (float*)alloc(8192 * 4);
  float* ubuf  = (float*)alloc(8192 * 4);
  float* vbuf  = (float*)alloc(8192 * 4);
  float* scbuf = (float*)alloc(8192 * 4);
  float* o1buf = (float*)alloc(8192 * 4);
  unsigned long long* Awords = (unsigned long long*)alloc((size_t)8192 * 128 * 8);
  short* h0  = (short*)alloc((size_t)8192 * 256 * 2);
  short* h1  = (short*)alloc((size_t)8192 * 256 * 2);
  short* h2  = (short*)alloc((size_t)8192 * 256 * 2);
  short* hT  = (short*)alloc((size_t)8192 * 256 * 2);
  short* agg = (short*)alloc((size_t)8192 * 256 * 2);
  int nsplit = (ws_size >= off + 4 * (size_t)8192 * 256 * 4 + 4096) ? 4 : 2;
  float* partials = (float*)alloc((size_t)nsplit * 8192 * 256 * 4);
  const int ksplit = 8192 / nsplit;

  hipMemsetAsync(hist1, 0, (1024 + 8192) * 4, stream);
  prep_x_kernel<<<2048, 256, 0, stream>>>(x, xb, xn);
  prep_w_kernel<<<1152, 256, 0, stream>>>(w_in, h1_wl, h1_wr, h2_wl, h2_wr,
                                          w_inT, w1lT, w1rT, w2lT, w2rT);
  sim_kernel<0><<<NTRI / 4, 256, 0, stream>>>(xn, hist1, sel, nullptr);
  scan_kernel<1024, 0><<<1, 256, 0, stream>>>(hist1, sel);
  sim_kernel<1><<<NTRI / 4, 256, 0, stream>>>(xn, hist2, sel, nullptr);
  scan_kernel<8192, 1><<<1, 256, 0, stream>>>(hist2, sel);
  sim_kernel<2><<<NTRI / 4, 256, 0, stream>>>(xn, nullptr, sel, Awords);
  deg_kernel<<<2048, 256, 0, stream>>>(Awords, deg_inv);

  // h0 = relu(x @ w_in + b_in)
  lin_kernel<false, true, false><<<dim3(128, 4), 256, 0, stream>>>(
      xb, w_inT, 128, nullptr, nullptr, 0, b_in, nullptr, h0);
  // h1 = relu(agg(h0)@h1_wl + h1_bl + h0@h1_wr)
  transpose_kernel<<<dim3(128, 4), 256, 0, stream>>>(h0, hT);
  aggA_kernel<<<dim3(64, 2, nsplit), 256, 0, stream>>>(Awords, hT, partials, ksplit);
  combine_kernel<<<2048, 256, 0, stream>>>(partials, nsplit, deg_inv, agg);
  lin_kernel<true, true, false><<<dim3(128, 4), 256, 0, stream>>>(
      agg, w1lT, 256, h0, w1rT, 256, h1_bl, nullptr, h1);
  // h2 = relu(agg(h1)@h2_wl + h2_bl + h1@h2_wr + h0)
  transpose_kernel<<<dim3(128, 4), 256, 0, stream>>>(h1, hT);
  aggA_kernel<<<dim3(64, 2, nsplit), 256, 0, stream>>>(Awords, hT, partials, ksplit);
  combine_kernel<<<2048, 256, 0, stream>>>(partials, nsplit, deg_inv, agg);
  lin_kernel<true, true, true><<<dim3(128, 4), 256, 0, stream>>>(
      agg, w2lT, 256, h1, w2rT, 256, h2_bl, h0, h2);
  // output block
  vec3_kernel<<<2048, 256, 0, stream>>>(h2, o1_wl, o1_wr, osc_w, osc_b, ubuf, vbuf, scbuf);
  aggv1_kernel<<<2048, 256, 0, stream>>>(Awords, ubuf, deg_inv, vbuf, o1_bl, o1buf);
  aggv2_kernel<<<2048, 256, 0, stream>>>(Awords, o1buf, deg_inv, o2_wl, o2_bl, o2_wr, scbuf, out);
}

// Round 4
// 393.248 us; speedup vs baseline: 1.3255x; 1.1117x over previous
//
#include <hip/hip_runtime.h>

// GNN_79937931313503: dynamic-graph SAGE GNN on MI355X.
// R4: xn stored in MFMA-fragment-major layout (chunk = 64 lanes x 8 bf16 =
// 1KB contiguous per (row_group, kc)); sim fragment loads are now perfectly
// coalesced (1 segment vs 16). LDS histogram only instantiated for MODE 0.

typedef __attribute__((ext_vector_type(8))) short s8v;   // 8 x bf16 (4 VGPR)
typedef __attribute__((ext_vector_type(4))) short s4v;   // 4 x bf16
typedef __attribute__((ext_vector_type(4))) float f4v;   // MFMA C/D frag

__device__ __forceinline__ f4v MFMA(s8v a, s8v b, f4v c) {
  return __builtin_amdgcn_mfma_f32_16x16x32_bf16(a, b, c, 0, 0, 0);
}
__device__ __forceinline__ short f2bf(float f) {  // RNE float->bf16 bits
  unsigned u = __float_as_uint(f);
  return (short)((u + 0x7FFFu + ((u >> 16) & 1u)) >> 16);
}
__device__ __forceinline__ float bf2f(short s) {
  return __uint_as_float(((unsigned)(unsigned short)s) << 16);
}

// ---------------- prep_x: norms + xb (row-major) + xnF (fragment-major) ----
// Fragment-major: chunk (rg, kc) holds rows [rg*16, rg*16+16) x k [kc*32,
// kc*32+32) as 512 shorts: element (m, k) at lane=(k>>3)*16+m, e=k&7.
// One wave per row-group; lane m = lane&15 (row), g = lane>>4 (k-quad).
__global__ __launch_bounds__(256) void prep_x_kernel(const float* __restrict__ x,
                                                     short* __restrict__ xb,
                                                     short* __restrict__ xnF) {
  const int w = threadIdx.x >> 6, lane = threadIdx.x & 63;
  const int rg = blockIdx.x * 4 + w;
  const int m = lane & 15, g = lane >> 4;
  const int row = rg * 16 + m;
  float v[4][8];
  float ss = 0.f;
#pragma unroll
  for (int kc = 0; kc < 4; ++kc) {
    const float* src = x + row * 128 + kc * 32 + g * 8;
    float4 a = *(const float4*)src;
    float4 b = *(const float4*)(src + 4);
    v[kc][0] = a.x; v[kc][1] = a.y; v[kc][2] = a.z; v[kc][3] = a.w;
    v[kc][4] = b.x; v[kc][5] = b.y; v[kc][6] = b.z; v[kc][7] = b.w;
#pragma unroll
    for (int e = 0; e < 8; ++e) ss += v[kc][e] * v[kc][e];
  }
  ss += __shfl_xor(ss, 16);
  ss += __shfl_xor(ss, 32);
  float inv = 1.0f / fmaxf(sqrtf(ss), 1e-8f);
#pragma unroll
  for (int kc = 0; kc < 4; ++kc) {
    s8v raw, nrm;
#pragma unroll
    for (int e = 0; e < 8; ++e) {
      raw[e] = f2bf(v[kc][e]);
      nrm[e] = f2bf(v[kc][e] * inv);
    }
    *(s8v*)(xb + row * 128 + kc * 32 + g * 8) = raw;
    *(s8v*)(xnF + (rg * 4 + kc) * 512 + lane * 8) = nrm;  // coalesced 1KB
  }
}

__global__ __launch_bounds__(256) void prep_w_kernel(
    const float* __restrict__ w_in, const float* __restrict__ w1l,
    const float* __restrict__ w1r, const float* __restrict__ w2l,
    const float* __restrict__ w2r, short* __restrict__ w_inT,
    short* __restrict__ w1lT, short* __restrict__ w1rT,
    short* __restrict__ w2lT, short* __restrict__ w2rT) {
  int idx = blockIdx.x * 256 + threadIdx.x;
  if (idx >= 294912) return;
  if (idx < 32768) {                       // w_in [128][256] -> [256][128]
    int n = idx >> 7, k = idx & 127;
    w_inT[idx] = f2bf(w_in[k * 256 + n]);
  } else {                                 // 4x [256][256] transposed
    int j = idx - 32768;
    int m = j >> 16, r = j & 65535;
    int n = r >> 8, k = r & 255;
    const float* src = (m == 0) ? w1l : (m == 1) ? w1r : (m == 2) ? w2l : w2r;
    short* dst = (m == 0) ? w1lT : (m == 1) ? w1rT : (m == 2) ? w2lT : w2rT;
    dst[r] = f2bf(src[k * 256 + n]);
  }
}

// ---------------- sim: per-wave 64x64 tiles, upper triangle only ----------------
// Fragments loaded directly from xnF (coalesced). MODE 0: weighted 1024-bin
// histogram. MODE 1: refine within prefix. MODE 2: adjacency bitmask + mirror.
#define NT64 128
#define NTRI 8256  // 128*129/2
template <int MODE>
__global__ __launch_bounds__(256) void sim_kernel(
    const short* __restrict__ xnF, unsigned int* __restrict__ hist,
    unsigned int* __restrict__ sel, unsigned long long* __restrict__ Awords) {
  __shared__ unsigned int lh[MODE == 0 ? 4096 : 1];
  const int tid = threadIdx.x, w = tid >> 6, lane = tid & 63;
  if (MODE == 0) {
    for (int b = tid; b < 4096; b += 256) lh[b] = 0;
    __syncthreads();
  }
  int t = blockIdx.x * 4 + w;
  // invert triangular index: cum(r) = r*128 - r*(r-1)/2
  int r = (int)((257.0f - sqrtf((float)(257 * 257 - 8 * t))) * 0.5f);
  if (r < 0) r = 0;
  if (r > 127) r = 127;
  while (r < 127 && ((r + 1) * NT64 - (r + 1) * r / 2) <= t) ++r;
  while (r > 0 && (r * NT64 - r * (r - 1) / 2) > t) --r;
  const int c = r + (t - (r * NT64 - r * (r - 1) / 2));
  const int i0 = r * 64, j0 = c * 64;
  const bool diag = (r == c);

  f4v acc[4][4];
#pragma unroll
  for (int a = 0; a < 4; ++a)
#pragma unroll
    for (int b = 0; b < 4; ++b) acc[a][b] = (f4v){0.f, 0.f, 0.f, 0.f};

  const int rga = r * 4, rgb = c * 4;  // 16-row group bases of the 64-tiles
#pragma unroll
  for (int kc = 0; kc < 4; ++kc) {
    s8v af[4], bf[4];
#pragma unroll
    for (int mt = 0; mt < 4; ++mt)
      af[mt] = *(const s8v*)(xnF + ((rga + mt) * 4 + kc) * 512 + lane * 8);
#pragma unroll
    for (int nt = 0; nt < 4; ++nt)
      bf[nt] = *(const s8v*)(xnF + ((rgb + nt) * 4 + kc) * 512 + lane * 8);
#pragma unroll
    for (int mt = 0; mt < 4; ++mt)
#pragma unroll
      for (int nt = 0; nt < 4; ++nt) acc[mt][nt] = MFMA(af[mt], bf[nt], acc[mt][nt]);
  }

  if (MODE == 0) {
    unsigned wgt = diag ? 1u : 2u;
#pragma unroll
    for (int mt = 0; mt < 4; ++mt)
      for (int nt = 0; nt < 4; ++nt)
        for (int rr = 0; rr < 4; ++rr) {
          unsigned bits = __float_as_uint(fabsf(acc[mt][nt][rr]));
          unsigned bin = bits >> 20;
          if (bin > 1023u) bin = 1023u;
          atomicAdd(&lh[bin * 4 + (lane & 3)], wgt);
        }
    __syncthreads();
    for (int b = tid; b < 1024; b += 256) {
      unsigned s = lh[b * 4] + lh[b * 4 + 1] + lh[b * 4 + 2] + lh[b * 4 + 3];
      if (s) atomicAdd(&hist[b], s);
    }
  } else if (MODE == 1) {
    unsigned pref = sel[0];
    unsigned wgt = diag ? 1u : 2u;
#pragma unroll
    for (int mt = 0; mt < 4; ++mt)
      for (int nt = 0; nt < 4; ++nt)
        for (int rr = 0; rr < 4; ++rr) {
          unsigned bits = __float_as_uint(fabsf(acc[mt][nt][rr]));
          if ((bits >> 20) == pref) atomicAdd(&hist[(bits >> 7) & 0x1FFFu], wgt);
        }
  } else {
    float eps = __uint_as_float(sel[2]);
    unsigned long long myword = 0;  // lane j holds row (i0+j)'s bits [j0..j0+64)
#pragma unroll
    for (int mt = 0; mt < 4; ++mt)
#pragma unroll
      for (int rr = 0; rr < 4; ++rr) {
        unsigned long long b0 = __ballot(fabsf(acc[mt][0][rr]) >= eps);
        unsigned long long b1 = __ballot(fabsf(acc[mt][1][rr]) >= eps);
        unsigned long long b2 = __ballot(fabsf(acc[mt][2][rr]) >= eps);
        unsigned long long b3 = __ballot(fabsf(acc[mt][3][rr]) >= eps);
        if ((lane >> 4) == mt && (lane & 3) == rr) {
          int gj = (lane >> 2) & 3;
          myword = ((b0 >> (16 * gj)) & 0xFFFFull) |
                   (((b1 >> (16 * gj)) & 0xFFFFull) << 16) |
                   (((b2 >> (16 * gj)) & 0xFFFFull) << 32) |
                   (((b3 >> (16 * gj)) & 0xFFFFull) << 48);
        }
      }
    Awords[(size_t)(i0 + lane) * 128 + (j0 >> 6)] = myword;
    if (!diag) {  // mirrored tile via 64x64 bit transpose (ballot per column)
      unsigned long long tw = 0;
#pragma unroll
      for (int c2 = 0; c2 < 64; ++c2) {
        unsigned long long bc = __ballot((myword >> c2) & 1ull);
        if (lane == c2) tw = bc;
      }
      Awords[(size_t)(j0 + lane) * 128 + (i0 >> 6)] = tw;
    }
  }
}

// ---------------- histogram selection scan ----------------
template <int NB, int MODE>
__global__ __launch_bounds__(256) void scan_kernel(const unsigned int* __restrict__ hist,
                                                   unsigned int* __restrict__ sel) {
  __shared__ unsigned long long csum[256];
  const int t = threadIdx.x;
  const int PER = NB / 256;
  unsigned int vals[NB / 256];
  unsigned long long s = 0;
  for (int i = 0; i < PER; ++i) {
    vals[i] = hist[t * PER + i];
    s += vals[i];
  }
  csum[t] = s;
  __syncthreads();
  for (int o = 1; o < 256; o <<= 1) {
    unsigned long long prev = (t >= o) ? csum[t - o] : 0ull;
    __syncthreads();
    csum[t] += prev;
    __syncthreads();
  }
  unsigned long long K = (MODE == 0) ? 63753421ull : (unsigned long long)sel[1];
  unsigned long long inc = csum[t], exc = inc - s;
  if (K > exc && K <= inc) {
    unsigned long long c = exc;
    for (int i = 0; i < PER; ++i) {
      c += vals[i];
      if (c >= K) {
        if (MODE == 0) {
          sel[0] = (unsigned)(t * PER + i);
          sel[1] = (unsigned)(K - (c - vals[i]));
        } else {
          sel[2] = (sel[0] << 20) | ((unsigned)(t * PER + i) << 7);
        }
        break;
      }
    }
  }
}

// ---------------- degree ----------------
__global__ __launch_bounds__(256) void deg_kernel(const unsigned long long* __restrict__ Awords,
                                                  float* __restrict__ deg_inv) {
  int row = blockIdx.x * 4 + (threadIdx.x >> 6);
  int lane = threadIdx.x & 63;
  int c = __popcll(Awords[row * 128 + lane]) + __popcll(Awords[row * 128 + 64 + lane]);
  for (int o = 32; o; o >>= 1) c += __shfl_down(c, o);
  if (lane == 0) deg_inv[row] = 1.0f / (float)max(c, 1);
}

// ---------------- small NT linears ----------------
template <bool TWO, bool RELU, bool RES>
__global__ __launch_bounds__(256) void lin_kernel(
    const short* __restrict__ A1, const short* __restrict__ B1, int K1,
    const short* __restrict__ A2, const short* __restrict__ B2, int K2,
    const float* __restrict__ bias, const short* __restrict__ res,
    short* __restrict__ out) {
  const int i0 = blockIdx.x * 64, n0 = blockIdx.y * 64;
  const int tid = threadIdx.x, w = tid >> 6, lane = tid & 63;
  const int wy = (w >> 1) * 32, wx = (w & 1) * 32;
  const int lr = lane & 15, lk = (lane >> 4) * 8;
  f4v acc[2][2];
#pragma unroll
  for (int a = 0; a < 2; ++a)
#pragma unroll
    for (int b = 0; b < 2; ++b) acc[a][b] = (f4v){0.f, 0.f, 0.f, 0.f};

  for (int kc = 0; kc < K1; kc += 32) {
    s8v a0 = *(const s8v*)(A1 + (i0 + wy + lr) * K1 + kc + lk);
    s8v a1 = *(const s8v*)(A1 + (i0 + wy + 16 + lr) * K1 + kc + lk);
    s8v b0 = *(const s8v*)(B1 + (n0 + wx + lr) * K1 + kc + lk);
    s8v b1 = *(const s8v*)(B1 + (n0 + wx + 16 + lr) * K1 + kc + lk);
    acc[0][0] = MFMA(a0, b0, acc[0][0]);
    acc[0][1] = MFMA(a0, b1, acc[0][1]);
    acc[1][0] = MFMA(a1, b0, acc[1][0]);
    acc[1][1] = MFMA(a1, b1, acc[1][1]);
  }
  if constexpr (TWO) {
    for (int kc = 0; kc < K2; kc += 32) {
      s8v a0 = *(const s8v*)(A2 + (i0 + wy + lr) * K2 + kc + lk);
      s8v a1 = *(const s8v*)(A2 + (i0 + wy + 16 + lr) * K2 + kc + lk);
      s8v b0 = *(const s8v*)(B2 + (n0 + wx + lr) * K2 + kc + lk);
      s8v b1 = *(const s8v*)(B2 + (n0 + wx + 16 + lr) * K2 + kc + lk);
      acc[0][0] = MFMA(a0, b0, acc[0][0]);
      acc[0][1] = MFMA(a0, b1, acc[0][1]);
      acc[1][0] = MFMA(a1, b0, acc[1][0]);
      acc[1][1] = MFMA(a1, b1, acc[1][1]);
    }
  }
#pragma unroll
  for (int mt = 0; mt < 2; ++mt)
#pragma unroll
    for (int nt = 0; nt < 2; ++nt)
#pragma unroll
      for (int rr = 0; rr < 4; ++rr) {
        int row = i0 + wy + mt * 16 + (lane >> 4) * 4 + rr;
        int col = n0 + wx + nt * 16 + (lane & 15);
        float v = acc[mt][nt][rr] + bias[col];
        if constexpr (RES) v += bf2f(res[row * 256 + col]);
        if constexpr (RELU) v = fmaxf(v, 0.f);
        out[row * 256 + col] = f2bf(v);
      }
}

// ---------------- transpose [8192][256] -> [256][8192] ----------------
__global__ __launch_bounds__(256) void transpose_kernel(const short* __restrict__ in,
                                                        short* __restrict__ out) {
  __shared__ __align__(16) short T[64][72];
  const int i0 = blockIdx.x * 64, f0 = blockIdx.y * 64;
  const int t = threadIdx.x;
  const int r = t >> 2, c0 = (t & 3) * 16;
  s8v v0 = *(const s8v*)(in + (i0 + r) * 256 + f0 + c0);
  s8v v1 = *(const s8v*)(in + (i0 + r) * 256 + f0 + c0 + 8);
#pragma unroll
  for (int e = 0; e < 8; ++e) {
    T[c0 + e][r] = v0[e];
    T[c0 + 8 + e][r] = v1[e];
  }
  __syncthreads();
  s8v o0, o1;
#pragma unroll
  for (int e = 0; e < 8; ++e) {
    o0[e] = T[r][c0 + e];
    o1[e] = T[r][c0 + 8 + e];
  }
  *(s8v*)(out + (f0 + r) * 8192 + i0 + c0) = o0;
  *(s8v*)(out + (f0 + r) * 8192 + i0 + c0 + 8) = o1;
}

// ---------------- aggA: partial[z] = A[:, kslice] @ h[kslice, :] ----------------
__global__ __launch_bounds__(256) void aggA_kernel(const unsigned long long* __restrict__ Awords,
                                                   const short* __restrict__ hT,
                                                   float* __restrict__ partial,
                                                   int ksplit) {
  __shared__ __align__(16) short As[128 * 128];
  __shared__ __align__(16) short Bs[128 * 128];
  const int i0 = blockIdx.x * 128;  // node rows
  const int f0 = blockIdx.y * 128;  // features
  const int k0 = blockIdx.z * ksplit;
  const int tid = threadIdx.x, w = tid >> 6, lane = tid & 63;
  const int wy = (w >> 1) * 64, wx = (w & 1) * 64;
  const int lr = lane & 15, g = lane >> 4;
  const int srow = tid >> 1, shalf = tid & 1;

  f4v acc[4][4];
#pragma unroll
  for (int a = 0; a < 4; ++a)
#pragma unroll
    for (int b = 0; b < 4; ++b) acc[a][b] = (f4v){0.f, 0.f, 0.f, 0.f};

  for (int kb = k0; kb < k0 + ksplit; kb += 128) {
    __syncthreads();
    {  // A: expand 128 rows x 128 bits -> bf16
      unsigned long long wv = Awords[(size_t)(i0 + srow) * 128 + (kb >> 6) + shalf];
#pragma unroll
      for (int j = 0; j < 8; ++j) {
        int unit = shalf * 8 + j;
        unsigned byte = (unsigned)(wv >> (j * 8)) & 0xFFu;
        s8v v;
#pragma unroll
        for (int e = 0; e < 8; ++e) v[e] = ((byte >> e) & 1u) ? (short)0x3F80 : (short)0;
        *(s8v*)&As[srow * 128 + ((unit ^ (srow & 7)) << 3)] = v;
      }
    }
    {  // B: 128 feats x 128 k from hT
      const short* src = hT + (size_t)(f0 + srow) * 8192 + kb + shalf * 64;
#pragma unroll
      for (int j = 0; j < 8; ++j) {
        s8v v = *(const s8v*)(src + j * 8);
        int unit = shalf * 8 + j;
        *(s8v*)&Bs[srow * 128 + ((unit ^ (srow & 7)) << 3)] = v;
      }
    }
    __syncthreads();
#pragma unroll
    for (int kc = 0; kc < 4; ++kc) {
      s8v af[4], bf[4];
#pragma unroll
      for (int mt = 0; mt < 4; ++mt) {
        int row = wy + mt * 16 + lr;
        af[mt] = *(const s8v*)&As[row * 128 + (((kc * 4 + g) ^ (row & 7)) << 3)];
      }
#pragma unroll
      for (int nt = 0; nt < 4; ++nt) {
        int col = wx + nt * 16 + lr;
        bf[nt] = *(const s8v*)&Bs[col * 128 + (((kc * 4 + g) ^ (col & 7)) << 3)];
      }
#pragma unroll
      for (int mt = 0; mt < 4; ++mt)
#pragma unroll
        for (int nt = 0; nt < 4; ++nt) acc[mt][nt] = MFMA(af[mt], bf[nt], acc[mt][nt]);
    }
  }
  float* P = partial + (size_t)blockIdx.z * (8192 * 256);
#pragma unroll
  for (int mt = 0; mt < 4; ++mt)
#pragma unroll
    for (int nt = 0; nt < 4; ++nt)
#pragma unroll
      for (int rr = 0; rr < 4; ++rr) {
        int row = i0 + wy + mt * 16 + g * 4 + rr;
        int col = f0 + wx + nt * 16 + lr;
        P[(size_t)row * 256 + col] = acc[mt][nt][rr];
      }
}

// combine: agg = bf16(sum_z partial[z] * deg_inv[row])
__global__ __launch_bounds__(256) void combine_kernel(const float* __restrict__ p, int nsplit,
                                                      const float* __restrict__ deg_inv,
                                                      short* __restrict__ agg) {
  int idx = blockIdx.x * 256 + threadIdx.x;  // group of 4 elems
  const float4* pv = (const float4*)p;
  float4 s = pv[idx];
  for (int k = 1; k < nsplit; ++k) {
    float4 v = pv[(size_t)k * 524288 + idx];
    s.x += v.x; s.y += v.y; s.z += v.z; s.w += v.w;
  }
  float di = deg_inv[idx >> 6];
  s4v o;
  o[0] = f2bf(s.x * di); o[1] = f2bf(s.y * di);
  o[2] = f2bf(s.z * di); o[3] = f2bf(s.w * di);
  *(s4v*)&agg[idx * 4] = o;
}

// ---------------- tail ----------------
__global__ __launch_bounds__(256) void vec3_kernel(const short* __restrict__ h2,
                                                   const float* __restrict__ o1wl,
                                                   const float* __restrict__ o1wr,
                                                   const float* __restrict__ oscw,
                                                   const float* __restrict__ oscb,
                                                   float* __restrict__ u, float* __restrict__ v,
                                                   float* __restrict__ sc) {
  int row = blockIdx.x * 4 + (threadIdx.x >> 6);
  int lane = threadIdx.x & 63;
  float su = 0.f, sv = 0.f, ss = 0.f;
#pragma unroll
  for (int e = 0; e < 4; ++e) {
    int k = lane * 4 + e;
    float hv = bf2f(h2[row * 256 + k]);
    su += hv * o1wl[k];
    sv += hv * o1wr[k];
    ss += hv * oscw[k];
  }
  for (int o = 1; o < 64; o <<= 1) {
    su += __shfl_xor(su, o);
    sv += __shfl_xor(sv, o);
    ss += __shfl_xor(ss, o);
  }
  if (lane == 0) {
    u[row] = su;
    v[row] = sv;
    sc[row] = ss + oscb[0];
  }
}

__global__ __launch_bounds__(256) void aggv1_kernel(const unsigned long long* __restrict__ Awords,
                                                    const float* __restrict__ u,
                                                    const float* __restrict__ deg_inv,
                                                    const float* __restrict__ v,
                                                    const float* __restrict__ o1bl,
                                                    float* __restrict__ o1) {
  int row = blockIdx.x * 4 + (threadIdx.x >> 6);
  int lane = threadIdx.x & 63;
  float s = 0.f;
#pragma unroll
  for (int wi = 0; wi < 2; ++wi) {
    unsigned long long bits = Awords[row * 128 + wi * 64 + lane];
    int base = (wi * 64 + lane) * 64;
    while (bits) {
      int b = __ffsll(bits) - 1;
      s += u[base + b];
      bits &= bits - 1;
    }
  }
  for (int o = 1; o < 64; o <<= 1) s += __shfl_xor(s, o);
  if (lane == 0) o1[row] = fmaxf(s * deg_inv[row] + o1bl[0] + v[row], 0.f);
}

__global__ __launch_bounds__(256) void aggv2_kernel(const unsigned long long* __restrict__ Awords,
                                                    const float* __restrict__ o1,
                                                    const float* __restrict__ deg_inv,
                                                    const float* __restrict__ o2wl,
                                                    const float* __restrict__ o2bl,
                                                    const float* __restrict__ o2wr,
                                                    const float* __restrict__ sc,
                                                    float* __restrict__ out) {
  int row = blockIdx.x * 4 + (threadIdx.x >> 6);
  int lane = threadIdx.x & 63;
  float s = 0.f;
#pragma unroll
  for (int wi = 0; wi < 2; ++wi) {
    unsigned long long bits = Awords[row * 128 + wi * 64 + lane];
    int base = (wi * 64 + lane) * 64;
    while (bits) {
      int b = __ffsll(bits) - 1;
      s += o1[base + b];
      bits &= bits - 1;
    }
  }
  for (int o = 1; o < 64; o <<= 1) s += __shfl_xor(s, o);
  if (lane == 0) {
    float z = s * deg_inv[row] * o2wl[0] + o2bl[0] + o1[row] * o2wr[0] + sc[row];
    out[row] = 1.f / (1.f + expf(-z));
  }
}

// ---------------- launch ----------------
extern "C" void kernel_launch(void* const* d_in, const int* in_sizes, int n_in,
                              void* d_out, int out_size, void* d_ws, size_t ws_size,
                              hipStream_t stream) {
  (void)in_sizes; (void)n_in; (void)out_size;
  const float* x     = (const float*)d_in[0];
  const float* w_in  = (const float*)d_in[1];
  const float* b_in  = (const float*)d_in[2];
  const float* h1_wl = (const float*)d_in[3];
  const float* h1_bl = (const float*)d_in[4];
  const float* h1_wr = (const float*)d_in[5];
  const float* h2_wl = (const float*)d_in[6];
  const float* h2_bl = (const float*)d_in[7];
  const float* h2_wr = (const float*)d_in[8];
  const float* o1_wl = (const float*)d_in[9];
  const float* o1_bl = (const float*)d_in[10];
  const float* o1_wr = (const float*)d_in[11];
  const float* o2_wl = (const float*)d_in[12];
  const float* o2_bl = (const float*)d_in[13];
  const float* o2_wr = (const float*)d_in[14];
  const float* osc_w = (const float*)d_in[15];
  const float* osc_b = (const float*)d_in[16];
  float* out = (float*)d_out;

  char* ws = (char*)d_ws;
  size_t off = 0;
  auto alloc = [&](size_t bytes) -> char* {
    char* p = ws + off;
    off += (bytes + 255) & ~(size_t)255;
    return p;
  };
  short* xnF   = (short*)alloc(8192 * 128 * 2);  // fragment-major normalized x
  short* xb    = (short*)alloc(8192 * 128 * 2);
  short* w_inT = (short*)alloc(256 * 128 * 2);
  short* w1lT  = (short*)alloc(256 * 256 * 2);
  short* w1rT  = (short*)alloc(256 * 256 * 2);
  short* w2lT  = (short*)alloc(256 * 256 * 2);
  short* w2rT  = (short*)alloc(256 * 256 * 2);
  unsigned int* hist1 = (unsigned int*)alloc(1024 * 4);
  unsigned int* hist2 = (unsigned int*)alloc(8192 * 4);
  unsigned int* sel   = (unsigned int*)alloc(256);
  float* deg_inv = (float*)alloc(8192 * 4);
  float* ubuf  = (float*)alloc(8192 * 4);
  float* vbuf  = (float*)alloc(8192 * 4);
  float* scbuf = (float*)alloc(8192 * 4);
  float* o1buf = (float*)alloc(8192 * 4);
  unsigned long long* Awords = (unsigned long long*)alloc((size_t)8192 * 128 * 8);
  short* h0  = (short*)alloc((size_t)8192 * 256 * 2);
  short* h1  = (short*)alloc((size_t)8192 * 256 * 2);
  short* h2  = (short*)alloc((size_t)8192 * 256 * 2);
  short* hT  = (short*)alloc((size_t)8192 * 256 * 2);
  short* agg = (short*)alloc((size_t)8192 * 256 * 2);
  int nsplit = (ws_size >= off + 4 * (size_t)8192 * 256 * 4 + 4096) ? 4 : 2;
  float* partials = (float*)alloc((size_t)nsplit * 8192 * 256 * 4);
  const int ksplit = 8192 / nsplit;

  hipMemsetAsync(hist1, 0, (1024 + 8192) * 4, stream);
  prep_x_kernel<<<128, 256, 0, stream>>>(x, xb, xnF);
  prep_w_kernel<<<1152, 256, 0, stream>>>(w_in, h1_wl, h1_wr, h2_wl, h2_wr,
                                          w_inT, w1lT, w1rT, w2lT, w2rT);
  sim_kernel<0><<<NTRI / 4, 256, 0, stream>>>(xnF, hist1, sel, nullptr);
  scan_kernel<1024, 0><<<1, 256, 0, stream>>>(hist1, sel);
  sim_kernel<1><<<NTRI / 4, 256, 0, stream>>>(xnF, hist2, sel, nullptr);
  scan_kernel<8192, 1><<<1, 256, 0, stream>>>(hist2, sel);
  sim_kernel<2><<<NTRI / 4, 256, 0, stream>>>(xnF, nullptr, sel, Awords);
  deg_kernel<<<2048, 256, 0, stream>>>(Awords, deg_inv);

  // h0 = relu(x @ w_in + b_in)
  lin_kernel<false, true, false><<<dim3(128, 4), 256, 0, stream>>>(
      xb, w_inT, 128, nullptr, nullptr, 0, b_in, nullptr, h0);
  // h1 = relu(agg(h0)@h1_wl + h1_bl + h0@h1_wr)
  transpose_kernel<<<dim3(128, 4), 256, 0, stream>>>(h0, hT);
  aggA_kernel<<<dim3(64, 2, nsplit), 256, 0, stream>>>(Awords, hT, partials, ksplit);
  combine_kernel<<<2048, 256, 0, stream>>>(partials, nsplit, deg_inv, agg);
  lin_kernel<true, true, false><<<dim3(128, 4), 256, 0, stream>>>(
      agg, w1lT, 256, h0, w1rT, 256, h1_bl, nullptr, h1);
  // h2 = relu(agg(h1)@h2_wl + h2_bl + h1@h2_wr + h0)
  transpose_kernel<<<dim3(128, 4), 256, 0, stream>>>(h1, hT);
  aggA_kernel<<<dim3(64, 2, nsplit), 256, 0, stream>>>(Awords, hT, partials, ksplit);
  combine_kernel<<<2048, 256, 0, stream>>>(partials, nsplit, deg_inv, agg);
  lin_kernel<true, true, true><<<dim3(128, 4), 256, 0, stream>>>(
      agg, w2lT, 256, h1, w2rT, 256, h2_bl, h0, h2);
  // output block
  vec3_kernel<<<2048, 256, 0, stream>>>(h2, o1_wl, o1_wr, osc_w, osc_b, ubuf, vbuf, scbuf);
  aggv1_kernel<<<2048, 256, 0, stream>>>(Awords, ubuf, deg_inv, vbuf, o1_bl, o1buf);
  aggv2_kernel<<<2048, 256, 0, stream>>>(Awords, o1buf, deg_inv, o2_wl, o2_bl, o2_wr, scbuf, out);
}

// Round 5
// 378.821 us; speedup vs baseline: 1.3760x; 1.0381x over previous
//
#include <hip/hip_runtime.h>

// GNN_79937931313503: dynamic-graph SAGE GNN on MI355X.
// R5: aggA made LDS-free — B fragments loaded coalesced from fragment-major
// hF; A bits loaded from column-major AT (written by sim MODE 2) and expanded
// to bf16 fragments in VGPRs. Zero barriers in the aggA K-loop.

typedef __attribute__((ext_vector_type(8))) short s8v;   // 8 x bf16 (4 VGPR)
typedef __attribute__((ext_vector_type(4))) short s4v;   // 4 x bf16
typedef __attribute__((ext_vector_type(4))) float f4v;   // MFMA C/D frag

__device__ __forceinline__ f4v MFMA(s8v a, s8v b, f4v c) {
  return __builtin_amdgcn_mfma_f32_16x16x32_bf16(a, b, c, 0, 0, 0);
}
__device__ __forceinline__ short f2bf(float f) {  // RNE float->bf16 bits
  unsigned u = __float_as_uint(f);
  return (short)((u + 0x7FFFu + ((u >> 16) & 1u)) >> 16);
}
__device__ __forceinline__ float bf2f(short s) {
  return __uint_as_float(((unsigned)(unsigned short)s) << 16);
}

// ---------------- prep_x: norms + xb (row-major) + xnF (fragment-major) ----
__global__ __launch_bounds__(256) void prep_x_kernel(const float* __restrict__ x,
                                                     short* __restrict__ xb,
                                                     short* __restrict__ xnF) {
  const int w = threadIdx.x >> 6, lane = threadIdx.x & 63;
  const int rg = blockIdx.x * 4 + w;
  const int m = lane & 15, g = lane >> 4;
  const int row = rg * 16 + m;
  float v[4][8];
  float ss = 0.f;
#pragma unroll
  for (int kc = 0; kc < 4; ++kc) {
    const float* src = x + row * 128 + kc * 32 + g * 8;
    float4 a = *(const float4*)src;
    float4 b = *(const float4*)(src + 4);
    v[kc][0] = a.x; v[kc][1] = a.y; v[kc][2] = a.z; v[kc][3] = a.w;
    v[kc][4] = b.x; v[kc][5] = b.y; v[kc][6] = b.z; v[kc][7] = b.w;
#pragma unroll
    for (int e = 0; e < 8; ++e) ss += v[kc][e] * v[kc][e];
  }
  ss += __shfl_xor(ss, 16);
  ss += __shfl_xor(ss, 32);
  float inv = 1.0f / fmaxf(sqrtf(ss), 1e-8f);
#pragma unroll
  for (int kc = 0; kc < 4; ++kc) {
    s8v raw, nrm;
#pragma unroll
    for (int e = 0; e < 8; ++e) {
      raw[e] = f2bf(v[kc][e]);
      nrm[e] = f2bf(v[kc][e] * inv);
    }
    *(s8v*)(xb + row * 128 + kc * 32 + g * 8) = raw;
    *(s8v*)(xnF + (rg * 4 + kc) * 512 + lane * 8) = nrm;  // coalesced 1KB
  }
}

__global__ __launch_bounds__(256) void prep_w_kernel(
    const float* __restrict__ w_in, const float* __restrict__ w1l,
    const float* __restrict__ w1r, const float* __restrict__ w2l,
    const float* __restrict__ w2r, short* __restrict__ w_inT,
    short* __restrict__ w1lT, short* __restrict__ w1rT,
    short* __restrict__ w2lT, short* __restrict__ w2rT) {
  int idx = blockIdx.x * 256 + threadIdx.x;
  if (idx >= 294912) return;
  if (idx < 32768) {                       // w_in [128][256] -> [256][128]
    int n = idx >> 7, k = idx & 127;
    w_inT[idx] = f2bf(w_in[k * 256 + n]);
  } else {                                 // 4x [256][256] transposed
    int j = idx - 32768;
    int m = j >> 16, r = j & 65535;
    int n = r >> 8, k = r & 255;
    const float* src = (m == 0) ? w1l : (m == 1) ? w1r : (m == 2) ? w2l : w2r;
    short* dst = (m == 0) ? w1lT : (m == 1) ? w1rT : (m == 2) ? w2lT : w2rT;
    dst[r] = f2bf(src[k * 256 + n]);
  }
}

// ---------------- sim: per-wave 64x64 tiles, upper triangle only ----------------
#define NT64 128
#define NTRI 8256  // 128*129/2
template <int MODE>
__global__ __launch_bounds__(256) void sim_kernel(
    const short* __restrict__ xnF, unsigned int* __restrict__ hist,
    unsigned int* __restrict__ sel, unsigned long long* __restrict__ Awords,
    unsigned long long* __restrict__ AT) {
  __shared__ unsigned int lh[MODE == 0 ? 4096 : 1];
  const int tid = threadIdx.x, w = tid >> 6, lane = tid & 63;
  if (MODE == 0) {
    for (int b = tid; b < 4096; b += 256) lh[b] = 0;
    __syncthreads();
  }
  int t = blockIdx.x * 4 + w;
  int r = (int)((257.0f - sqrtf((float)(257 * 257 - 8 * t))) * 0.5f);
  if (r < 0) r = 0;
  if (r > 127) r = 127;
  while (r < 127 && ((r + 1) * NT64 - (r + 1) * r / 2) <= t) ++r;
  while (r > 0 && (r * NT64 - r * (r - 1) / 2) > t) --r;
  const int c = r + (t - (r * NT64 - r * (r - 1) / 2));
  const int i0 = r * 64, j0 = c * 64;
  const bool diag = (r == c);

  f4v acc[4][4];
#pragma unroll
  for (int a = 0; a < 4; ++a)
#pragma unroll
    for (int b = 0; b < 4; ++b) acc[a][b] = (f4v){0.f, 0.f, 0.f, 0.f};

  const int rga = r * 4, rgb = c * 4;
#pragma unroll
  for (int kc = 0; kc < 4; ++kc) {
    s8v af[4], bf[4];
#pragma unroll
    for (int mt = 0; mt < 4; ++mt)
      af[mt] = *(const s8v*)(xnF + ((rga + mt) * 4 + kc) * 512 + lane * 8);
#pragma unroll
    for (int nt = 0; nt < 4; ++nt)
      bf[nt] = *(const s8v*)(xnF + ((rgb + nt) * 4 + kc) * 512 + lane * 8);
#pragma unroll
    for (int mt = 0; mt < 4; ++mt)
#pragma unroll
      for (int nt = 0; nt < 4; ++nt) acc[mt][nt] = MFMA(af[mt], bf[nt], acc[mt][nt]);
  }

  if (MODE == 0) {
    unsigned wgt = diag ? 1u : 2u;
#pragma unroll
    for (int mt = 0; mt < 4; ++mt)
      for (int nt = 0; nt < 4; ++nt)
        for (int rr = 0; rr < 4; ++rr) {
          unsigned bits = __float_as_uint(fabsf(acc[mt][nt][rr]));
          unsigned bin = bits >> 20;
          if (bin > 1023u) bin = 1023u;
          atomicAdd(&lh[bin * 4 + (lane & 3)], wgt);
        }
    __syncthreads();
    for (int b = tid; b < 1024; b += 256) {
      unsigned s = lh[b * 4] + lh[b * 4 + 1] + lh[b * 4 + 2] + lh[b * 4 + 3];
      if (s) atomicAdd(&hist[b], s);
    }
  } else if (MODE == 1) {
    unsigned pref = sel[0];
    unsigned wgt = diag ? 1u : 2u;
#pragma unroll
    for (int mt = 0; mt < 4; ++mt)
      for (int nt = 0; nt < 4; ++nt)
        for (int rr = 0; rr < 4; ++rr) {
          unsigned bits = __float_as_uint(fabsf(acc[mt][nt][rr]));
          if ((bits >> 20) == pref) atomicAdd(&hist[(bits >> 7) & 0x1FFFu], wgt);
        }
  } else {
    float eps = __uint_as_float(sel[2]);
    unsigned long long myword = 0;  // lane j holds row (i0+j)'s bits [j0..j0+64)
#pragma unroll
    for (int mt = 0; mt < 4; ++mt)
#pragma unroll
      for (int rr = 0; rr < 4; ++rr) {
        unsigned long long b0 = __ballot(fabsf(acc[mt][0][rr]) >= eps);
        unsigned long long b1 = __ballot(fabsf(acc[mt][1][rr]) >= eps);
        unsigned long long b2 = __ballot(fabsf(acc[mt][2][rr]) >= eps);
        unsigned long long b3 = __ballot(fabsf(acc[mt][3][rr]) >= eps);
        if ((lane >> 4) == mt && (lane & 3) == rr) {
          int gj = (lane >> 2) & 3;
          myword = ((b0 >> (16 * gj)) & 0xFFFFull) |
                   (((b1 >> (16 * gj)) & 0xFFFFull) << 16) |
                   (((b2 >> (16 * gj)) & 0xFFFFull) << 32) |
                   (((b3 >> (16 * gj)) & 0xFFFFull) << 48);
        }
      }
    Awords[(size_t)(i0 + lane) * 128 + (j0 >> 6)] = myword;
    AT[(size_t)(j0 >> 6) * 8192 + i0 + lane] = myword;
    if (!diag) {  // mirrored tile via 64x64 bit transpose (ballot per column)
      unsigned long long tw = 0;
#pragma unroll
      for (int c2 = 0; c2 < 64; ++c2) {
        unsigned long long bc = __ballot((myword >> c2) & 1ull);
        if (lane == c2) tw = bc;
      }
      Awords[(size_t)(j0 + lane) * 128 + (i0 >> 6)] = tw;
      AT[(size_t)(i0 >> 6) * 8192 + j0 + lane] = tw;
    }
  }
}

// ---------------- histogram selection scan ----------------
template <int NB, int MODE>
__global__ __launch_bounds__(256) void scan_kernel(const unsigned int* __restrict__ hist,
                                                   unsigned int* __restrict__ sel) {
  __shared__ unsigned long long csum[256];
  const int t = threadIdx.x;
  const int PER = NB / 256;
  unsigned int vals[NB / 256];
  unsigned long long s = 0;
  for (int i = 0; i < PER; ++i) {
    vals[i] = hist[t * PER + i];
    s += vals[i];
  }
  csum[t] = s;
  __syncthreads();
  for (int o = 1; o < 256; o <<= 1) {
    unsigned long long prev = (t >= o) ? csum[t - o] : 0ull;
    __syncthreads();
    csum[t] += prev;
    __syncthreads();
  }
  unsigned long long K = (MODE == 0) ? 63753421ull : (unsigned long long)sel[1];
  unsigned long long inc = csum[t], exc = inc - s;
  if (K > exc && K <= inc) {
    unsigned long long c = exc;
    for (int i = 0; i < PER; ++i) {
      c += vals[i];
      if (c >= K) {
        if (MODE == 0) {
          sel[0] = (unsigned)(t * PER + i);
          sel[1] = (unsigned)(K - (c - vals[i]));
        } else {
          sel[2] = (sel[0] << 20) | ((unsigned)(t * PER + i) << 7);
        }
        break;
      }
    }
  }
}

// ---------------- degree ----------------
__global__ __launch_bounds__(256) void deg_kernel(const unsigned long long* __restrict__ Awords,
                                                  float* __restrict__ deg_inv) {
  int row = blockIdx.x * 4 + (threadIdx.x >> 6);
  int lane = threadIdx.x & 63;
  int c = __popcll(Awords[row * 128 + lane]) + __popcll(Awords[row * 128 + 64 + lane]);
  for (int o = 32; o; o >>= 1) c += __shfl_down(c, o);
  if (lane == 0) deg_inv[row] = 1.0f / (float)max(c, 1);
}

// ---------------- small NT linears ----------------
template <bool TWO, bool RELU, bool RES>
__global__ __launch_bounds__(256) void lin_kernel(
    const short* __restrict__ A1, const short* __restrict__ B1, int K1,
    const short* __restrict__ A2, const short* __restrict__ B2, int K2,
    const float* __restrict__ bias, const short* __restrict__ res,
    short* __restrict__ out) {
  const int i0 = blockIdx.x * 64, n0 = blockIdx.y * 64;
  const int tid = threadIdx.x, w = tid >> 6, lane = tid & 63;
  const int wy = (w >> 1) * 32, wx = (w & 1) * 32;
  const int lr = lane & 15, lk = (lane >> 4) * 8;
  f4v acc[2][2];
#pragma unroll
  for (int a = 0; a < 2; ++a)
#pragma unroll
    for (int b = 0; b < 2; ++b) acc[a][b] = (f4v){0.f, 0.f, 0.f, 0.f};

  for (int kc = 0; kc < K1; kc += 32) {
    s8v a0 = *(const s8v*)(A1 + (i0 + wy + lr) * K1 + kc + lk);
    s8v a1 = *(const s8v*)(A1 + (i0 + wy + 16 + lr) * K1 + kc + lk);
    s8v b0 = *(const s8v*)(B1 + (n0 + wx + lr) * K1 + kc + lk);
    s8v b1 = *(const s8v*)(B1 + (n0 + wx + 16 + lr) * K1 + kc + lk);
    acc[0][0] = MFMA(a0, b0, acc[0][0]);
    acc[0][1] = MFMA(a0, b1, acc[0][1]);
    acc[1][0] = MFMA(a1, b0, acc[1][0]);
    acc[1][1] = MFMA(a1, b1, acc[1][1]);
  }
  if constexpr (TWO) {
    for (int kc = 0; kc < K2; kc += 32) {
      s8v a0 = *(const s8v*)(A2 + (i0 + wy + lr) * K2 + kc + lk);
      s8v a1 = *(const s8v*)(A2 + (i0 + wy + 16 + lr) * K2 + kc + lk);
      s8v b0 = *(const s8v*)(B2 + (n0 + wx + lr) * K2 + kc + lk);
      s8v b1 = *(const s8v*)(B2 + (n0 + wx + 16 + lr) * K2 + kc + lk);
      acc[0][0] = MFMA(a0, b0, acc[0][0]);
      acc[0][1] = MFMA(a0, b1, acc[0][1]);
      acc[1][0] = MFMA(a1, b0, acc[1][0]);
      acc[1][1] = MFMA(a1, b1, acc[1][1]);
    }
  }
#pragma unroll
  for (int mt = 0; mt < 2; ++mt)
#pragma unroll
    for (int nt = 0; nt < 2; ++nt)
#pragma unroll
      for (int rr = 0; rr < 4; ++rr) {
        int row = i0 + wy + mt * 16 + (lane >> 4) * 4 + rr;
        int col = n0 + wx + nt * 16 + (lane & 15);
        float v = acc[mt][nt][rr] + bias[col];
        if constexpr (RES) v += bf2f(res[row * 256 + col]);
        if constexpr (RELU) v = fmaxf(v, 0.f);
        out[row * 256 + col] = f2bf(v);
      }
}

// ---------------- packB: h [8192][256] -> hF fragment-major ----------------
// hF chunk (fg, kc2): feats [fg*16,+16) x nodes [kc2*32,+32); element
// (feat f, node k) at lane=(k>>3)&... : lane = ((k&31)>>3)*16 + (f&15), e=k&7.
__global__ __launch_bounds__(256) void packB_kernel(const short* __restrict__ in,
                                                    short* __restrict__ hF) {
  __shared__ __align__(16) short T[64][80];
  const int i0 = blockIdx.x * 64, f0 = blockIdx.y * 64;
  const int t = threadIdx.x;
  const int r = t >> 2, c0 = (t & 3) * 16;
  s8v v0 = *(const s8v*)(in + (i0 + r) * 256 + f0 + c0);
  s8v v1 = *(const s8v*)(in + (i0 + r) * 256 + f0 + c0 + 8);
#pragma unroll
  for (int e = 0; e < 8; ++e) {
    T[c0 + e][r] = v0[e];       // T[feat][node]
    T[c0 + 8 + e][r] = v1[e];
  }
  __syncthreads();
  const int w = t >> 6, lane = t & 63;
  const int c = lane & 15, g = lane >> 4;
#pragma unroll
  for (int kc2 = 0; kc2 < 2; ++kc2) {
    s8v o = *(const s8v*)&T[w * 16 + c][kc2 * 32 + g * 8];
    size_t chunk = (size_t)((f0 >> 4) + w) * 256 + (i0 >> 5) + kc2;
    *(s8v*)(hF + chunk * 512 + lane * 8) = o;
  }
}

// ---------------- aggA: partial[z] = A[:, kslice] @ h[kslice, :] ------------
// LDS-free: B frags coalesced from hF; A bits from AT + VGPR expansion.
__global__ __launch_bounds__(256) void aggA_kernel(const unsigned long long* __restrict__ AT,
                                                   const short* __restrict__ hF,
                                                   float* __restrict__ partial,
                                                   int ksplit) {
  const int i0 = blockIdx.x * 128;  // node rows
  const int f0 = blockIdx.y * 128;  // features
  const int k0 = blockIdx.z * ksplit;
  const int tid = threadIdx.x, w = tid >> 6, lane = tid & 63;
  const int wy = (w >> 1) * 64, wx = (w & 1) * 64;
  const int lr = lane & 15, g = lane >> 4;
  const int g8 = g * 8;
  const short one = (short)0x3F80;

  f4v acc[4][4];
#pragma unroll
  for (int a = 0; a < 4; ++a)
#pragma unroll
    for (int b = 0; b < 4; ++b) acc[a][b] = (f4v){0.f, 0.f, 0.f, 0.f};

  for (int kb = k0; kb < k0 + ksplit; kb += 128) {
    // A bit-words: row (i0+wy+mt*16+lr), word columns kb/64 and kb/64+1
    unsigned long long aw[4][2];
#pragma unroll
    for (int mt = 0; mt < 4; ++mt) {
      size_t row = (size_t)i0 + wy + mt * 16 + lr;
      aw[mt][0] = AT[(size_t)(kb >> 6) * 8192 + row];
      aw[mt][1] = AT[(size_t)((kb >> 6) + 1) * 8192 + row];
    }
#pragma unroll
    for (int kc = 0; kc < 4; ++kc) {
      s8v bf[4];
#pragma unroll
      for (int nt = 0; nt < 4; ++nt) {
        size_t chunk = (size_t)((f0 + wx) >> 4) + nt;
        chunk = chunk * 256 + (kb >> 5) + kc;
        bf[nt] = *(const s8v*)(hF + chunk * 512 + lane * 8);
      }
#pragma unroll
      for (int mt = 0; mt < 4; ++mt) {
        unsigned byte = (unsigned)(aw[mt][kc >> 1] >> ((kc & 1) * 32 + g8)) & 0xFFu;
        s8v a;
#pragma unroll
        for (int e = 0; e < 8; ++e) a[e] = ((byte >> e) & 1u) ? one : (short)0;
#pragma unroll
        for (int nt = 0; nt < 4; ++nt) acc[mt][nt] = MFMA(a, bf[nt], acc[mt][nt]);
      }
    }
  }
  float* P = partial + (size_t)blockIdx.z * (8192 * 256);
#pragma unroll
  for (int mt = 0; mt < 4; ++mt)
#pragma unroll
    for (int nt = 0; nt < 4; ++nt)
#pragma unroll
      for (int rr = 0; rr < 4; ++rr) {
        int row = i0 + wy + mt * 16 + g * 4 + rr;
        int col = f0 + wx + nt * 16 + lr;
        P[(size_t)row * 256 + col] = acc[mt][nt][rr];
      }
}

// combine: agg = bf16(sum_z partial[z] * deg_inv[row])
__global__ __launch_bounds__(256) void combine_kernel(const float* __restrict__ p, int nsplit,
                                                      const float* __restrict__ deg_inv,
                                                      short* __restrict__ agg) {
  int idx = blockIdx.x * 256 + threadIdx.x;  // group of 4 elems
  const float4* pv = (const float4*)p;
  float4 s = pv[idx];
  for (int k = 1; k < nsplit; ++k) {
    float4 v = pv[(size_t)k * 524288 + idx];
    s.x += v.x; s.y += v.y; s.z += v.z; s.w += v.w;
  }
  float di = deg_inv[idx >> 6];
  s4v o;
  o[0] = f2bf(s.x * di); o[1] = f2bf(s.y * di);
  o[2] = f2bf(s.z * di); o[3] = f2bf(s.w * di);
  *(s4v*)&agg[idx * 4] = o;
}

// ---------------- tail ----------------
__global__ __launch_bounds__(256) void vec3_kernel(const short* __restrict__ h2,
                                                   const float* __restrict__ o1wl,
                                                   const float* __restrict__ o1wr,
                                                   const float* __restrict__ oscw,
                                                   const float* __restrict__ oscb,
                                                   float* __restrict__ u, float* __restrict__ v,
                                                   float* __restrict__ sc) {
  int row = blockIdx.x * 4 + (threadIdx.x >> 6);
  int lane = threadIdx.x & 63;
  float su = 0.f, sv = 0.f, ss = 0.f;
#pragma unroll
  for (int e = 0; e < 4; ++e) {
    int k = lane * 4 + e;
    float hv = bf2f(h2[row * 256 + k]);
    su += hv * o1wl[k];
    sv += hv * o1wr[k];
    ss += hv * oscw[k];
  }
  for (int o = 1; o < 64; o <<= 1) {
    su += __shfl_xor(su, o);
    sv += __shfl_xor(sv, o);
    ss += __shfl_xor(ss, o);
  }
  if (lane == 0) {
    u[row] = su;
    v[row] = sv;
    sc[row] = ss + oscb[0];
  }
}

__global__ __launch_bounds__(256) void aggv1_kernel(const unsigned long long* __restrict__ Awords,
                                                    const float* __restrict__ u,
                                                    const float* __restrict__ deg_inv,
                                                    const float* __restrict__ v,
                                                    const float* __restrict__ o1bl,
                                                    float* __restrict__ o1) {
  int row = blockIdx.x * 4 + (threadIdx.x >> 6);
  int lane = threadIdx.x & 63;
  float s = 0.f;
#pragma unroll
  for (int wi = 0; wi < 2; ++wi) {
    unsigned long long bits = Awords[row * 128 + wi * 64 + lane];
    int base = (wi * 64 + lane) * 64;
    while (bits) {
      int b = __ffsll(bits) - 1;
      s += u[base + b];
      bits &= bits - 1;
    }
  }
  for (int o = 1; o < 64; o <<= 1) s += __shfl_xor(s, o);
  if (lane == 0) o1[row] = fmaxf(s * deg_inv[row] + o1bl[0] + v[row], 0.f);
}

__global__ __launch_bounds__(256) void aggv2_kernel(const unsigned long long* __restrict__ Awords,
                                                    const float* __restrict__ o1,
                                                    const float* __restrict__ deg_inv,
                                                    const float* __restrict__ o2wl,
                                                    const float* __restrict__ o2bl,
                                                    const float* __restrict__ o2wr,
                                                    const float* __restrict__ sc,
                                                    float* __restrict__ out) {
  int row = blockIdx.x * 4 + (threadIdx.x >> 6);
  int lane = threadIdx.x & 63;
  float s = 0.f;
#pragma unroll
  for (int wi = 0; wi < 2; ++wi) {
    unsigned long long bits = Awords[row * 128 + wi * 64 + lane];
    int base = (wi * 64 + lane) * 64;
    while (bits) {
      int b = __ffsll(bits) - 1;
      s += o1[base + b];
      bits &= bits - 1;
    }
  }
  for (int o = 1; o < 64; o <<= 1) s += __shfl_xor(s, o);
  if (lane == 0) {
    float z = s * deg_inv[row] * o2wl[0] + o2bl[0] + o1[row] * o2wr[0] + sc[row];
    out[row] = 1.f / (1.f + expf(-z));
  }
}

// ---------------- launch ----------------
extern "C" void kernel_launch(void* const* d_in, const int* in_sizes, int n_in,
                              void* d_out, int out_size, void* d_ws, size_t ws_size,
                              hipStream_t stream) {
  (void)in_sizes; (void)n_in; (void)out_size;
  const float* x     = (const float*)d_in[0];
  const float* w_in  = (const float*)d_in[1];
  const float* b_in  = (const float*)d_in[2];
  const float* h1_wl = (const float*)d_in[3];
  const float* h1_bl = (const float*)d_in[4];
  const float* h1_wr = (const float*)d_in[5];
  const float* h2_wl = (const float*)d_in[6];
  const float* h2_bl = (const float*)d_in[7];
  const float* h2_wr = (const float*)d_in[8];
  const float* o1_wl = (const float*)d_in[9];
  const float* o1_bl = (const float*)d_in[10];
  const float* o1_wr = (const float*)d_in[11];
  const float* o2_wl = (const float*)d_in[12];
  const float* o2_bl = (const float*)d_in[13];
  const float* o2_wr = (const float*)d_in[14];
  const float* osc_w = (const float*)d_in[15];
  const float* osc_b = (const float*)d_in[16];
  float* out = (float*)d_out;

  char* ws = (char*)d_ws;
  size_t off = 0;
  auto alloc = [&](size_t bytes) -> char* {
    char* p = ws + off;
    off += (bytes + 255) & ~(size_t)255;
    return p;
  };
  short* xnF   = (short*)alloc(8192 * 128 * 2);  // fragment-major normalized x
  short* xb    = (short*)alloc(8192 * 128 * 2);
  short* w_inT = (short*)alloc(256 * 128 * 2);
  short* w1lT  = (short*)alloc(256 * 256 * 2);
  short* w1rT  = (short*)alloc(256 * 256 * 2);
  short* w2lT  = (short*)alloc(256 * 256 * 2);
  short* w2rT  = (short*)alloc(256 * 256 * 2);
  unsigned int* hist1 = (unsigned int*)alloc(1024 * 4);
  unsigned int* hist2 = (unsigned int*)alloc(8192 * 4);
  unsigned int* sel   = (unsigned int*)alloc(256);
  float* deg_inv = (float*)alloc(8192 * 4);
  float* ubuf  = (float*)alloc(8192 * 4);
  float* vbuf  = (float*)alloc(8192 * 4);
  float* scbuf = (float*)alloc(8192 * 4);
  float* o1buf = (float*)alloc(8192 * 4);
  unsigned long long* Awords = (unsigned long long*)alloc((size_t)8192 * 128 * 8);
  unsigned long long* AT     = (unsigned long long*)alloc((size_t)8192 * 128 * 8);
  short* h0  = (short*)alloc((size_t)8192 * 256 * 2);
  short* h1  = (short*)alloc((size_t)8192 * 256 * 2);
  short* h2  = (short*)alloc((size_t)8192 * 256 * 2);
  short* hF  = (short*)alloc((size_t)8192 * 256 * 2);
  short* agg = (short*)alloc((size_t)8192 * 256 * 2);
  int nsplit = (ws_size >= off + 4 * (size_t)8192 * 256 * 4 + 4096) ? 4 : 2;
  float* partials = (float*)alloc((size_t)nsplit * 8192 * 256 * 4);
  const int ksplit = 8192 / nsplit;

  hipMemsetAsync(hist1, 0, (1024 + 8192) * 4, stream);
  prep_x_kernel<<<128, 256, 0, stream>>>(x, xb, xnF);
  prep_w_kernel<<<1152, 256, 0, stream>>>(w_in, h1_wl, h1_wr, h2_wl, h2_wr,
                                          w_inT, w1lT, w1rT, w2lT, w2rT);
  sim_kernel<0><<<NTRI / 4, 256, 0, stream>>>(xnF, hist1, sel, nullptr, nullptr);
  scan_kernel<1024, 0><<<1, 256, 0, stream>>>(hist1, sel);
  sim_kernel<1><<<NTRI / 4, 256, 0, stream>>>(xnF, hist2, sel, nullptr, nullptr);
  scan_kernel<8192, 1><<<1, 256, 0, stream>>>(hist2, sel);
  sim_kernel<2><<<NTRI / 4, 256, 0, stream>>>(xnF, nullptr, sel, Awords, AT);
  deg_kernel<<<2048, 256, 0, stream>>>(Awords, deg_inv);

  // h0 = relu(x @ w_in + b_in)
  lin_kernel<false, true, false><<<dim3(128, 4), 256, 0, stream>>>(
      xb, w_inT, 128, nullptr, nullptr, 0, b_in, nullptr, h0);
  // h1 = relu(agg(h0)@h1_wl + h1_bl + h0@h1_wr)
  packB_kernel<<<dim3(128, 4), 256, 0, stream>>>(h0, hF);
  aggA_kernel<<<dim3(64, 2, nsplit), 256, 0, stream>>>(AT, hF, partials, ksplit);
  combine_kernel<<<2048, 256, 0, stream>>>(partials, nsplit, deg_inv, agg);
  lin_kernel<true, true, false><<<dim3(128, 4), 256, 0, stream>>>(
      agg, w1lT, 256, h0, w1rT, 256, h1_bl, nullptr, h1);
  // h2 = relu(agg(h1)@h2_wl + h2_bl + h1@h2_wr + h0)
  packB_kernel<<<dim3(128, 4), 256, 0, stream>>>(h1, hF);
  aggA_kernel<<<dim3(64, 2, nsplit), 256, 0, stream>>>(AT, hF, partials, ksplit);
  combine_kernel<<<2048, 256, 0, stream>>>(partials, nsplit, deg_inv, agg);
  lin_kernel<true, true, true><<<dim3(128, 4), 256, 0, stream>>>(
      agg, w2lT, 256, h1, w2rT, 256, h2_bl, h0, h2);
  // output block
  vec3_kernel<<<2048, 256, 0, stream>>>(h2, o1_wl, o1_wr, osc_w, osc_b, ubuf, vbuf, scbuf);
  aggv1_kernel<<<2048, 256, 0, stream>>>(Awords, ubuf, deg_inv, vbuf, o1_bl, o1buf);
  aggv2_kernel<<<2048, 256, 0, stream>>>(Awords, o1buf, deg_inv, o2_wl, o2_bl, o2_wr, scbuf, out);
}

// Round 6
// 366.891 us; speedup vs baseline: 1.4208x; 1.0325x over previous
//
#include <hip/hip_runtime.h>

// GNN_79937931313503: dynamic-graph SAGE GNN on MI355X.
// R6: aggA — LDS LUT (byte -> 4 dwords bf16 0/1) replaces VALU bit-expansion;
// wave tile widened to 64 rows x 128 feats (nt=8) so each A expansion feeds
// 8 MFMAs; split-K=8 for 512 blocks (2/CU). No barriers in the K-loop.

typedef __attribute__((ext_vector_type(8))) short s8v;   // 8 x bf16 (4 VGPR)
typedef __attribute__((ext_vector_type(4))) short s4v;   // 4 x bf16
typedef __attribute__((ext_vector_type(4))) float f4v;   // MFMA C/D frag

__device__ __forceinline__ f4v MFMA(s8v a, s8v b, f4v c) {
  return __builtin_amdgcn_mfma_f32_16x16x32_bf16(a, b, c, 0, 0, 0);
}
__device__ __forceinline__ short f2bf(float f) {  // RNE float->bf16 bits
  unsigned u = __float_as_uint(f);
  return (short)((u + 0x7FFFu + ((u >> 16) & 1u)) >> 16);
}
__device__ __forceinline__ float bf2f(short s) {
  return __uint_as_float(((unsigned)(unsigned short)s) << 16);
}

// ---------------- prep_x: norms + xb (row-major) + xnF (fragment-major) ----
__global__ __launch_bounds__(256) void prep_x_kernel(const float* __restrict__ x,
                                                     short* __restrict__ xb,
                                                     short* __restrict__ xnF) {
  const int w = threadIdx.x >> 6, lane = threadIdx.x & 63;
  const int rg = blockIdx.x * 4 + w;
  const int m = lane & 15, g = lane >> 4;
  const int row = rg * 16 + m;
  float v[4][8];
  float ss = 0.f;
#pragma unroll
  for (int kc = 0; kc < 4; ++kc) {
    const float* src = x + row * 128 + kc * 32 + g * 8;
    float4 a = *(const float4*)src;
    float4 b = *(const float4*)(src + 4);
    v[kc][0] = a.x; v[kc][1] = a.y; v[kc][2] = a.z; v[kc][3] = a.w;
    v[kc][4] = b.x; v[kc][5] = b.y; v[kc][6] = b.z; v[kc][7] = b.w;
#pragma unroll
    for (int e = 0; e < 8; ++e) ss += v[kc][e] * v[kc][e];
  }
  ss += __shfl_xor(ss, 16);
  ss += __shfl_xor(ss, 32);
  float inv = 1.0f / fmaxf(sqrtf(ss), 1e-8f);
#pragma unroll
  for (int kc = 0; kc < 4; ++kc) {
    s8v raw, nrm;
#pragma unroll
    for (int e = 0; e < 8; ++e) {
      raw[e] = f2bf(v[kc][e]);
      nrm[e] = f2bf(v[kc][e] * inv);
    }
    *(s8v*)(xb + row * 128 + kc * 32 + g * 8) = raw;
    *(s8v*)(xnF + (rg * 4 + kc) * 512 + lane * 8) = nrm;  // coalesced 1KB
  }
}

__global__ __launch_bounds__(256) void prep_w_kernel(
    const float* __restrict__ w_in, const float* __restrict__ w1l,
    const float* __restrict__ w1r, const float* __restrict__ w2l,
    const float* __restrict__ w2r, short* __restrict__ w_inT,
    short* __restrict__ w1lT, short* __restrict__ w1rT,
    short* __restrict__ w2lT, short* __restrict__ w2rT) {
  int idx = blockIdx.x * 256 + threadIdx.x;
  if (idx >= 294912) return;
  if (idx < 32768) {                       // w_in [128][256] -> [256][128]
    int n = idx >> 7, k = idx & 127;
    w_inT[idx] = f2bf(w_in[k * 256 + n]);
  } else {                                 // 4x [256][256] transposed
    int j = idx - 32768;
    int m = j >> 16, r = j & 65535;
    int n = r >> 8, k = r & 255;
    const float* src = (m == 0) ? w1l : (m == 1) ? w1r : (m == 2) ? w2l : w2r;
    short* dst = (m == 0) ? w1lT : (m == 1) ? w1rT : (m == 2) ? w2lT : w2rT;
    dst[r] = f2bf(src[k * 256 + n]);
  }
}

// ---------------- sim: per-wave 64x64 tiles, upper triangle only ----------------
#define NT64 128
#define NTRI 8256  // 128*129/2
template <int MODE>
__global__ __launch_bounds__(256) void sim_kernel(
    const short* __restrict__ xnF, unsigned int* __restrict__ hist,
    unsigned int* __restrict__ sel, unsigned long long* __restrict__ Awords,
    unsigned long long* __restrict__ AT) {
  __shared__ unsigned int lh[MODE == 0 ? 4096 : 1];
  const int tid = threadIdx.x, w = tid >> 6, lane = tid & 63;
  if (MODE == 0) {
    for (int b = tid; b < 4096; b += 256) lh[b] = 0;
    __syncthreads();
  }
  int t = blockIdx.x * 4 + w;
  int r = (int)((257.0f - sqrtf((float)(257 * 257 - 8 * t))) * 0.5f);
  if (r < 0) r = 0;
  if (r > 127) r = 127;
  while (r < 127 && ((r + 1) * NT64 - (r + 1) * r / 2) <= t) ++r;
  while (r > 0 && (r * NT64 - r * (r - 1) / 2) > t) --r;
  const int c = r + (t - (r * NT64 - r * (r - 1) / 2));
  const int i0 = r * 64, j0 = c * 64;
  const bool diag = (r == c);

  f4v acc[4][4];
#pragma unroll
  for (int a = 0; a < 4; ++a)
#pragma unroll
    for (int b = 0; b < 4; ++b) acc[a][b] = (f4v){0.f, 0.f, 0.f, 0.f};

  const int rga = r * 4, rgb = c * 4;
#pragma unroll
  for (int kc = 0; kc < 4; ++kc) {
    s8v af[4], bf[4];
#pragma unroll
    for (int mt = 0; mt < 4; ++mt)
      af[mt] = *(const s8v*)(xnF + ((rga + mt) * 4 + kc) * 512 + lane * 8);
#pragma unroll
    for (int nt = 0; nt < 4; ++nt)
      bf[nt] = *(const s8v*)(xnF + ((rgb + nt) * 4 + kc) * 512 + lane * 8);
#pragma unroll
    for (int mt = 0; mt < 4; ++mt)
#pragma unroll
      for (int nt = 0; nt < 4; ++nt) acc[mt][nt] = MFMA(af[mt], bf[nt], acc[mt][nt]);
  }

  if (MODE == 0) {
    unsigned wgt = diag ? 1u : 2u;
#pragma unroll
    for (int mt = 0; mt < 4; ++mt)
      for (int nt = 0; nt < 4; ++nt)
        for (int rr = 0; rr < 4; ++rr) {
          unsigned bits = __float_as_uint(fabsf(acc[mt][nt][rr]));
          unsigned bin = bits >> 20;
          if (bin > 1023u) bin = 1023u;
          atomicAdd(&lh[bin * 4 + (lane & 3)], wgt);
        }
    __syncthreads();
    for (int b = tid; b < 1024; b += 256) {
      unsigned s = lh[b * 4] + lh[b * 4 + 1] + lh[b * 4 + 2] + lh[b * 4 + 3];
      if (s) atomicAdd(&hist[b], s);
    }
  } else if (MODE == 1) {
    unsigned pref = sel[0];
    unsigned wgt = diag ? 1u : 2u;
#pragma unroll
    for (int mt = 0; mt < 4; ++mt)
      for (int nt = 0; nt < 4; ++nt)
        for (int rr = 0; rr < 4; ++rr) {
          unsigned bits = __float_as_uint(fabsf(acc[mt][nt][rr]));
          if ((bits >> 20) == pref) atomicAdd(&hist[(bits >> 7) & 0x1FFFu], wgt);
        }
  } else {
    float eps = __uint_as_float(sel[2]);
    unsigned long long myword = 0;  // lane j holds row (i0+j)'s bits [j0..j0+64)
#pragma unroll
    for (int mt = 0; mt < 4; ++mt)
#pragma unroll
      for (int rr = 0; rr < 4; ++rr) {
        unsigned long long b0 = __ballot(fabsf(acc[mt][0][rr]) >= eps);
        unsigned long long b1 = __ballot(fabsf(acc[mt][1][rr]) >= eps);
        unsigned long long b2 = __ballot(fabsf(acc[mt][2][rr]) >= eps);
        unsigned long long b3 = __ballot(fabsf(acc[mt][3][rr]) >= eps);
        if ((lane >> 4) == mt && (lane & 3) == rr) {
          int gj = (lane >> 2) & 3;
          myword = ((b0 >> (16 * gj)) & 0xFFFFull) |
                   (((b1 >> (16 * gj)) & 0xFFFFull) << 16) |
                   (((b2 >> (16 * gj)) & 0xFFFFull) << 32) |
                   (((b3 >> (16 * gj)) & 0xFFFFull) << 48);
        }
      }
    Awords[(size_t)(i0 + lane) * 128 + (j0 >> 6)] = myword;
    AT[(size_t)(j0 >> 6) * 8192 + i0 + lane] = myword;
    if (!diag) {  // mirrored tile via 64x64 bit transpose (ballot per column)
      unsigned long long tw = 0;
#pragma unroll
      for (int c2 = 0; c2 < 64; ++c2) {
        unsigned long long bc = __ballot((myword >> c2) & 1ull);
        if (lane == c2) tw = bc;
      }
      Awords[(size_t)(j0 + lane) * 128 + (i0 >> 6)] = tw;
      AT[(size_t)(i0 >> 6) * 8192 + j0 + lane] = tw;
    }
  }
}

// ---------------- histogram selection scan ----------------
template <int NB, int MODE>
__global__ __launch_bounds__(256) void scan_kernel(const unsigned int* __restrict__ hist,
                                                   unsigned int* __restrict__ sel) {
  __shared__ unsigned long long csum[256];
  const int t = threadIdx.x;
  const int PER = NB / 256;
  unsigned int vals[NB / 256];
  unsigned long long s = 0;
  for (int i = 0; i < PER; ++i) {
    vals[i] = hist[t * PER + i];
    s += vals[i];
  }
  csum[t] = s;
  __syncthreads();
  for (int o = 1; o < 256; o <<= 1) {
    unsigned long long prev = (t >= o) ? csum[t - o] : 0ull;
    __syncthreads();
    csum[t] += prev;
    __syncthreads();
  }
  unsigned long long K = (MODE == 0) ? 63753421ull : (unsigned long long)sel[1];
  unsigned long long inc = csum[t], exc = inc - s;
  if (K > exc && K <= inc) {
    unsigned long long c = exc;
    for (int i = 0; i < PER; ++i) {
      c += vals[i];
      if (c >= K) {
        if (MODE == 0) {
          sel[0] = (unsigned)(t * PER + i);
          sel[1] = (unsigned)(K - (c - vals[i]));
        } else {
          sel[2] = (sel[0] << 20) | ((unsigned)(t * PER + i) << 7);
        }
        break;
      }
    }
  }
}

// ---------------- degree ----------------
__global__ __launch_bounds__(256) void deg_kernel(const unsigned long long* __restrict__ Awords,
                                                  float* __restrict__ deg_inv) {
  int row = blockIdx.x * 4 + (threadIdx.x >> 6);
  int lane = threadIdx.x & 63;
  int c = __popcll(Awords[row * 128 + lane]) + __popcll(Awords[row * 128 + 64 + lane]);
  for (int o = 32; o; o >>= 1) c += __shfl_down(c, o);
  if (lane == 0) deg_inv[row] = 1.0f / (float)max(c, 1);
}

// ---------------- small NT linears ----------------
template <bool TWO, bool RELU, bool RES>
__global__ __launch_bounds__(256) void lin_kernel(
    const short* __restrict__ A1, const short* __restrict__ B1, int K1,
    const short* __restrict__ A2, const short* __restrict__ B2, int K2,
    const float* __restrict__ bias, const short* __restrict__ res,
    short* __restrict__ out) {
  const int i0 = blockIdx.x * 64, n0 = blockIdx.y * 64;
  const int tid = threadIdx.x, w = tid >> 6, lane = tid & 63;
  const int wy = (w >> 1) * 32, wx = (w & 1) * 32;
  const int lr = lane & 15, lk = (lane >> 4) * 8;
  f4v acc[2][2];
#pragma unroll
  for (int a = 0; a < 2; ++a)
#pragma unroll
    for (int b = 0; b < 2; ++b) acc[a][b] = (f4v){0.f, 0.f, 0.f, 0.f};

  for (int kc = 0; kc < K1; kc += 32) {
    s8v a0 = *(const s8v*)(A1 + (i0 + wy + lr) * K1 + kc + lk);
    s8v a1 = *(const s8v*)(A1 + (i0 + wy + 16 + lr) * K1 + kc + lk);
    s8v b0 = *(const s8v*)(B1 + (n0 + wx + lr) * K1 + kc + lk);
    s8v b1 = *(const s8v*)(B1 + (n0 + wx + 16 + lr) * K1 + kc + lk);
    acc[0][0] = MFMA(a0, b0, acc[0][0]);
    acc[0][1] = MFMA(a0, b1, acc[0][1]);
    acc[1][0] = MFMA(a1, b0, acc[1][0]);
    acc[1][1] = MFMA(a1, b1, acc[1][1]);
  }
  if constexpr (TWO) {
    for (int kc = 0; kc < K2; kc += 32) {
      s8v a0 = *(const s8v*)(A2 + (i0 + wy + lr) * K2 + kc + lk);
      s8v a1 = *(const s8v*)(A2 + (i0 + wy + 16 + lr) * K2 + kc + lk);
      s8v b0 = *(const s8v*)(B2 + (n0 + wx + lr) * K2 + kc + lk);
      s8v b1 = *(const s8v*)(B2 + (n0 + wx + 16 + lr) * K2 + kc + lk);
      acc[0][0] = MFMA(a0, b0, acc[0][0]);
      acc[0][1] = MFMA(a0, b1, acc[0][1]);
      acc[1][0] = MFMA(a1, b0, acc[1][0]);
      acc[1][1] = MFMA(a1, b1, acc[1][1]);
    }
  }
#pragma unroll
  for (int mt = 0; mt < 2; ++mt)
#pragma unroll
    for (int nt = 0; nt < 2; ++nt)
#pragma unroll
      for (int rr = 0; rr < 4; ++rr) {
        int row = i0 + wy + mt * 16 + (lane >> 4) * 4 + rr;
        int col = n0 + wx + nt * 16 + (lane & 15);
        float v = acc[mt][nt][rr] + bias[col];
        if constexpr (RES) v += bf2f(res[row * 256 + col]);
        if constexpr (RELU) v = fmaxf(v, 0.f);
        out[row * 256 + col] = f2bf(v);
      }
}

// ---------------- packB: h [8192][256] -> hF fragment-major ----------------
__global__ __launch_bounds__(256) void packB_kernel(const short* __restrict__ in,
                                                    short* __restrict__ hF) {
  __shared__ __align__(16) short T[64][80];
  const int i0 = blockIdx.x * 64, f0 = blockIdx.y * 64;
  const int t = threadIdx.x;
  const int r = t >> 2, c0 = (t & 3) * 16;
  s8v v0 = *(const s8v*)(in + (i0 + r) * 256 + f0 + c0);
  s8v v1 = *(const s8v*)(in + (i0 + r) * 256 + f0 + c0 + 8);
#pragma unroll
  for (int e = 0; e < 8; ++e) {
    T[c0 + e][r] = v0[e];       // T[feat][node]
    T[c0 + 8 + e][r] = v1[e];
  }
  __syncthreads();
  const int w = t >> 6, lane = t & 63;
  const int c = lane & 15, g = lane >> 4;
#pragma unroll
  for (int kc2 = 0; kc2 < 2; ++kc2) {
    s8v o = *(const s8v*)&T[w * 16 + c][kc2 * 32 + g * 8];
    size_t chunk = (size_t)((f0 >> 4) + w) * 256 + (i0 >> 5) + kc2;
    *(s8v*)(hF + chunk * 512 + lane * 8) = o;
  }
}

// ---------------- aggA: partial[z] = A[:, kslice] @ h[kslice, :] ------------
// Wave = 64 rows x 128 feats (mt=4, nt=8); block = 4 waves = 128 rows x 256
// feats. A bits -> bf16 frags via 256x16B LDS LUT (1 ds_read_b128/frag).
__global__ __launch_bounds__(256, 2) void aggA_kernel(
    const unsigned long long* __restrict__ AT, const short* __restrict__ hF,
    float* __restrict__ partial, int ksplit) {
  __shared__ __align__(16) unsigned int lut[256 * 4];
  {
    unsigned b = threadIdx.x;
    unsigned v0 = ((b & 1u) ? 0x3F80u : 0u) | ((b & 2u) ? 0x3F800000u : 0u);
    unsigned v1 = ((b & 4u) ? 0x3F80u : 0u) | ((b & 8u) ? 0x3F800000u : 0u);
    unsigned v2 = ((b & 16u) ? 0x3F80u : 0u) | ((b & 32u) ? 0x3F800000u : 0u);
    unsigned v3 = ((b & 64u) ? 0x3F80u : 0u) | ((b & 128u) ? 0x3F800000u : 0u);
    lut[b * 4] = v0; lut[b * 4 + 1] = v1; lut[b * 4 + 2] = v2; lut[b * 4 + 3] = v3;
  }
  __syncthreads();

  const int i0 = blockIdx.x * 128;            // node rows
  const int k0 = blockIdx.y * ksplit;         // k split
  const int tid = threadIdx.x, w = tid >> 6, lane = tid & 63;
  const int wy = (w >> 1) * 64;               // row offset within block
  const int wx = (w & 1) * 128;               // feat offset within block
  const int lr = lane & 15, g = lane >> 4;
  const int g8 = g * 8;

  f4v acc[4][8];
#pragma unroll
  for (int a = 0; a < 4; ++a)
#pragma unroll
    for (int b = 0; b < 8; ++b) acc[a][b] = (f4v){0.f, 0.f, 0.f, 0.f};

  for (int kb = k0; kb < k0 + ksplit; kb += 64) {
    unsigned long long aw[4];
#pragma unroll
    for (int mt = 0; mt < 4; ++mt)
      aw[mt] = AT[(size_t)(kb >> 6) * 8192 + i0 + wy + mt * 16 + lr];
#pragma unroll
    for (int kc = 0; kc < 2; ++kc) {
      s8v bf[8];
#pragma unroll
      for (int nt = 0; nt < 8; ++nt) {
        size_t chunk = (size_t)((wx >> 4) + nt) * 256 + (kb >> 5) + kc;
        bf[nt] = *(const s8v*)(hF + chunk * 512 + lane * 8);
      }
#pragma unroll
      for (int mt = 0; mt < 4; ++mt) {
        unsigned byte = ((unsigned)(aw[mt] >> (kc * 32)) >> g8) & 0xFFu;
        s8v a = *(const s8v*)&lut[byte * 4];  // ds_read_b128
#pragma unroll
        for (int nt = 0; nt < 8; ++nt) acc[mt][nt] = MFMA(a, bf[nt], acc[mt][nt]);
      }
    }
  }
  float* P = partial + (size_t)blockIdx.y * (8192 * 256);
#pragma unroll
  for (int mt = 0; mt < 4; ++mt)
#pragma unroll
    for (int nt = 0; nt < 8; ++nt)
#pragma unroll
      for (int rr = 0; rr < 4; ++rr) {
        int row = i0 + wy + mt * 16 + g * 4 + rr;
        int col = wx + nt * 16 + lr;
        P[(size_t)row * 256 + col] = acc[mt][nt][rr];
      }
}

// combine: agg = bf16(sum_z partial[z] * deg_inv[row])
__global__ __launch_bounds__(256) void combine_kernel(const float* __restrict__ p, int nsplit,
                                                      const float* __restrict__ deg_inv,
                                                      short* __restrict__ agg) {
  int idx = blockIdx.x * 256 + threadIdx.x;  // group of 4 elems
  const float4* pv = (const float4*)p;
  float4 s = pv[idx];
  for (int k = 1; k < nsplit; ++k) {
    float4 v = pv[(size_t)k * 524288 + idx];
    s.x += v.x; s.y += v.y; s.z += v.z; s.w += v.w;
  }
  float di = deg_inv[idx >> 6];
  s4v o;
  o[0] = f2bf(s.x * di); o[1] = f2bf(s.y * di);
  o[2] = f2bf(s.z * di); o[3] = f2bf(s.w * di);
  *(s4v*)&agg[idx * 4] = o;
}

// ---------------- tail ----------------
__global__ __launch_bounds__(256) void vec3_kernel(const short* __restrict__ h2,
                                                   const float* __restrict__ o1wl,
                                                   const float* __restrict__ o1wr,
                                                   const float* __restrict__ oscw,
                                                   const float* __restrict__ oscb,
                                                   float* __restrict__ u, float* __restrict__ v,
                                                   float* __restrict__ sc) {
  int row = blockIdx.x * 4 + (threadIdx.x >> 6);
  int lane = threadIdx.x & 63;
  float su = 0.f, sv = 0.f, ss = 0.f;
#pragma unroll
  for (int e = 0; e < 4; ++e) {
    int k = lane * 4 + e;
    float hv = bf2f(h2[row * 256 + k]);
    su += hv * o1wl[k];
    sv += hv * o1wr[k];
    ss += hv * oscw[k];
  }
  for (int o = 1; o < 64; o <<= 1) {
    su += __shfl_xor(su, o);
    sv += __shfl_xor(sv, o);
    ss += __shfl_xor(ss, o);
  }
  if (lane == 0) {
    u[row] = su;
    v[row] = sv;
    sc[row] = ss + oscb[0];
  }
}

__global__ __launch_bounds__(256) void aggv1_kernel(const unsigned long long* __restrict__ Awords,
                                                    const float* __restrict__ u,
                                                    const float* __restrict__ deg_inv,
                                                    const float* __restrict__ v,
                                                    const float* __restrict__ o1bl,
                                                    float* __restrict__ o1) {
  int row = blockIdx.x * 4 + (threadIdx.x >> 6);
  int lane = threadIdx.x & 63;
  float s = 0.f;
#pragma unroll
  for (int wi = 0; wi < 2; ++wi) {
    unsigned long long bits = Awords[row * 128 + wi * 64 + lane];
    int base = (wi * 64 + lane) * 64;
    while (bits) {
      int b = __ffsll(bits) - 1;
      s += u[base + b];
      bits &= bits - 1;
    }
  }
  for (int o = 1; o < 64; o <<= 1) s += __shfl_xor(s, o);
  if (lane == 0) o1[row] = fmaxf(s * deg_inv[row] + o1bl[0] + v[row], 0.f);
}

__global__ __launch_bounds__(256) void aggv2_kernel(const unsigned long long* __restrict__ Awords,
                                                    const float* __restrict__ o1,
                                                    const float* __restrict__ deg_inv,
                                                    const float* __restrict__ o2wl,
                                                    const float* __restrict__ o2bl,
                                                    const float* __restrict__ o2wr,
                                                    const float* __restrict__ sc,
                                                    float* __restrict__ out) {
  int row = blockIdx.x * 4 + (threadIdx.x >> 6);
  int lane = threadIdx.x & 63;
  float s = 0.f;
#pragma unroll
  for (int wi = 0; wi < 2; ++wi) {
    unsigned long long bits = Awords[row * 128 + wi * 64 + lane];
    int base = (wi * 64 + lane) * 64;
    while (bits) {
      int b = __ffsll(bits) - 1;
      s += o1[base + b];
      bits &= bits - 1;
    }
  }
  for (int o = 1; o < 64; o <<= 1) s += __shfl_xor(s, o);
  if (lane == 0) {
    float z = s * deg_inv[row] * o2wl[0] + o2bl[0] + o1[row] * o2wr[0] + sc[row];
    out[row] = 1.f / (1.f + expf(-z));
  }
}

// ---------------- launch ----------------
extern "C" void kernel_launch(void* const* d_in, const int* in_sizes, int n_in,
                              void* d_out, int out_size, void* d_ws, size_t ws_size,
                              hipStream_t stream) {
  (void)in_sizes; (void)n_in; (void)out_size;
  const float* x     = (const float*)d_in[0];
  const float* w_in  = (const float*)d_in[1];
  const float* b_in  = (const float*)d_in[2];
  const float* h1_wl = (const float*)d_in[3];
  const float* h1_bl = (const float*)d_in[4];
  const float* h1_wr = (const float*)d_in[5];
  const float* h2_wl = (const float*)d_in[6];
  const float* h2_bl = (const float*)d_in[7];
  const float* h2_wr = (const float*)d_in[8];
  const float* o1_wl = (const float*)d_in[9];
  const float* o1_bl = (const float*)d_in[10];
  const float* o1_wr = (const float*)d_in[11];
  const float* o2_wl = (const float*)d_in[12];
  const float* o2_bl = (const float*)d_in[13];
  const float* o2_wr = (const float*)d_in[14];
  const float* osc_w = (const float*)d_in[15];
  const float* osc_b = (const float*)d_in[16];
  float* out = (float*)d_out;

  char* ws = (char*)d_ws;
  size_t off = 0;
  auto alloc = [&](size_t bytes) -> char* {
    char* p = ws + off;
    off += (bytes + 255) & ~(size_t)255;
    return p;
  };
  short* xnF   = (short*)alloc(8192 * 128 * 2);  // fragment-major normalized x
  short* xb    = (short*)alloc(8192 * 128 * 2);
  short* w_inT = (short*)alloc(256 * 128 * 2);
  short* w1lT  = (short*)alloc(256 * 256 * 2);
  short* w1rT  = (short*)alloc(256 * 256 * 2);
  short* w2lT  = (short*)alloc(256 * 256 * 2);
  short* w2rT  = (short*)alloc(256 * 256 * 2);
  unsigned int* hist1 = (unsigned int*)alloc(1024 * 4);
  unsigned int* hist2 = (unsigned int*)alloc(8192 * 4);
  unsigned int* sel   = (unsigned int*)alloc(256);
  float* deg_inv = (float*)alloc(8192 * 4);
  float* ubuf  = (float*)alloc(8192 * 4);
  float* vbuf  = (float*)alloc(8192 * 4);
  float* scbuf = (float*)alloc(8192 * 4);
  float* o1buf = (float*)alloc(8192 * 4);
  unsigned long long* Awords = (unsigned long long*)alloc((size_t)8192 * 128 * 8);
  unsigned long long* AT     = (unsigned long long*)alloc((size_t)8192 * 128 * 8);
  short* h0  = (short*)alloc((size_t)8192 * 256 * 2);
  short* h1  = (short*)alloc((size_t)8192 * 256 * 2);
  short* h2  = (short*)alloc((size_t)8192 * 256 * 2);
  short* hF  = (short*)alloc((size_t)8192 * 256 * 2);
  short* agg = (short*)alloc((size_t)8192 * 256 * 2);
  // split-K: prefer 8 (512 blocks, 2/CU), fall back if workspace is tight
  const size_t SLICE = (size_t)8192 * 256 * 4;
  int nsplit = (ws_size >= off + 8 * SLICE + 4096) ? 8
             : (ws_size >= off + 4 * SLICE + 4096) ? 4 : 2;
  float* partials = (float*)alloc((size_t)nsplit * SLICE);
  const int ksplit = 8192 / nsplit;

  hipMemsetAsync(hist1, 0, (1024 + 8192) * 4, stream);
  prep_x_kernel<<<128, 256, 0, stream>>>(x, xb, xnF);
  prep_w_kernel<<<1152, 256, 0, stream>>>(w_in, h1_wl, h1_wr, h2_wl, h2_wr,
                                          w_inT, w1lT, w1rT, w2lT, w2rT);
  sim_kernel<0><<<NTRI / 4, 256, 0, stream>>>(xnF, hist1, sel, nullptr, nullptr);
  scan_kernel<1024, 0><<<1, 256, 0, stream>>>(hist1, sel);
  sim_kernel<1><<<NTRI / 4, 256, 0, stream>>>(xnF, hist2, sel, nullptr, nullptr);
  scan_kernel<8192, 1><<<1, 256, 0, stream>>>(hist2, sel);
  sim_kernel<2><<<NTRI / 4, 256, 0, stream>>>(xnF, nullptr, sel, Awords, AT);
  deg_kernel<<<2048, 256, 0, stream>>>(Awords, deg_inv);

  // h0 = relu(x @ w_in + b_in)
  lin_kernel<false, true, false><<<dim3(128, 4), 256, 0, stream>>>(
      xb, w_inT, 128, nullptr, nullptr, 0, b_in, nullptr, h0);
  // h1 = relu(agg(h0)@h1_wl + h1_bl + h0@h1_wr)
  packB_kernel<<<dim3(128, 4), 256, 0, stream>>>(h0, hF);
  aggA_kernel<<<dim3(64, nsplit), 256, 0, stream>>>(AT, hF, partials, ksplit);
  combine_kernel<<<2048, 256, 0, stream>>>(partials, nsplit, deg_inv, agg);
  lin_kernel<true, true, false><<<dim3(128, 4), 256, 0, stream>>>(
      agg, w1lT, 256, h0, w1rT, 256, h1_bl, nullptr, h1);
  // h2 = relu(agg(h1)@h2_wl + h2_bl + h1@h2_wr + h0)
  packB_kernel<<<dim3(128, 4), 256, 0, stream>>>(h1, hF);
  aggA_kernel<<<dim3(64, nsplit), 256, 0, stream>>>(AT, hF, partials, ksplit);
  combine_kernel<<<2048, 256, 0, stream>>>(partials, nsplit, deg_inv, agg);
  lin_kernel<true, true, true><<<dim3(128, 4), 256, 0, stream>>>(
      agg, w2lT, 256, h1, w2rT, 256, h2_bl, h0, h2);
  // output block
  vec3_kernel<<<2048, 256, 0, stream>>>(h2, o1_wl, o1_wr, osc_w, osc_b, ubuf, vbuf, scbuf);
  aggv1_kernel<<<2048, 256, 0, stream>>>(Awords, ubuf, deg_inv, vbuf, o1_bl, o1buf);
  aggv2_kernel<<<2048, 256, 0, stream>>>(Awords, o1buf, deg_inv, o2_wl, o2_bl, o2_wr, scbuf, out);
}

// Round 7
// 354.963 us; speedup vs baseline: 1.4685x; 1.0336x over previous
//
#include <hip/hip_runtime.h>

// GNN_79937931313503: dynamic-graph SAGE GNN on MI355X.
// R7: sim histogram -> linear 4096-bin (low contention); aggA -> pure-VALU
// bit expansion (no LDS LUT, no barriers); split-K partials in bf16.

typedef __attribute__((ext_vector_type(8))) short s8v;   // 8 x bf16 (4 VGPR)
typedef __attribute__((ext_vector_type(4))) short s4v;   // 4 x bf16
typedef __attribute__((ext_vector_type(4))) float f4v;   // MFMA C/D frag

__device__ __forceinline__ f4v MFMA(s8v a, s8v b, f4v c) {
  return __builtin_amdgcn_mfma_f32_16x16x32_bf16(a, b, c, 0, 0, 0);
}
__device__ __forceinline__ short f2bf(float f) {  // RNE float->bf16 bits
  unsigned u = __float_as_uint(f);
  return (short)((u + 0x7FFFu + ((u >> 16) & 1u)) >> 16);
}
__device__ __forceinline__ float bf2f(short s) {
  return __uint_as_float(((unsigned)(unsigned short)s) << 16);
}

// ---------------- prep_x: norms + xb (row-major) + xnF (fragment-major) ----
__global__ __launch_bounds__(256) void prep_x_kernel(const float* __restrict__ x,
                                                     short* __restrict__ xb,
                                                     short* __restrict__ xnF) {
  const int w = threadIdx.x >> 6, lane = threadIdx.x & 63;
  const int rg = blockIdx.x * 4 + w;
  const int m = lane & 15, g = lane >> 4;
  const int row = rg * 16 + m;
  float v[4][8];
  float ss = 0.f;
#pragma unroll
  for (int kc = 0; kc < 4; ++kc) {
    const float* src = x + row * 128 + kc * 32 + g * 8;
    float4 a = *(const float4*)src;
    float4 b = *(const float4*)(src + 4);
    v[kc][0] = a.x; v[kc][1] = a.y; v[kc][2] = a.z; v[kc][3] = a.w;
    v[kc][4] = b.x; v[kc][5] = b.y; v[kc][6] = b.z; v[kc][7] = b.w;
#pragma unroll
    for (int e = 0; e < 8; ++e) ss += v[kc][e] * v[kc][e];
  }
  ss += __shfl_xor(ss, 16);
  ss += __shfl_xor(ss, 32);
  float inv = 1.0f / fmaxf(sqrtf(ss), 1e-8f);
#pragma unroll
  for (int kc = 0; kc < 4; ++kc) {
    s8v raw, nrm;
#pragma unroll
    for (int e = 0; e < 8; ++e) {
      raw[e] = f2bf(v[kc][e]);
      nrm[e] = f2bf(v[kc][e] * inv);
    }
    *(s8v*)(xb + row * 128 + kc * 32 + g * 8) = raw;
    *(s8v*)(xnF + (rg * 4 + kc) * 512 + lane * 8) = nrm;  // coalesced 1KB
  }
}

__global__ __launch_bounds__(256) void prep_w_kernel(
    const float* __restrict__ w_in, const float* __restrict__ w1l,
    const float* __restrict__ w1r, const float* __restrict__ w2l,
    const float* __restrict__ w2r, short* __restrict__ w_inT,
    short* __restrict__ w1lT, short* __restrict__ w1rT,
    short* __restrict__ w2lT, short* __restrict__ w2rT) {
  int idx = blockIdx.x * 256 + threadIdx.x;
  if (idx >= 294912) return;
  if (idx < 32768) {                       // w_in [128][256] -> [256][128]
    int n = idx >> 7, k = idx & 127;
    w_inT[idx] = f2bf(w_in[k * 256 + n]);
  } else {                                 // 4x [256][256] transposed
    int j = idx - 32768;
    int m = j >> 16, r = j & 65535;
    int n = r >> 8, k = r & 255;
    const float* src = (m == 0) ? w1l : (m == 1) ? w1r : (m == 2) ? w2l : w2r;
    short* dst = (m == 0) ? w1lT : (m == 1) ? w1rT : (m == 2) ? w2lT : w2rT;
    dst[r] = f2bf(src[k * 256 + n]);
  }
}

// ---------------- sim: per-wave 64x64 tiles, upper triangle only ----------------
// Linear binning: bin = clamp((int)(|s|*4096), 0, 4095). MODE 0: LDS 4096-bin
// weighted histogram. MODE 1: refine window [B1,B1+1)/4096 into 8192 sub-bins.
// MODE 2: adjacency bitmask (+ column-major AT) via ballot.
#define NT64 128
#define NTRI 8256  // 128*129/2
template <int MODE>
__global__ __launch_bounds__(256) void sim_kernel(
    const short* __restrict__ xnF, unsigned int* __restrict__ hist,
    unsigned int* __restrict__ sel, unsigned long long* __restrict__ Awords,
    unsigned long long* __restrict__ AT) {
  __shared__ unsigned int lh[MODE == 0 ? 4096 : 1];
  const int tid = threadIdx.x, w = tid >> 6, lane = tid & 63;
  if (MODE == 0) {
    for (int b = tid; b < 4096; b += 256) lh[b] = 0;
    __syncthreads();
  }
  int t = blockIdx.x * 4 + w;
  int r = (int)((257.0f - sqrtf((float)(257 * 257 - 8 * t))) * 0.5f);
  if (r < 0) r = 0;
  if (r > 127) r = 127;
  while (r < 127 && ((r + 1) * NT64 - (r + 1) * r / 2) <= t) ++r;
  while (r > 0 && (r * NT64 - r * (r - 1) / 2) > t) --r;
  const int c = r + (t - (r * NT64 - r * (r - 1) / 2));
  const int i0 = r * 64, j0 = c * 64;
  const bool diag = (r == c);

  f4v acc[4][4];
#pragma unroll
  for (int a = 0; a < 4; ++a)
#pragma unroll
    for (int b = 0; b < 4; ++b) acc[a][b] = (f4v){0.f, 0.f, 0.f, 0.f};

  const int rga = r * 4, rgb = c * 4;
#pragma unroll
  for (int kc = 0; kc < 4; ++kc) {
    s8v af[4], bf[4];
#pragma unroll
    for (int mt = 0; mt < 4; ++mt)
      af[mt] = *(const s8v*)(xnF + ((rga + mt) * 4 + kc) * 512 + lane * 8);
#pragma unroll
    for (int nt = 0; nt < 4; ++nt)
      bf[nt] = *(const s8v*)(xnF + ((rgb + nt) * 4 + kc) * 512 + lane * 8);
#pragma unroll
    for (int mt = 0; mt < 4; ++mt)
#pragma unroll
      for (int nt = 0; nt < 4; ++nt) acc[mt][nt] = MFMA(af[mt], bf[nt], acc[mt][nt]);
  }

  if (MODE == 0) {
    unsigned wgt = diag ? 1u : 2u;
#pragma unroll
    for (int mt = 0; mt < 4; ++mt)
      for (int nt = 0; nt < 4; ++nt)
        for (int rr = 0; rr < 4; ++rr) {
          float val = fabsf(acc[mt][nt][rr]);
          int bin = (int)(val * 4096.0f);
          bin = min(max(bin, 0), 4095);
          atomicAdd(&lh[bin], wgt);
        }
    __syncthreads();
    for (int b = tid; b < 4096; b += 256)
      if (lh[b]) atomicAdd(&hist[b], lh[b]);
  } else if (MODE == 1) {
    int pref = (int)sel[0];
    unsigned wgt = diag ? 1u : 2u;
#pragma unroll
    for (int mt = 0; mt < 4; ++mt)
      for (int nt = 0; nt < 4; ++nt)
        for (int rr = 0; rr < 4; ++rr) {
          float tt = fabsf(acc[mt][nt][rr]) * 4096.0f;
          int bin = min(max((int)tt, 0), 4095);
          if (bin == pref) {
            int b2 = (int)((tt - (float)pref) * 8192.0f);
            b2 = min(max(b2, 0), 8191);
            atomicAdd(&hist[b2], wgt);
          }
        }
  } else {
    float eps = __uint_as_float(sel[2]);
    unsigned long long myword = 0;  // lane j holds row (i0+j)'s bits [j0..j0+64)
#pragma unroll
    for (int mt = 0; mt < 4; ++mt)
#pragma unroll
      for (int rr = 0; rr < 4; ++rr) {
        unsigned long long b0 = __ballot(fabsf(acc[mt][0][rr]) >= eps);
        unsigned long long b1 = __ballot(fabsf(acc[mt][1][rr]) >= eps);
        unsigned long long b2 = __ballot(fabsf(acc[mt][2][rr]) >= eps);
        unsigned long long b3 = __ballot(fabsf(acc[mt][3][rr]) >= eps);
        if ((lane >> 4) == mt && (lane & 3) == rr) {
          int gj = (lane >> 2) & 3;
          myword = ((b0 >> (16 * gj)) & 0xFFFFull) |
                   (((b1 >> (16 * gj)) & 0xFFFFull) << 16) |
                   (((b2 >> (16 * gj)) & 0xFFFFull) << 32) |
                   (((b3 >> (16 * gj)) & 0xFFFFull) << 48);
        }
      }
    Awords[(size_t)(i0 + lane) * 128 + (j0 >> 6)] = myword;
    AT[(size_t)(j0 >> 6) * 8192 + i0 + lane] = myword;
    if (!diag) {  // mirrored tile via 64x64 bit transpose (ballot per column)
      unsigned long long tw = 0;
#pragma unroll
      for (int c2 = 0; c2 < 64; ++c2) {
        unsigned long long bc = __ballot((myword >> c2) & 1ull);
        if (lane == c2) tw = bc;
      }
      Awords[(size_t)(j0 + lane) * 128 + (i0 >> 6)] = tw;
      AT[(size_t)(i0 >> 6) * 8192 + j0 + lane] = tw;
    }
  }
}

// ---------------- histogram selection scan ----------------
// MODE 0 over 4096 linear bins -> sel[0]=bin, sel[1]=rank within bin.
// MODE 1 over 8192 sub-bins -> sel[2]=float bits of eps (lower edge).
template <int NB, int MODE>
__global__ __launch_bounds__(256) void scan_kernel(const unsigned int* __restrict__ hist,
                                                   unsigned int* __restrict__ sel) {
  __shared__ unsigned long long csum[256];
  const int t = threadIdx.x;
  const int PER = NB / 256;
  unsigned int vals[NB / 256];
  unsigned long long s = 0;
  for (int i = 0; i < PER; ++i) {
    vals[i] = hist[t * PER + i];
    s += vals[i];
  }
  csum[t] = s;
  __syncthreads();
  for (int o = 1; o < 256; o <<= 1) {
    unsigned long long prev = (t >= o) ? csum[t - o] : 0ull;
    __syncthreads();
    csum[t] += prev;
    __syncthreads();
  }
  unsigned long long K = (MODE == 0) ? 63753421ull : (unsigned long long)sel[1];
  unsigned long long inc = csum[t], exc = inc - s;
  if (K > exc && K <= inc) {
    unsigned long long c = exc;
    for (int i = 0; i < PER; ++i) {
      c += vals[i];
      if (c >= K) {
        if (MODE == 0) {
          sel[0] = (unsigned)(t * PER + i);
          sel[1] = (unsigned)(K - (c - vals[i]));
        } else {
          float eps = ((float)sel[0] + (float)(t * PER + i) * (1.0f / 8192.0f)) *
                      (1.0f / 4096.0f);
          sel[2] = __float_as_uint(eps);
        }
        break;
      }
    }
  }
}

// ---------------- degree ----------------
__global__ __launch_bounds__(256) void deg_kernel(const unsigned long long* __restrict__ Awords,
                                                  float* __restrict__ deg_inv) {
  int row = blockIdx.x * 4 + (threadIdx.x >> 6);
  int lane = threadIdx.x & 63;
  int c = __popcll(Awords[row * 128 + lane]) + __popcll(Awords[row * 128 + 64 + lane]);
  for (int o = 32; o; o >>= 1) c += __shfl_down(c, o);
  if (lane == 0) deg_inv[row] = 1.0f / (float)max(c, 1);
}

// ---------------- small NT linears ----------------
template <bool TWO, bool RELU, bool RES>
__global__ __launch_bounds__(256) void lin_kernel(
    const short* __restrict__ A1, const short* __restrict__ B1, int K1,
    const short* __restrict__ A2, const short* __restrict__ B2, int K2,
    const float* __restrict__ bias, const short* __restrict__ res,
    short* __restrict__ out) {
  const int i0 = blockIdx.x * 64, n0 = blockIdx.y * 64;
  const int tid = threadIdx.x, w = tid >> 6, lane = tid & 63;
  const int wy = (w >> 1) * 32, wx = (w & 1) * 32;
  const int lr = lane & 15, lk = (lane >> 4) * 8;
  f4v acc[2][2];
#pragma unroll
  for (int a = 0; a < 2; ++a)
#pragma unroll
    for (int b = 0; b < 2; ++b) acc[a][b] = (f4v){0.f, 0.f, 0.f, 0.f};

  for (int kc = 0; kc < K1; kc += 32) {
    s8v a0 = *(const s8v*)(A1 + (i0 + wy + lr) * K1 + kc + lk);
    s8v a1 = *(const s8v*)(A1 + (i0 + wy + 16 + lr) * K1 + kc + lk);
    s8v b0 = *(const s8v*)(B1 + (n0 + wx + lr) * K1 + kc + lk);
    s8v b1 = *(const s8v*)(B1 + (n0 + wx + 16 + lr) * K1 + kc + lk);
    acc[0][0] = MFMA(a0, b0, acc[0][0]);
    acc[0][1] = MFMA(a0, b1, acc[0][1]);
    acc[1][0] = MFMA(a1, b0, acc[1][0]);
    acc[1][1] = MFMA(a1, b1, acc[1][1]);
  }
  if constexpr (TWO) {
    for (int kc = 0; kc < K2; kc += 32) {
      s8v a0 = *(const s8v*)(A2 + (i0 + wy + lr) * K2 + kc + lk);
      s8v a1 = *(const s8v*)(A2 + (i0 + wy + 16 + lr) * K2 + kc + lk);
      s8v b0 = *(const s8v*)(B2 + (n0 + wx + lr) * K2 + kc + lk);
      s8v b1 = *(const s8v*)(B2 + (n0 + wx + 16 + lr) * K2 + kc + lk);
      acc[0][0] = MFMA(a0, b0, acc[0][0]);
      acc[0][1] = MFMA(a0, b1, acc[0][1]);
      acc[1][0] = MFMA(a1, b0, acc[1][0]);
      acc[1][1] = MFMA(a1, b1, acc[1][1]);
    }
  }
#pragma unroll
  for (int mt = 0; mt < 2; ++mt)
#pragma unroll
    for (int nt = 0; nt < 2; ++nt)
#pragma unroll
      for (int rr = 0; rr < 4; ++rr) {
        int row = i0 + wy + mt * 16 + (lane >> 4) * 4 + rr;
        int col = n0 + wx + nt * 16 + (lane & 15);
        float v = acc[mt][nt][rr] + bias[col];
        if constexpr (RES) v += bf2f(res[row * 256 + col]);
        if constexpr (RELU) v = fmaxf(v, 0.f);
        out[row * 256 + col] = f2bf(v);
      }
}

// ---------------- packB: h [8192][256] -> hF fragment-major ----------------
__global__ __launch_bounds__(256) void packB_kernel(const short* __restrict__ in,
                                                    short* __restrict__ hF) {
  __shared__ __align__(16) short T[64][80];
  const int i0 = blockIdx.x * 64, f0 = blockIdx.y * 64;
  const int t = threadIdx.x;
  const int r = t >> 2, c0 = (t & 3) * 16;
  s8v v0 = *(const s8v*)(in + (i0 + r) * 256 + f0 + c0);
  s8v v1 = *(const s8v*)(in + (i0 + r) * 256 + f0 + c0 + 8);
#pragma unroll
  for (int e = 0; e < 8; ++e) {
    T[c0 + e][r] = v0[e];       // T[feat][node]
    T[c0 + 8 + e][r] = v1[e];
  }
  __syncthreads();
  const int w = t >> 6, lane = t & 63;
  const int c = lane & 15, g = lane >> 4;
#pragma unroll
  for (int kc2 = 0; kc2 < 2; ++kc2) {
    s8v o = *(const s8v*)&T[w * 16 + c][kc2 * 32 + g * 8];
    size_t chunk = (size_t)((f0 >> 4) + w) * 256 + (i0 >> 5) + kc2;
    *(s8v*)(hF + chunk * 512 + lane * 8) = o;
  }
}

// ---------------- aggA: partial[z] = A[:, kslice] @ h[kslice, :] ------------
// Wave = 64 rows x 128 feats (mt=4, nt=8). Pure-VALU A expansion, no LDS,
// no barriers. Partials stored bf16.
__global__ __launch_bounds__(256, 2) void aggA_kernel(
    const unsigned long long* __restrict__ AT, const short* __restrict__ hF,
    short* __restrict__ partial, int ksplit) {
  const int i0 = blockIdx.x * 128;            // node rows
  const int k0 = blockIdx.y * ksplit;         // k split
  const int tid = threadIdx.x, w = tid >> 6, lane = tid & 63;
  const int wy = (w >> 1) * 64;               // row offset within block
  const int wx = (w & 1) * 128;               // feat offset within block
  const int lr = lane & 15, g = lane >> 4;
  const int g8 = g * 8;
  const short one = (short)0x3F80;

  f4v acc[4][8];
#pragma unroll
  for (int a = 0; a < 4; ++a)
#pragma unroll
    for (int b = 0; b < 8; ++b) acc[a][b] = (f4v){0.f, 0.f, 0.f, 0.f};

  for (int kb = k0; kb < k0 + ksplit; kb += 64) {
    unsigned long long aw[4];
#pragma unroll
    for (int mt = 0; mt < 4; ++mt)
      aw[mt] = AT[(size_t)(kb >> 6) * 8192 + i0 + wy + mt * 16 + lr];
#pragma unroll
    for (int kc = 0; kc < 2; ++kc) {
      s8v bf[8];
#pragma unroll
      for (int nt = 0; nt < 8; ++nt) {
        size_t chunk = (size_t)((wx >> 4) + nt) * 256 + (kb >> 5) + kc;
        bf[nt] = *(const s8v*)(hF + chunk * 512 + lane * 8);
      }
#pragma unroll
      for (int mt = 0; mt < 4; ++mt) {
        unsigned byte = ((unsigned)(aw[mt] >> (kc * 32)) >> g8) & 0xFFu;
        s8v a;
#pragma unroll
        for (int e = 0; e < 8; ++e) a[e] = ((byte >> e) & 1u) ? one : (short)0;
#pragma unroll
        for (int nt = 0; nt < 8; ++nt) acc[mt][nt] = MFMA(a, bf[nt], acc[mt][nt]);
      }
    }
  }
  short* P = partial + (size_t)blockIdx.y * (8192 * 256);
#pragma unroll
  for (int mt = 0; mt < 4; ++mt)
#pragma unroll
    for (int nt = 0; nt < 8; ++nt)
#pragma unroll
      for (int rr = 0; rr < 4; ++rr) {
        int row = i0 + wy + mt * 16 + g * 4 + rr;
        int col = wx + nt * 16 + lr;
        P[(size_t)row * 256 + col] = f2bf(acc[mt][nt][rr]);
      }
}

// combine: agg = bf16((sum_z partial[z]) * deg_inv[row]); 8 elems/thread
__global__ __launch_bounds__(256) void combine_kernel(const short* __restrict__ p, int nsplit,
                                                      const float* __restrict__ deg_inv,
                                                      short* __restrict__ agg) {
  int idx8 = blockIdx.x * 256 + threadIdx.x;  // group of 8 elems
  float s[8];
#pragma unroll
  for (int e = 0; e < 8; ++e) s[e] = 0.f;
  for (int k = 0; k < nsplit; ++k) {
    s8v v = *(const s8v*)(p + (size_t)k * 2097152 + (size_t)idx8 * 8);
#pragma unroll
    for (int e = 0; e < 8; ++e) s[e] += bf2f(v[e]);
  }
  float di = deg_inv[idx8 >> 5];
  s8v o;
#pragma unroll
  for (int e = 0; e < 8; ++e) o[e] = f2bf(s[e] * di);
  *(s8v*)(agg + (size_t)idx8 * 8) = o;
}

// ---------------- tail ----------------
__global__ __launch_bounds__(256) void vec3_kernel(const short* __restrict__ h2,
                                                   const float* __restrict__ o1wl,
                                                   const float* __restrict__ o1wr,
                                                   const float* __restrict__ oscw,
                                                   const float* __restrict__ oscb,
                                                   float* __restrict__ u, float* __restrict__ v,
                                                   float* __restrict__ sc) {
  int row = blockIdx.x * 4 + (threadIdx.x >> 6);
  int lane = threadIdx.x & 63;
  float su = 0.f, sv = 0.f, ss = 0.f;
#pragma unroll
  for (int e = 0; e < 4; ++e) {
    int k = lane * 4 + e;
    float hv = bf2f(h2[row * 256 + k]);
    su += hv * o1wl[k];
    sv += hv * o1wr[k];
    ss += hv * oscw[k];
  }
  for (int o = 1; o < 64; o <<= 1) {
    su += __shfl_xor(su, o);
    sv += __shfl_xor(sv, o);
    ss += __shfl_xor(ss, o);
  }
  if (lane == 0) {
    u[row] = su;
    v[row] = sv;
    sc[row] = ss + oscb[0];
  }
}

__global__ __launch_bounds__(256) void aggv1_kernel(const unsigned long long* __restrict__ Awords,
                                                    const float* __restrict__ u,
                                                    const float* __restrict__ deg_inv,
                                                    const float* __restrict__ v,
                                                    const float* __restrict__ o1bl,
                                                    float* __restrict__ o1) {
  int row = blockIdx.x * 4 + (threadIdx.x >> 6);
  int lane = threadIdx.x & 63;
  float s = 0.f;
#pragma unroll
  for (int wi = 0; wi < 2; ++wi) {
    unsigned long long bits = Awords[row * 128 + wi * 64 + lane];
    int base = (wi * 64 + lane) * 64;
    while (bits) {
      int b = __ffsll(bits) - 1;
      s += u[base + b];
      bits &= bits - 1;
    }
  }
  for (int o = 1; o < 64; o <<= 1) s += __shfl_xor(s, o);
  if (lane == 0) o1[row] = fmaxf(s * deg_inv[row] + o1bl[0] + v[row], 0.f);
}

__global__ __launch_bounds__(256) void aggv2_kernel(const unsigned long long* __restrict__ Awords,
                                                    const float* __restrict__ o1,
                                                    const float* __restrict__ deg_inv,
                                                    const float* __restrict__ o2wl,
                                                    const float* __restrict__ o2bl,
                                                    const float* __restrict__ o2wr,
                                                    const float* __restrict__ sc,
                                                    float* __restrict__ out) {
  int row = blockIdx.x * 4 + (threadIdx.x >> 6);
  int lane = threadIdx.x & 63;
  float s = 0.f;
#pragma unroll
  for (int wi = 0; wi < 2; ++wi) {
    unsigned long long bits = Awords[row * 128 + wi * 64 + lane];
    int base = (wi * 64 + lane) * 64;
    while (bits) {
      int b = __ffsll(bits) - 1;
      s += o1[base + b];
      bits &= bits - 1;
    }
  }
  for (int o = 1; o < 64; o <<= 1) s += __shfl_xor(s, o);
  if (lane == 0) {
    float z = s * deg_inv[row] * o2wl[0] + o2bl[0] + o1[row] * o2wr[0] + sc[row];
    out[row] = 1.f / (1.f + expf(-z));
  }
}

// ---------------- launch ----------------
extern "C" void kernel_launch(void* const* d_in, const int* in_sizes, int n_in,
                              void* d_out, int out_size, void* d_ws, size_t ws_size,
                              hipStream_t stream) {
  (void)in_sizes; (void)n_in; (void)out_size;
  const float* x     = (const float*)d_in[0];
  const float* w_in  = (const float*)d_in[1];
  const float* b_in  = (const float*)d_in[2];
  const float* h1_wl = (const float*)d_in[3];
  const float* h1_bl = (const float*)d_in[4];
  const float* h1_wr = (const float*)d_in[5];
  const float* h2_wl = (const float*)d_in[6];
  const float* h2_bl = (const float*)d_in[7];
  const float* h2_wr = (const float*)d_in[8];
  const float* o1_wl = (const float*)d_in[9];
  const float* o1_bl = (const float*)d_in[10];
  const float* o1_wr = (const float*)d_in[11];
  const float* o2_wl = (const float*)d_in[12];
  const float* o2_bl = (const float*)d_in[13];
  const float* o2_wr = (const float*)d_in[14];
  const float* osc_w = (const float*)d_in[15];
  const float* osc_b = (const float*)d_in[16];
  float* out = (float*)d_out;

  char* ws = (char*)d_ws;
  size_t off = 0;
  auto alloc = [&](size_t bytes) -> char* {
    char* p = ws + off;
    off += (bytes + 255) & ~(size_t)255;
    return p;
  };
  short* xnF   = (short*)alloc(8192 * 128 * 2);  // fragment-major normalized x
  short* xb    = (short*)alloc(8192 * 128 * 2);
  short* w_inT = (short*)alloc(256 * 128 * 2);
  short* w1lT  = (short*)alloc(256 * 256 * 2);
  short* w1rT  = (short*)alloc(256 * 256 * 2);
  short* w2lT  = (short*)alloc(256 * 256 * 2);
  short* w2rT  = (short*)alloc(256 * 256 * 2);
  unsigned int* hist1 = (unsigned int*)alloc(4096 * 4);
  unsigned int* hist2 = (unsigned int*)alloc(8192 * 4);
  unsigned int* sel   = (unsigned int*)alloc(256);
  float* deg_inv = (float*)alloc(8192 * 4);
  float* ubuf  = (float*)alloc(8192 * 4);
  float* vbuf  = (float*)alloc(8192 * 4);
  float* scbuf = (float*)alloc(8192 * 4);
  float* o1buf = (float*)alloc(8192 * 4);
  unsigned long long* Awords = (unsigned long long*)alloc((size_t)8192 * 128 * 8);
  unsigned long long* AT     = (unsigned long long*)alloc((size_t)8192 * 128 * 8);
  short* h0  = (short*)alloc((size_t)8192 * 256 * 2);
  short* h1  = (short*)alloc((size_t)8192 * 256 * 2);
  short* h2  = (short*)alloc((size_t)8192 * 256 * 2);
  short* hF  = (short*)alloc((size_t)8192 * 256 * 2);
  short* agg = (short*)alloc((size_t)8192 * 256 * 2);
  // split-K: prefer 8 (512 blocks, 2/CU); bf16 partial slices of 4 MB
  const size_t SLICE = (size_t)8192 * 256 * 2;
  int nsplit = (ws_size >= off + 8 * SLICE + 4096) ? 8
             : (ws_size >= off + 4 * SLICE + 4096) ? 4 : 2;
  short* partials = (short*)alloc((size_t)nsplit * SLICE);
  const int ksplit = 8192 / nsplit;

  hipMemsetAsync(hist1, 0, (4096 + 8192) * 4, stream);
  prep_x_kernel<<<128, 256, 0, stream>>>(x, xb, xnF);
  prep_w_kernel<<<1152, 256, 0, stream>>>(w_in, h1_wl, h1_wr, h2_wl, h2_wr,
                                          w_inT, w1lT, w1rT, w2lT, w2rT);
  sim_kernel<0><<<NTRI / 4, 256, 0, stream>>>(xnF, hist1, sel, nullptr, nullptr);
  scan_kernel<4096, 0><<<1, 256, 0, stream>>>(hist1, sel);
  sim_kernel<1><<<NTRI / 4, 256, 0, stream>>>(xnF, hist2, sel, nullptr, nullptr);
  scan_kernel<8192, 1><<<1, 256, 0, stream>>>(hist2, sel);
  sim_kernel<2><<<NTRI / 4, 256, 0, stream>>>(xnF, nullptr, sel, Awords, AT);
  deg_kernel<<<2048, 256, 0, stream>>>(Awords, deg_inv);

  // h0 = relu(x @ w_in + b_in)
  lin_kernel<false, true, false><<<dim3(128, 4), 256, 0, stream>>>(
      xb, w_inT, 128, nullptr, nullptr, 0, b_in, nullptr, h0);
  // h1 = relu(agg(h0)@h1_wl + h1_bl + h0@h1_wr)
  packB_kernel<<<dim3(128, 4), 256, 0, stream>>>(h0, hF);
  aggA_kernel<<<dim3(64, nsplit), 256, 0, stream>>>(AT, hF, partials, ksplit);
  combine_kernel<<<1024, 256, 0, stream>>>(partials, nsplit, deg_inv, agg);
  lin_kernel<true, true, false><<<dim3(128, 4), 256, 0, stream>>>(
      agg, w1lT, 256, h0, w1rT, 256, h1_bl, nullptr, h1);
  // h2 = relu(agg(h1)@h2_wl + h2_bl + h1@h2_wr + h0)
  packB_kernel<<<dim3(128, 4), 256, 0, stream>>>(h1, hF);
  aggA_kernel<<<dim3(64, nsplit), 256, 0, stream>>>(AT, hF, partials, ksplit);
  combine_kernel<<<1024, 256, 0, stream>>>(partials, nsplit, deg_inv, agg);
  lin_kernel<true, true, true><<<dim3(128, 4), 256, 0, stream>>>(
      agg, w2lT, 256, h1, w2rT, 256, h2_bl, h0, h2);
  // output block
  vec3_kernel<<<2048, 256, 0, stream>>>(h2, o1_wl, o1_wr, osc_w, osc_b, ubuf, vbuf, scbuf);
  aggv1_kernel<<<2048, 256, 0, stream>>>(Awords, ubuf, deg_inv, vbuf, o1_bl, o1buf);
  aggv2_kernel<<<2048, 256, 0, stream>>>(Awords, o1buf, deg_inv, o2_wl, o2_bl, o2_wr, scbuf, out);
}

// Round 8
// 329.999 us; speedup vs baseline: 1.5796x; 1.0756x over previous
//
#include <hip/hip_runtime.h>

// GNN_79937931313503: dynamic-graph SAGE GNN on MI355X.
// R8: sim MODE 0 -> persistent grid-stride histogram (512 blocks, one LDS
// flush at end, 8-way-replicated global hist to kill L2 atomic serialization).

typedef __attribute__((ext_vector_type(8))) short s8v;   // 8 x bf16 (4 VGPR)
typedef __attribute__((ext_vector_type(4))) short s4v;   // 4 x bf16
typedef __attribute__((ext_vector_type(4))) float f4v;   // MFMA C/D frag

__device__ __forceinline__ f4v MFMA(s8v a, s8v b, f4v c) {
  return __builtin_amdgcn_mfma_f32_16x16x32_bf16(a, b, c, 0, 0, 0);
}
__device__ __forceinline__ short f2bf(float f) {  // RNE float->bf16 bits
  unsigned u = __float_as_uint(f);
  return (short)((u + 0x7FFFu + ((u >> 16) & 1u)) >> 16);
}
__device__ __forceinline__ float bf2f(short s) {
  return __uint_as_float(((unsigned)(unsigned short)s) << 16);
}

#define NT64 128
#define NTRI 8256  // 128*129/2
#define NHC 8      // global histogram copies

__device__ __forceinline__ void tri_invert(int t, int& r, int& c) {
  int rr = (int)((257.0f - sqrtf((float)(257 * 257 - 8 * t))) * 0.5f);
  if (rr < 0) rr = 0;
  if (rr > 127) rr = 127;
  while (rr < 127 && ((rr + 1) * NT64 - (rr + 1) * rr / 2) <= t) ++rr;
  while (rr > 0 && (rr * NT64 - rr * (rr - 1) / 2) > t) --rr;
  r = rr;
  c = rr + (t - (rr * NT64 - rr * (rr - 1) / 2));
}

// ---------------- prep_x: norms + xb (row-major) + xnF (fragment-major) ----
__global__ __launch_bounds__(256) void prep_x_kernel(const float* __restrict__ x,
                                                     short* __restrict__ xb,
                                                     short* __restrict__ xnF) {
  const int w = threadIdx.x >> 6, lane = threadIdx.x & 63;
  const int rg = blockIdx.x * 4 + w;
  const int m = lane & 15, g = lane >> 4;
  const int row = rg * 16 + m;
  float v[4][8];
  float ss = 0.f;
#pragma unroll
  for (int kc = 0; kc < 4; ++kc) {
    const float* src = x + row * 128 + kc * 32 + g * 8;
    float4 a = *(const float4*)src;
    float4 b = *(const float4*)(src + 4);
    v[kc][0] = a.x; v[kc][1] = a.y; v[kc][2] = a.z; v[kc][3] = a.w;
    v[kc][4] = b.x; v[kc][5] = b.y; v[kc][6] = b.z; v[kc][7] = b.w;
#pragma unroll
    for (int e = 0; e < 8; ++e) ss += v[kc][e] * v[kc][e];
  }
  ss += __shfl_xor(ss, 16);
  ss += __shfl_xor(ss, 32);
  float inv = 1.0f / fmaxf(sqrtf(ss), 1e-8f);
#pragma unroll
  for (int kc = 0; kc < 4; ++kc) {
    s8v raw, nrm;
#pragma unroll
    for (int e = 0; e < 8; ++e) {
      raw[e] = f2bf(v[kc][e]);
      nrm[e] = f2bf(v[kc][e] * inv);
    }
    *(s8v*)(xb + row * 128 + kc * 32 + g * 8) = raw;
    *(s8v*)(xnF + (rg * 4 + kc) * 512 + lane * 8) = nrm;  // coalesced 1KB
  }
}

__global__ __launch_bounds__(256) void prep_w_kernel(
    const float* __restrict__ w_in, const float* __restrict__ w1l,
    const float* __restrict__ w1r, const float* __restrict__ w2l,
    const float* __restrict__ w2r, short* __restrict__ w_inT,
    short* __restrict__ w1lT, short* __restrict__ w1rT,
    short* __restrict__ w2lT, short* __restrict__ w2rT) {
  int idx = blockIdx.x * 256 + threadIdx.x;
  if (idx >= 294912) return;
  if (idx < 32768) {                       // w_in [128][256] -> [256][128]
    int n = idx >> 7, k = idx & 127;
    w_inT[idx] = f2bf(w_in[k * 256 + n]);
  } else {                                 // 4x [256][256] transposed
    int j = idx - 32768;
    int m = j >> 16, r = j & 65535;
    int n = r >> 8, k = r & 255;
    const float* src = (m == 0) ? w1l : (m == 1) ? w1r : (m == 2) ? w2l : w2r;
    short* dst = (m == 0) ? w1lT : (m == 1) ? w1rT : (m == 2) ? w2lT : w2rT;
    dst[r] = f2bf(src[k * 256 + n]);
  }
}

// ---------------- hist0: persistent grid-stride linear histogram ----------
// 512 blocks; each processes tile-groups tg = blockIdx.x + 512*i, flushes its
// 4096-bin LDS hist ONCE into global copy (blockIdx.x & (NHC-1)).
__global__ __launch_bounds__(256) void hist0_kernel(const short* __restrict__ xnF,
                                                    unsigned int* __restrict__ hist) {
  __shared__ unsigned int lh[4096];
  const int tid = threadIdx.x, w = tid >> 6, lane = tid & 63;
  for (int b = tid; b < 4096; b += 256) lh[b] = 0;
  __syncthreads();

  for (int tg = blockIdx.x; tg < NTRI / 4; tg += gridDim.x) {
    int t = tg * 4 + w;
    int r, c;
    tri_invert(t, r, c);
    const bool diag = (r == c);
    f4v acc[4][4];
#pragma unroll
    for (int a = 0; a < 4; ++a)
#pragma unroll
      for (int b = 0; b < 4; ++b) acc[a][b] = (f4v){0.f, 0.f, 0.f, 0.f};
    const int rga = r * 4, rgb = c * 4;
#pragma unroll
    for (int kc = 0; kc < 4; ++kc) {
      s8v af[4], bf[4];
#pragma unroll
      for (int mt = 0; mt < 4; ++mt)
        af[mt] = *(const s8v*)(xnF + ((rga + mt) * 4 + kc) * 512 + lane * 8);
#pragma unroll
      for (int nt = 0; nt < 4; ++nt)
        bf[nt] = *(const s8v*)(xnF + ((rgb + nt) * 4 + kc) * 512 + lane * 8);
#pragma unroll
      for (int mt = 0; mt < 4; ++mt)
#pragma unroll
        for (int nt = 0; nt < 4; ++nt) acc[mt][nt] = MFMA(af[mt], bf[nt], acc[mt][nt]);
    }
    unsigned wgt = diag ? 1u : 2u;
#pragma unroll
    for (int mt = 0; mt < 4; ++mt)
      for (int nt = 0; nt < 4; ++nt)
        for (int rr = 0; rr < 4; ++rr) {
          float val = fabsf(acc[mt][nt][rr]);
          int bin = (int)(val * 4096.0f);
          bin = min(max(bin, 0), 4095);
          atomicAdd(&lh[bin], wgt);
        }
  }
  __syncthreads();
  unsigned int* hc = hist + (blockIdx.x & (NHC - 1)) * 4096;
  for (int b = tid; b < 4096; b += 256)
    if (lh[b]) atomicAdd(&hc[b], lh[b]);
}

// ---------------- sim: per-wave 64x64 tiles, upper triangle only ----------------
// MODE 1: refine window [B1,B1+1)/4096 into 8192 sub-bins (global atomics,
// sparse). MODE 2: adjacency bitmask (+ column-major AT) via ballot.
template <int MODE>
__global__ __launch_bounds__(256) void sim_kernel(
    const short* __restrict__ xnF, unsigned int* __restrict__ hist,
    unsigned int* __restrict__ sel, unsigned long long* __restrict__ Awords,
    unsigned long long* __restrict__ AT) {
  const int tid = threadIdx.x, w = tid >> 6, lane = tid & 63;
  int t = blockIdx.x * 4 + w;
  int r, c;
  tri_invert(t, r, c);
  const int i0 = r * 64, j0 = c * 64;
  const bool diag = (r == c);

  f4v acc[4][4];
#pragma unroll
  for (int a = 0; a < 4; ++a)
#pragma unroll
    for (int b = 0; b < 4; ++b) acc[a][b] = (f4v){0.f, 0.f, 0.f, 0.f};

  const int rga = r * 4, rgb = c * 4;
#pragma unroll
  for (int kc = 0; kc < 4; ++kc) {
    s8v af[4], bf[4];
#pragma unroll
    for (int mt = 0; mt < 4; ++mt)
      af[mt] = *(const s8v*)(xnF + ((rga + mt) * 4 + kc) * 512 + lane * 8);
#pragma unroll
    for (int nt = 0; nt < 4; ++nt)
      bf[nt] = *(const s8v*)(xnF + ((rgb + nt) * 4 + kc) * 512 + lane * 8);
#pragma unroll
    for (int mt = 0; mt < 4; ++mt)
#pragma unroll
      for (int nt = 0; nt < 4; ++nt) acc[mt][nt] = MFMA(af[mt], bf[nt], acc[mt][nt]);
  }

  if (MODE == 1) {
    int pref = (int)sel[0];
    unsigned wgt = diag ? 1u : 2u;
#pragma unroll
    for (int mt = 0; mt < 4; ++mt)
      for (int nt = 0; nt < 4; ++nt)
        for (int rr = 0; rr < 4; ++rr) {
          float tt = fabsf(acc[mt][nt][rr]) * 4096.0f;
          int bin = min(max((int)tt, 0), 4095);
          if (bin == pref) {
            int b2 = (int)((tt - (float)pref) * 8192.0f);
            b2 = min(max(b2, 0), 8191);
            atomicAdd(&hist[b2], wgt);
          }
        }
  } else {
    float eps = __uint_as_float(sel[2]);
    unsigned long long myword = 0;  // lane j holds row (i0+j)'s bits [j0..j0+64)
#pragma unroll
    for (int mt = 0; mt < 4; ++mt)
#pragma unroll
      for (int rr = 0; rr < 4; ++rr) {
        unsigned long long b0 = __ballot(fabsf(acc[mt][0][rr]) >= eps);
        unsigned long long b1 = __ballot(fabsf(acc[mt][1][rr]) >= eps);
        unsigned long long b2 = __ballot(fabsf(acc[mt][2][rr]) >= eps);
        unsigned long long b3 = __ballot(fabsf(acc[mt][3][rr]) >= eps);
        if ((lane >> 4) == mt && (lane & 3) == rr) {
          int gj = (lane >> 2) & 3;
          myword = ((b0 >> (16 * gj)) & 0xFFFFull) |
                   (((b1 >> (16 * gj)) & 0xFFFFull) << 16) |
                   (((b2 >> (16 * gj)) & 0xFFFFull) << 32) |
                   (((b3 >> (16 * gj)) & 0xFFFFull) << 48);
        }
      }
    Awords[(size_t)(i0 + lane) * 128 + (j0 >> 6)] = myword;
    AT[(size_t)(j0 >> 6) * 8192 + i0 + lane] = myword;
    if (!diag) {  // mirrored tile via 64x64 bit transpose (ballot per column)
      unsigned long long tw = 0;
#pragma unroll
      for (int c2 = 0; c2 < 64; ++c2) {
        unsigned long long bc = __ballot((myword >> c2) & 1ull);
        if (lane == c2) tw = bc;
      }
      Awords[(size_t)(j0 + lane) * 128 + (i0 >> 6)] = tw;
      AT[(size_t)(i0 >> 6) * 8192 + j0 + lane] = tw;
    }
  }
}

// ---------------- histogram selection scan ----------------
// MODE 0 over 4096 linear bins (summing NHC copies) -> sel[0]=bin, sel[1]=rank.
// MODE 1 over 8192 sub-bins -> sel[2]=float bits of eps (lower edge).
template <int NB, int MODE>
__global__ __launch_bounds__(256) void scan_kernel(const unsigned int* __restrict__ hist,
                                                   unsigned int* __restrict__ sel) {
  __shared__ unsigned long long csum[256];
  const int t = threadIdx.x;
  const int PER = NB / 256;
  unsigned int vals[NB / 256];
  unsigned long long s = 0;
  for (int i = 0; i < PER; ++i) {
    unsigned v = 0;
    if (MODE == 0) {
      for (int cc = 0; cc < NHC; ++cc) v += hist[cc * NB + t * PER + i];
    } else {
      v = hist[t * PER + i];
    }
    vals[i] = v;
    s += v;
  }
  csum[t] = s;
  __syncthreads();
  for (int o = 1; o < 256; o <<= 1) {
    unsigned long long prev = (t >= o) ? csum[t - o] : 0ull;
    __syncthreads();
    csum[t] += prev;
    __syncthreads();
  }
  unsigned long long K = (MODE == 0) ? 63753421ull : (unsigned long long)sel[1];
  unsigned long long inc = csum[t], exc = inc - s;
  if (K > exc && K <= inc) {
    unsigned long long c = exc;
    for (int i = 0; i < PER; ++i) {
      c += vals[i];
      if (c >= K) {
        if (MODE == 0) {
          sel[0] = (unsigned)(t * PER + i);
          sel[1] = (unsigned)(K - (c - vals[i]));
        } else {
          float eps = ((float)sel[0] + (float)(t * PER + i) * (1.0f / 8192.0f)) *
                      (1.0f / 4096.0f);
          sel[2] = __float_as_uint(eps);
        }
        break;
      }
    }
  }
}

// ---------------- degree ----------------
__global__ __launch_bounds__(256) void deg_kernel(const unsigned long long* __restrict__ Awords,
                                                  float* __restrict__ deg_inv) {
  int row = blockIdx.x * 4 + (threadIdx.x >> 6);
  int lane = threadIdx.x & 63;
  int c = __popcll(Awords[row * 128 + lane]) + __popcll(Awords[row * 128 + 64 + lane]);
  for (int o = 32; o; o >>= 1) c += __shfl_down(c, o);
  if (lane == 0) deg_inv[row] = 1.0f / (float)max(c, 1);
}

// ---------------- small NT linears ----------------
template <bool TWO, bool RELU, bool RES>
__global__ __launch_bounds__(256) void lin_kernel(
    const short* __restrict__ A1, const short* __restrict__ B1, int K1,
    const short* __restrict__ A2, const short* __restrict__ B2, int K2,
    const float* __restrict__ bias, const short* __restrict__ res,
    short* __restrict__ out) {
  const int i0 = blockIdx.x * 64, n0 = blockIdx.y * 64;
  const int tid = threadIdx.x, w = tid >> 6, lane = tid & 63;
  const int wy = (w >> 1) * 32, wx = (w & 1) * 32;
  const int lr = lane & 15, lk = (lane >> 4) * 8;
  f4v acc[2][2];
#pragma unroll
  for (int a = 0; a < 2; ++a)
#pragma unroll
    for (int b = 0; b < 2; ++b) acc[a][b] = (f4v){0.f, 0.f, 0.f, 0.f};

  for (int kc = 0; kc < K1; kc += 32) {
    s8v a0 = *(const s8v*)(A1 + (i0 + wy + lr) * K1 + kc + lk);
    s8v a1 = *(const s8v*)(A1 + (i0 + wy + 16 + lr) * K1 + kc + lk);
    s8v b0 = *(const s8v*)(B1 + (n0 + wx + lr) * K1 + kc + lk);
    s8v b1 = *(const s8v*)(B1 + (n0 + wx + 16 + lr) * K1 + kc + lk);
    acc[0][0] = MFMA(a0, b0, acc[0][0]);
    acc[0][1] = MFMA(a0, b1, acc[0][1]);
    acc[1][0] = MFMA(a1, b0, acc[1][0]);
    acc[1][1] = MFMA(a1, b1, acc[1][1]);
  }
  if constexpr (TWO) {
    for (int kc = 0; kc < K2; kc += 32) {
      s8v a0 = *(const s8v*)(A2 + (i0 + wy + lr) * K2 + kc + lk);
      s8v a1 = *(const s8v*)(A2 + (i0 + wy + 16 + lr) * K2 + kc + lk);
      s8v b0 = *(const s8v*)(B2 + (n0 + wx + lr) * K2 + kc + lk);
      s8v b1 = *(const s8v*)(B2 + (n0 + wx + 16 + lr) * K2 + kc + lk);
      acc[0][0] = MFMA(a0, b0, acc[0][0]);
      acc[0][1] = MFMA(a0, b1, acc[0][1]);
      acc[1][0] = MFMA(a1, b0, acc[1][0]);
      acc[1][1] = MFMA(a1, b1, acc[1][1]);
    }
  }
#pragma unroll
  for (int mt = 0; mt < 2; ++mt)
#pragma unroll
    for (int nt = 0; nt < 2; ++nt)
#pragma unroll
      for (int rr = 0; rr < 4; ++rr) {
        int row = i0 + wy + mt * 16 + (lane >> 4) * 4 + rr;
        int col = n0 + wx + nt * 16 + (lane & 15);
        float v = acc[mt][nt][rr] + bias[col];
        if constexpr (RES) v += bf2f(res[row * 256 + col]);
        if constexpr (RELU) v = fmaxf(v, 0.f);
        out[row * 256 + col] = f2bf(v);
      }
}

// ---------------- packB: h [8192][256] -> hF fragment-major ----------------
__global__ __launch_bounds__(256) void packB_kernel(const short* __restrict__ in,
                                                    short* __restrict__ hF) {
  __shared__ __align__(16) short T[64][80];
  const int i0 = blockIdx.x * 64, f0 = blockIdx.y * 64;
  const int t = threadIdx.x;
  const int r = t >> 2, c0 = (t & 3) * 16;
  s8v v0 = *(const s8v*)(in + (i0 + r) * 256 + f0 + c0);
  s8v v1 = *(const s8v*)(in + (i0 + r) * 256 + f0 + c0 + 8);
#pragma unroll
  for (int e = 0; e < 8; ++e) {
    T[c0 + e][r] = v0[e];       // T[feat][node]
    T[c0 + 8 + e][r] = v1[e];
  }
  __syncthreads();
  const int w = t >> 6, lane = t & 63;
  const int c = lane & 15, g = lane >> 4;
#pragma unroll
  for (int kc2 = 0; kc2 < 2; ++kc2) {
    s8v o = *(const s8v*)&T[w * 16 + c][kc2 * 32 + g * 8];
    size_t chunk = (size_t)((f0 >> 4) + w) * 256 + (i0 >> 5) + kc2;
    *(s8v*)(hF + chunk * 512 + lane * 8) = o;
  }
}

// ---------------- aggA: partial[z] = A[:, kslice] @ h[kslice, :] ------------
__global__ __launch_bounds__(256, 2) void aggA_kernel(
    const unsigned long long* __restrict__ AT, const short* __restrict__ hF,
    short* __restrict__ partial, int ksplit) {
  const int i0 = blockIdx.x * 128;            // node rows
  const int k0 = blockIdx.y * ksplit;         // k split
  const int tid = threadIdx.x, w = tid >> 6, lane = tid & 63;
  const int wy = (w >> 1) * 64;               // row offset within block
  const int wx = (w & 1) * 128;               // feat offset within block
  const int lr = lane & 15, g = lane >> 4;
  const int g8 = g * 8;
  const short one = (short)0x3F80;

  f4v acc[4][8];
#pragma unroll
  for (int a = 0; a < 4; ++a)
#pragma unroll
    for (int b = 0; b < 8; ++b) acc[a][b] = (f4v){0.f, 0.f, 0.f, 0.f};

  for (int kb = k0; kb < k0 + ksplit; kb += 64) {
    unsigned long long aw[4];
#pragma unroll
    for (int mt = 0; mt < 4; ++mt)
      aw[mt] = AT[(size_t)(kb >> 6) * 8192 + i0 + wy + mt * 16 + lr];
#pragma unroll
    for (int kc = 0; kc < 2; ++kc) {
      s8v bf[8];
#pragma unroll
      for (int nt = 0; nt < 8; ++nt) {
        size_t chunk = (size_t)((wx >> 4) + nt) * 256 + (kb >> 5) + kc;
        bf[nt] = *(const s8v*)(hF + chunk * 512 + lane * 8);
      }
#pragma unroll
      for (int mt = 0; mt < 4; ++mt) {
        unsigned byte = ((unsigned)(aw[mt] >> (kc * 32)) >> g8) & 0xFFu;
        s8v a;
#pragma unroll
        for (int e = 0; e < 8; ++e) a[e] = ((byte >> e) & 1u) ? one : (short)0;
#pragma unroll
        for (int nt = 0; nt < 8; ++nt) acc[mt][nt] = MFMA(a, bf[nt], acc[mt][nt]);
      }
    }
  }
  short* P = partial + (size_t)blockIdx.y * (8192 * 256);
#pragma unroll
  for (int mt = 0; mt < 4; ++mt)
#pragma unroll
    for (int nt = 0; nt < 8; ++nt)
#pragma unroll
      for (int rr = 0; rr < 4; ++rr) {
        int row = i0 + wy + mt * 16 + g * 4 + rr;
        int col = wx + nt * 16 + lr;
        P[(size_t)row * 256 + col] = f2bf(acc[mt][nt][rr]);
      }
}

// combine: agg = bf16((sum_z partial[z]) * deg_inv[row]); 8 elems/thread
__global__ __launch_bounds__(256) void combine_kernel(const short* __restrict__ p, int nsplit,
                                                      const float* __restrict__ deg_inv,
                                                      short* __restrict__ agg) {
  int idx8 = blockIdx.x * 256 + threadIdx.x;  // group of 8 elems
  float s[8];
#pragma unroll
  for (int e = 0; e < 8; ++e) s[e] = 0.f;
  for (int k = 0; k < nsplit; ++k) {
    s8v v = *(const s8v*)(p + (size_t)k * 2097152 + (size_t)idx8 * 8);
#pragma unroll
    for (int e = 0; e < 8; ++e) s[e] += bf2f(v[e]);
  }
  float di = deg_inv[idx8 >> 5];
  s8v o;
#pragma unroll
  for (int e = 0; e < 8; ++e) o[e] = f2bf(s[e] * di);
  *(s8v*)(agg + (size_t)idx8 * 8) = o;
}

// ---------------- tail ----------------
__global__ __launch_bounds__(256) void vec3_kernel(const short* __restrict__ h2,
                                                   const float* __restrict__ o1wl,
                                                   const float* __restrict__ o1wr,
                                                   const float* __restrict__ oscw,
                                                   const float* __restrict__ oscb,
                                                   float* __restrict__ u, float* __restrict__ v,
                                                   float* __restrict__ sc) {
  int row = blockIdx.x * 4 + (threadIdx.x >> 6);
  int lane = threadIdx.x & 63;
  float su = 0.f, sv = 0.f, ss = 0.f;
#pragma unroll
  for (int e = 0; e < 4; ++e) {
    int k = lane * 4 + e;
    float hv = bf2f(h2[row * 256 + k]);
    su += hv * o1wl[k];
    sv += hv * o1wr[k];
    ss += hv * oscw[k];
  }
  for (int o = 1; o < 64; o <<= 1) {
    su += __shfl_xor(su, o);
    sv += __shfl_xor(sv, o);
    ss += __shfl_xor(ss, o);
  }
  if (lane == 0) {
    u[row] = su;
    v[row] = sv;
    sc[row] = ss + oscb[0];
  }
}

__global__ __launch_bounds__(256) void aggv1_kernel(const unsigned long long* __restrict__ Awords,
                                                    const float* __restrict__ u,
                                                    const float* __restrict__ deg_inv,
                                                    const float* __restrict__ v,
                                                    const float* __restrict__ o1bl,
                                                    float* __restrict__ o1) {
  int row = blockIdx.x * 4 + (threadIdx.x >> 6);
  int lane = threadIdx.x & 63;
  float s = 0.f;
#pragma unroll
  for (int wi = 0; wi < 2; ++wi) {
    unsigned long long bits = Awords[row * 128 + wi * 64 + lane];
    int base = (wi * 64 + lane) * 64;
    while (bits) {
      int b = __ffsll(bits) - 1;
      s += u[base + b];
      bits &= bits - 1;
    }
  }
  for (int o = 1; o < 64; o <<= 1) s += __shfl_xor(s, o);
  if (lane == 0) o1[row] = fmaxf(s * deg_inv[row] + o1bl[0] + v[row], 0.f);
}

__global__ __launch_bounds__(256) void aggv2_kernel(const unsigned long long* __restrict__ Awords,
                                                    const float* __restrict__ o1,
                                                    const float* __restrict__ deg_inv,
                                                    const float* __restrict__ o2wl,
                                                    const float* __restrict__ o2bl,
                                                    const float* __restrict__ o2wr,
                                                    const float* __restrict__ sc,
                                                    float* __restrict__ out) {
  int row = blockIdx.x * 4 + (threadIdx.x >> 6);
  int lane = threadIdx.x & 63;
  float s = 0.f;
#pragma unroll
  for (int wi = 0; wi < 2; ++wi) {
    unsigned long long bits = Awords[row * 128 + wi * 64 + lane];
    int base = (wi * 64 + lane) * 64;
    while (bits) {
      int b = __ffsll(bits) - 1;
      s += o1[base + b];
      bits &= bits - 1;
    }
  }
  for (int o = 1; o < 64; o <<= 1) s += __shfl_xor(s, o);
  if (lane == 0) {
    float z = s * deg_inv[row] * o2wl[0] + o2bl[0] + o1[row] * o2wr[0] + sc[row];
    out[row] = 1.f / (1.f + expf(-z));
  }
}

// ---------------- launch ----------------
extern "C" void kernel_launch(void* const* d_in, const int* in_sizes, int n_in,
                              void* d_out, int out_size, void* d_ws, size_t ws_size,
                              hipStream_t stream) {
  (void)in_sizes; (void)n_in; (void)out_size;
  const float* x     = (const float*)d_in[0];
  const float* w_in  = (const float*)d_in[1];
  const float* b_in  = (const float*)d_in[2];
  const float* h1_wl = (const float*)d_in[3];
  const float* h1_bl = (const float*)d_in[4];
  const float* h1_wr = (const float*)d_in[5];
  const float* h2_wl = (const float*)d_in[6];
  const float* h2_bl = (const float*)d_in[7];
  const float* h2_wr = (const float*)d_in[8];
  const float* o1_wl = (const float*)d_in[9];
  const float* o1_bl = (const float*)d_in[10];
  const float* o1_wr = (const float*)d_in[11];
  const float* o2_wl = (const float*)d_in[12];
  const float* o2_bl = (const float*)d_in[13];
  const float* o2_wr = (const float*)d_in[14];
  const float* osc_w = (const float*)d_in[15];
  const float* osc_b = (const float*)d_in[16];
  float* out = (float*)d_out;

  char* ws = (char*)d_ws;
  size_t off = 0;
  auto alloc = [&](size_t bytes) -> char* {
    char* p = ws + off;
    off += (bytes + 255) & ~(size_t)255;
    return p;
  };
  short* xnF   = (short*)alloc(8192 * 128 * 2);  // fragment-major normalized x
  short* xb    = (short*)alloc(8192 * 128 * 2);
  short* w_inT = (short*)alloc(256 * 128 * 2);
  short* w1lT  = (short*)alloc(256 * 256 * 2);
  short* w1rT  = (short*)alloc(256 * 256 * 2);
  short* w2lT  = (short*)alloc(256 * 256 * 2);
  short* w2rT  = (short*)alloc(256 * 256 * 2);
  unsigned int* hist1 = (unsigned int*)alloc(NHC * 4096 * 4);
  unsigned int* hist2 = (unsigned int*)alloc(8192 * 4);
  unsigned int* sel   = (unsigned int*)alloc(256);
  float* deg_inv = (float*)alloc(8192 * 4);
  float* ubuf  = (float*)alloc(8192 * 4);
  float* vbuf  = (float*)alloc(8192 * 4);
  float* scbuf = (float*)alloc(8192 * 4);
  float* o1buf = (float*)alloc(8192 * 4);
  unsigned long long* Awords = (unsigned long long*)alloc((size_t)8192 * 128 * 8);
  unsigned long long* AT     = (unsigned long long*)alloc((size_t)8192 * 128 * 8);
  short* h0  = (short*)alloc((size_t)8192 * 256 * 2);
  short* h1  = (short*)alloc((size_t)8192 * 256 * 2);
  short* h2  = (short*)alloc((size_t)8192 * 256 * 2);
  short* hF  = (short*)alloc((size_t)8192 * 256 * 2);
  short* agg = (short*)alloc((size_t)8192 * 256 * 2);
  // split-K: prefer 8 (512 blocks, 2/CU); bf16 partial slices of 4 MB
  const size_t SLICE = (size_t)8192 * 256 * 2;
  int nsplit = (ws_size >= off + 8 * SLICE + 4096) ? 8
             : (ws_size >= off + 4 * SLICE + 4096) ? 4 : 2;
  short* partials = (short*)alloc((size_t)nsplit * SLICE);
  const int ksplit = 8192 / nsplit;

  hipMemsetAsync(hist1, 0, (NHC * 4096 + 8192) * 4, stream);
  prep_x_kernel<<<128, 256, 0, stream>>>(x, xb, xnF);
  prep_w_kernel<<<1152, 256, 0, stream>>>(w_in, h1_wl, h1_wr, h2_wl, h2_wr,
                                          w_inT, w1lT, w1rT, w2lT, w2rT);
  hist0_kernel<<<512, 256, 0, stream>>>(xnF, hist1);
  scan_kernel<4096, 0><<<1, 256, 0, stream>>>(hist1, sel);
  sim_kernel<1><<<NTRI / 4, 256, 0, stream>>>(xnF, hist2, sel, nullptr, nullptr);
  scan_kernel<8192, 1><<<1, 256, 0, stream>>>(hist2, sel);
  sim_kernel<2><<<NTRI / 4, 256, 0, stream>>>(xnF, nullptr, sel, Awords, AT);
  deg_kernel<<<2048, 256, 0, stream>>>(Awords, deg_inv);

  // h0 = relu(x @ w_in + b_in)
  lin_kernel<false, true, false><<<dim3(128, 4), 256, 0, stream>>>(
      xb, w_inT, 128, nullptr, nullptr, 0, b_in, nullptr, h0);
  // h1 = relu(agg(h0)@h1_wl + h1_bl + h0@h1_wr)
  packB_kernel<<<dim3(128, 4), 256, 0, stream>>>(h0, hF);
  aggA_kernel<<<dim3(64, nsplit), 256, 0, stream>>>(AT, hF, partials, ksplit);
  combine_kernel<<<1024, 256, 0, stream>>>(partials, nsplit, deg_inv, agg);
  lin_kernel<true, true, false><<<dim3(128, 4), 256, 0, stream>>>(
      agg, w1lT, 256, h0, w1rT, 256, h1_bl, nullptr, h1);
  // h2 = relu(agg(h1)@h2_wl + h2_bl + h1@h2_wr + h0)
  packB_kernel<<<dim3(128, 4), 256, 0, stream>>>(h1, hF);
  aggA_kernel<<<dim3(64, nsplit), 256, 0, stream>>>(AT, hF, partials, ksplit);
  combine_kernel<<<1024, 256, 0, stream>>>(partials, nsplit, deg_inv, agg);
  lin_kernel<true, true, true><<<dim3(128, 4), 256, 0, stream>>>(
      agg, w2lT, 256, h1, w2rT, 256, h2_bl, h0, h2);
  // output block
  vec3_kernel<<<2048, 256, 0, stream>>>(h2, o1_wl, o1_wr, osc_w, osc_b, ubuf, vbuf, scbuf);
  aggv1_kernel<<<2048, 256, 0, stream>>>(Awords, ubuf, deg_inv, vbuf, o1_bl, o1buf);
  aggv2_kernel<<<2048, 256, 0, stream>>>(Awords, o1buf, deg_inv, o2_wl, o2_bl, o2_wr, scbuf, out);
}

// Round 9
// 324.527 us; speedup vs baseline: 1.6062x; 1.0169x over previous
//
#include <hip/hip_runtime.h>

// GNN_79937931313503: dynamic-graph SAGE GNN on MI355X.
// R9: aggA software-pipelined — A bit-words prefetched one iter ahead,
// B-fragment loads issued under A-expansion VALU and prior-kc MFMAs.

typedef __attribute__((ext_vector_type(8))) short s8v;   // 8 x bf16 (4 VGPR)
typedef __attribute__((ext_vector_type(4))) short s4v;   // 4 x bf16
typedef __attribute__((ext_vector_type(4))) float f4v;   // MFMA C/D frag

__device__ __forceinline__ f4v MFMA(s8v a, s8v b, f4v c) {
  return __builtin_amdgcn_mfma_f32_16x16x32_bf16(a, b, c, 0, 0, 0);
}
__device__ __forceinline__ short f2bf(float f) {  // RNE float->bf16 bits
  unsigned u = __float_as_uint(f);
  return (short)((u + 0x7FFFu + ((u >> 16) & 1u)) >> 16);
}
__device__ __forceinline__ float bf2f(short s) {
  return __uint_as_float(((unsigned)(unsigned short)s) << 16);
}

#define NT64 128
#define NTRI 8256  // 128*129/2
#define NHC 8      // global histogram copies

__device__ __forceinline__ void tri_invert(int t, int& r, int& c) {
  int rr = (int)((257.0f - sqrtf((float)(257 * 257 - 8 * t))) * 0.5f);
  if (rr < 0) rr = 0;
  if (rr > 127) rr = 127;
  while (rr < 127 && ((rr + 1) * NT64 - (rr + 1) * rr / 2) <= t) ++rr;
  while (rr > 0 && (rr * NT64 - rr * (rr - 1) / 2) > t) --rr;
  r = rr;
  c = rr + (t - (rr * NT64 - rr * (rr - 1) / 2));
}

// ---------------- prep_x: norms + xb (row-major) + xnF (fragment-major) ----
__global__ __launch_bounds__(256) void prep_x_kernel(const float* __restrict__ x,
                                                     short* __restrict__ xb,
                                                     short* __restrict__ xnF) {
  const int w = threadIdx.x >> 6, lane = threadIdx.x & 63;
  const int rg = blockIdx.x * 4 + w;
  const int m = lane & 15, g = lane >> 4;
  const int row = rg * 16 + m;
  float v[4][8];
  float ss = 0.f;
#pragma unroll
  for (int kc = 0; kc < 4; ++kc) {
    const float* src = x + row * 128 + kc * 32 + g * 8;
    float4 a = *(const float4*)src;
    float4 b = *(const float4*)(src + 4);
    v[kc][0] = a.x; v[kc][1] = a.y; v[kc][2] = a.z; v[kc][3] = a.w;
    v[kc][4] = b.x; v[kc][5] = b.y; v[kc][6] = b.z; v[kc][7] = b.w;
#pragma unroll
    for (int e = 0; e < 8; ++e) ss += v[kc][e] * v[kc][e];
  }
  ss += __shfl_xor(ss, 16);
  ss += __shfl_xor(ss, 32);
  float inv = 1.0f / fmaxf(sqrtf(ss), 1e-8f);
#pragma unroll
  for (int kc = 0; kc < 4; ++kc) {
    s8v raw, nrm;
#pragma unroll
    for (int e = 0; e < 8; ++e) {
      raw[e] = f2bf(v[kc][e]);
      nrm[e] = f2bf(v[kc][e] * inv);
    }
    *(s8v*)(xb + row * 128 + kc * 32 + g * 8) = raw;
    *(s8v*)(xnF + (rg * 4 + kc) * 512 + lane * 8) = nrm;  // coalesced 1KB
  }
}

__global__ __launch_bounds__(256) void prep_w_kernel(
    const float* __restrict__ w_in, const float* __restrict__ w1l,
    const float* __restrict__ w1r, const float* __restrict__ w2l,
    const float* __restrict__ w2r, short* __restrict__ w_inT,
    short* __restrict__ w1lT, short* __restrict__ w1rT,
    short* __restrict__ w2lT, short* __restrict__ w2rT) {
  int idx = blockIdx.x * 256 + threadIdx.x;
  if (idx >= 294912) return;
  if (idx < 32768) {                       // w_in [128][256] -> [256][128]
    int n = idx >> 7, k = idx & 127;
    w_inT[idx] = f2bf(w_in[k * 256 + n]);
  } else {                                 // 4x [256][256] transposed
    int j = idx - 32768;
    int m = j >> 16, r = j & 65535;
    int n = r >> 8, k = r & 255;
    const float* src = (m == 0) ? w1l : (m == 1) ? w1r : (m == 2) ? w2l : w2r;
    short* dst = (m == 0) ? w1lT : (m == 1) ? w1rT : (m == 2) ? w2lT : w2rT;
    dst[r] = f2bf(src[k * 256 + n]);
  }
}

// ---------------- hist0: persistent grid-stride linear histogram ----------
__global__ __launch_bounds__(256) void hist0_kernel(const short* __restrict__ xnF,
                                                    unsigned int* __restrict__ hist) {
  __shared__ unsigned int lh[4096];
  const int tid = threadIdx.x, w = tid >> 6, lane = tid & 63;
  for (int b = tid; b < 4096; b += 256) lh[b] = 0;
  __syncthreads();

  for (int tg = blockIdx.x; tg < NTRI / 4; tg += gridDim.x) {
    int t = tg * 4 + w;
    int r, c;
    tri_invert(t, r, c);
    const bool diag = (r == c);
    f4v acc[4][4];
#pragma unroll
    for (int a = 0; a < 4; ++a)
#pragma unroll
      for (int b = 0; b < 4; ++b) acc[a][b] = (f4v){0.f, 0.f, 0.f, 0.f};
    const int rga = r * 4, rgb = c * 4;
#pragma unroll
    for (int kc = 0; kc < 4; ++kc) {
      s8v af[4], bf[4];
#pragma unroll
      for (int mt = 0; mt < 4; ++mt)
        af[mt] = *(const s8v*)(xnF + ((rga + mt) * 4 + kc) * 512 + lane * 8);
#pragma unroll
      for (int nt = 0; nt < 4; ++nt)
        bf[nt] = *(const s8v*)(xnF + ((rgb + nt) * 4 + kc) * 512 + lane * 8);
#pragma unroll
      for (int mt = 0; mt < 4; ++mt)
#pragma unroll
        for (int nt = 0; nt < 4; ++nt) acc[mt][nt] = MFMA(af[mt], bf[nt], acc[mt][nt]);
    }
    unsigned wgt = diag ? 1u : 2u;
#pragma unroll
    for (int mt = 0; mt < 4; ++mt)
      for (int nt = 0; nt < 4; ++nt)
        for (int rr = 0; rr < 4; ++rr) {
          float val = fabsf(acc[mt][nt][rr]);
          int bin = (int)(val * 4096.0f);
          bin = min(max(bin, 0), 4095);
          atomicAdd(&lh[bin], wgt);
        }
  }
  __syncthreads();
  unsigned int* hc = hist + (blockIdx.x & (NHC - 1)) * 4096;
  for (int b = tid; b < 4096; b += 256)
    if (lh[b]) atomicAdd(&hc[b], lh[b]);
}

// ---------------- sim: per-wave 64x64 tiles, upper triangle only ----------------
template <int MODE>
__global__ __launch_bounds__(256) void sim_kernel(
    const short* __restrict__ xnF, unsigned int* __restrict__ hist,
    unsigned int* __restrict__ sel, unsigned long long* __restrict__ Awords,
    unsigned long long* __restrict__ AT) {
  const int tid = threadIdx.x, w = tid >> 6, lane = tid & 63;
  int t = blockIdx.x * 4 + w;
  int r, c;
  tri_invert(t, r, c);
  const int i0 = r * 64, j0 = c * 64;
  const bool diag = (r == c);

  f4v acc[4][4];
#pragma unroll
  for (int a = 0; a < 4; ++a)
#pragma unroll
    for (int b = 0; b < 4; ++b) acc[a][b] = (f4v){0.f, 0.f, 0.f, 0.f};

  const int rga = r * 4, rgb = c * 4;
#pragma unroll
  for (int kc = 0; kc < 4; ++kc) {
    s8v af[4], bf[4];
#pragma unroll
    for (int mt = 0; mt < 4; ++mt)
      af[mt] = *(const s8v*)(xnF + ((rga + mt) * 4 + kc) * 512 + lane * 8);
#pragma unroll
    for (int nt = 0; nt < 4; ++nt)
      bf[nt] = *(const s8v*)(xnF + ((rgb + nt) * 4 + kc) * 512 + lane * 8);
#pragma unroll
    for (int mt = 0; mt < 4; ++mt)
#pragma unroll
      for (int nt = 0; nt < 4; ++nt) acc[mt][nt] = MFMA(af[mt], bf[nt], acc[mt][nt]);
  }

  if (MODE == 1) {
    int pref = (int)sel[0];
    unsigned wgt = diag ? 1u : 2u;
#pragma unroll
    for (int mt = 0; mt < 4; ++mt)
      for (int nt = 0; nt < 4; ++nt)
        for (int rr = 0; rr < 4; ++rr) {
          float tt = fabsf(acc[mt][nt][rr]) * 4096.0f;
          int bin = min(max((int)tt, 0), 4095);
          if (bin == pref) {
            int b2 = (int)((tt - (float)pref) * 8192.0f);
            b2 = min(max(b2, 0), 8191);
            atomicAdd(&hist[b2], wgt);
          }
        }
  } else {
    float eps = __uint_as_float(sel[2]);
    unsigned long long myword = 0;  // lane j holds row (i0+j)'s bits [j0..j0+64)
#pragma unroll
    for (int mt = 0; mt < 4; ++mt)
#pragma unroll
      for (int rr = 0; rr < 4; ++rr) {
        unsigned long long b0 = __ballot(fabsf(acc[mt][0][rr]) >= eps);
        unsigned long long b1 = __ballot(fabsf(acc[mt][1][rr]) >= eps);
        unsigned long long b2 = __ballot(fabsf(acc[mt][2][rr]) >= eps);
        unsigned long long b3 = __ballot(fabsf(acc[mt][3][rr]) >= eps);
        if ((lane >> 4) == mt && (lane & 3) == rr) {
          int gj = (lane >> 2) & 3;
          myword = ((b0 >> (16 * gj)) & 0xFFFFull) |
                   (((b1 >> (16 * gj)) & 0xFFFFull) << 16) |
                   (((b2 >> (16 * gj)) & 0xFFFFull) << 32) |
                   (((b3 >> (16 * gj)) & 0xFFFFull) << 48);
        }
      }
    Awords[(size_t)(i0 + lane) * 128 + (j0 >> 6)] = myword;
    AT[(size_t)(j0 >> 6) * 8192 + i0 + lane] = myword;
    if (!diag) {  // mirrored tile via 64x64 bit transpose (ballot per column)
      unsigned long long tw = 0;
#pragma unroll
      for (int c2 = 0; c2 < 64; ++c2) {
        unsigned long long bc = __ballot((myword >> c2) & 1ull);
        if (lane == c2) tw = bc;
      }
      Awords[(size_t)(j0 + lane) * 128 + (i0 >> 6)] = tw;
      AT[(size_t)(i0 >> 6) * 8192 + j0 + lane] = tw;
    }
  }
}

// ---------------- histogram selection scan ----------------
template <int NB, int MODE>
__global__ __launch_bounds__(256) void scan_kernel(const unsigned int* __restrict__ hist,
                                                   unsigned int* __restrict__ sel) {
  __shared__ unsigned long long csum[256];
  const int t = threadIdx.x;
  const int PER = NB / 256;
  unsigned int vals[NB / 256];
  unsigned long long s = 0;
  for (int i = 0; i < PER; ++i) {
    unsigned v = 0;
    if (MODE == 0) {
      for (int cc = 0; cc < NHC; ++cc) v += hist[cc * NB + t * PER + i];
    } else {
      v = hist[t * PER + i];
    }
    vals[i] = v;
    s += v;
  }
  csum[t] = s;
  __syncthreads();
  for (int o = 1; o < 256; o <<= 1) {
    unsigned long long prev = (t >= o) ? csum[t - o] : 0ull;
    __syncthreads();
    csum[t] += prev;
    __syncthreads();
  }
  unsigned long long K = (MODE == 0) ? 63753421ull : (unsigned long long)sel[1];
  unsigned long long inc = csum[t], exc = inc - s;
  if (K > exc && K <= inc) {
    unsigned long long c = exc;
    for (int i = 0; i < PER; ++i) {
      c += vals[i];
      if (c >= K) {
        if (MODE == 0) {
          sel[0] = (unsigned)(t * PER + i);
          sel[1] = (unsigned)(K - (c - vals[i]));
        } else {
          float eps = ((float)sel[0] + (float)(t * PER + i) * (1.0f / 8192.0f)) *
                      (1.0f / 4096.0f);
          sel[2] = __float_as_uint(eps);
        }
        break;
      }
    }
  }
}

// ---------------- degree ----------------
__global__ __launch_bounds__(256) void deg_kernel(const unsigned long long* __restrict__ Awords,
                                                  float* __restrict__ deg_inv) {
  int row = blockIdx.x * 4 + (threadIdx.x >> 6);
  int lane = threadIdx.x & 63;
  int c = __popcll(Awords[row * 128 + lane]) + __popcll(Awords[row * 128 + 64 + lane]);
  for (int o = 32; o; o >>= 1) c += __shfl_down(c, o);
  if (lane == 0) deg_inv[row] = 1.0f / (float)max(c, 1);
}

// ---------------- small NT linears ----------------
template <bool TWO, bool RELU, bool RES>
__global__ __launch_bounds__(256) void lin_kernel(
    const short* __restrict__ A1, const short* __restrict__ B1, int K1,
    const short* __restrict__ A2, const short* __restrict__ B2, int K2,
    const float* __restrict__ bias, const short* __restrict__ res,
    short* __restrict__ out) {
  const int i0 = blockIdx.x * 64, n0 = blockIdx.y * 64;
  const int tid = threadIdx.x, w = tid >> 6, lane = tid & 63;
  const int wy = (w >> 1) * 32, wx = (w & 1) * 32;
  const int lr = lane & 15, lk = (lane >> 4) * 8;
  f4v acc[2][2];
#pragma unroll
  for (int a = 0; a < 2; ++a)
#pragma unroll
    for (int b = 0; b < 2; ++b) acc[a][b] = (f4v){0.f, 0.f, 0.f, 0.f};

  for (int kc = 0; kc < K1; kc += 32) {
    s8v a0 = *(const s8v*)(A1 + (i0 + wy + lr) * K1 + kc + lk);
    s8v a1 = *(const s8v*)(A1 + (i0 + wy + 16 + lr) * K1 + kc + lk);
    s8v b0 = *(const s8v*)(B1 + (n0 + wx + lr) * K1 + kc + lk);
    s8v b1 = *(const s8v*)(B1 + (n0 + wx + 16 + lr) * K1 + kc + lk);
    acc[0][0] = MFMA(a0, b0, acc[0][0]);
    acc[0][1] = MFMA(a0, b1, acc[0][1]);
    acc[1][0] = MFMA(a1, b0, acc[1][0]);
    acc[1][1] = MFMA(a1, b1, acc[1][1]);
  }
  if constexpr (TWO) {
    for (int kc = 0; kc < K2; kc += 32) {
      s8v a0 = *(const s8v*)(A2 + (i0 + wy + lr) * K2 + kc + lk);
      s8v a1 = *(const s8v*)(A2 + (i0 + wy + 16 + lr) * K2 + kc + lk);
      s8v b0 = *(const s8v*)(B2 + (n0 + wx + lr) * K2 + kc + lk);
      s8v b1 = *(const s8v*)(B2 + (n0 + wx + 16 + lr) * K2 + kc + lk);
      acc[0][0] = MFMA(a0, b0, acc[0][0]);
      acc[0][1] = MFMA(a0, b1, acc[0][1]);
      acc[1][0] = MFMA(a1, b0, acc[1][0]);
      acc[1][1] = MFMA(a1, b1, acc[1][1]);
    }
  }
#pragma unroll
  for (int mt = 0; mt < 2; ++mt)
#pragma unroll
    for (int nt = 0; nt < 2; ++nt)
#pragma unroll
      for (int rr = 0; rr < 4; ++rr) {
        int row = i0 + wy + mt * 16 + (lane >> 4) * 4 + rr;
        int col = n0 + wx + nt * 16 + (lane & 15);
        float v = acc[mt][nt][rr] + bias[col];
        if constexpr (RES) v += bf2f(res[row * 256 + col]);
        if constexpr (RELU) v = fmaxf(v, 0.f);
        out[row * 256 + col] = f2bf(v);
      }
}

// ---------------- packB: h [8192][256] -> hF fragment-major ----------------
__global__ __launch_bounds__(256) void packB_kernel(const short* __restrict__ in,
                                                    short* __restrict__ hF) {
  __shared__ __align__(16) short T[64][80];
  const int i0 = blockIdx.x * 64, f0 = blockIdx.y * 64;
  const int t = threadIdx.x;
  const int r = t >> 2, c0 = (t & 3) * 16;
  s8v v0 = *(const s8v*)(in + (i0 + r) * 256 + f0 + c0);
  s8v v1 = *(const s8v*)(in + (i0 + r) * 256 + f0 + c0 + 8);
#pragma unroll
  for (int e = 0; e < 8; ++e) {
    T[c0 + e][r] = v0[e];       // T[feat][node]
    T[c0 + 8 + e][r] = v1[e];
  }
  __syncthreads();
  const int w = t >> 6, lane = t & 63;
  const int c = lane & 15, g = lane >> 4;
#pragma unroll
  for (int kc2 = 0; kc2 < 2; ++kc2) {
    s8v o = *(const s8v*)&T[w * 16 + c][kc2 * 32 + g * 8];
    size_t chunk = (size_t)((f0 >> 4) + w) * 256 + (i0 >> 5) + kc2;
    *(s8v*)(hF + chunk * 512 + lane * 8) = o;
  }
}

// ---------------- aggA: partial[z] = A[:, kslice] @ h[kslice, :] ------------
// Software-pipelined: awn prefetched one iter ahead; bf(kc1) loads issued
// under kc0 MFMAs; A expansion VALU covers bf(kc0) latency.
__global__ __launch_bounds__(256, 2) void aggA_kernel(
    const unsigned long long* __restrict__ AT, const short* __restrict__ hF,
    short* __restrict__ partial, int ksplit) {
  const int i0 = blockIdx.x * 128;            // node rows
  const int k0 = blockIdx.y * ksplit;         // k split
  const int tid = threadIdx.x, w = tid >> 6, lane = tid & 63;
  const int wy = (w >> 1) * 64;               // row offset within block
  const int wx = (w & 1) * 128;               // feat offset within block
  const int lr = lane & 15, g = lane >> 4;
  const int g8 = g * 8;
  const short one = (short)0x3F80;

  f4v acc[4][8];
#pragma unroll
  for (int a = 0; a < 4; ++a)
#pragma unroll
    for (int b = 0; b < 8; ++b) acc[a][b] = (f4v){0.f, 0.f, 0.f, 0.f};

  unsigned long long aw[4];
#pragma unroll
  for (int mt = 0; mt < 4; ++mt)
    aw[mt] = AT[(size_t)(k0 >> 6) * 8192 + i0 + wy + mt * 16 + lr];

  for (int kb = k0; kb < k0 + ksplit; kb += 64) {
    // prefetch next iter's A bit-words (tail read is harmless in-ws garbage)
    unsigned long long awn[4];
#pragma unroll
    for (int mt = 0; mt < 4; ++mt)
      awn[mt] = AT[(size_t)((kb + 64) >> 6) * 8192 + i0 + wy + mt * 16 + lr];
    // kc0 B loads
    s8v bf0[8];
#pragma unroll
    for (int nt = 0; nt < 8; ++nt) {
      size_t chunk = (size_t)((wx >> 4) + nt) * 256 + (kb >> 5);
      bf0[nt] = *(const s8v*)(hF + chunk * 512 + lane * 8);
    }
    // expand kc0 A frags (VALU covers bf0 latency)
    s8v a0[4];
#pragma unroll
    for (int mt = 0; mt < 4; ++mt) {
      unsigned byte = ((unsigned)aw[mt] >> g8) & 0xFFu;
#pragma unroll
      for (int e = 0; e < 8; ++e) a0[mt][e] = ((byte >> e) & 1u) ? one : (short)0;
    }
    // kc1 B loads (in flight under kc0 MFMAs)
    s8v bf1[8];
#pragma unroll
    for (int nt = 0; nt < 8; ++nt) {
      size_t chunk = (size_t)((wx >> 4) + nt) * 256 + (kb >> 5) + 1;
      bf1[nt] = *(const s8v*)(hF + chunk * 512 + lane * 8);
    }
    // kc0 MFMAs
#pragma unroll
    for (int mt = 0; mt < 4; ++mt)
#pragma unroll
      for (int nt = 0; nt < 8; ++nt) acc[mt][nt] = MFMA(a0[mt], bf0[nt], acc[mt][nt]);
    // expand kc1 (reuse a0 storage) + MFMAs
#pragma unroll
    for (int mt = 0; mt < 4; ++mt) {
      unsigned byte = ((unsigned)(aw[mt] >> 32) >> g8) & 0xFFu;
#pragma unroll
      for (int e = 0; e < 8; ++e) a0[mt][e] = ((byte >> e) & 1u) ? one : (short)0;
#pragma unroll
      for (int nt = 0; nt < 8; ++nt) acc[mt][nt] = MFMA(a0[mt], bf1[nt], acc[mt][nt]);
    }
#pragma unroll
    for (int mt = 0; mt < 4; ++mt) aw[mt] = awn[mt];
  }
  short* P = partial + (size_t)blockIdx.y * (8192 * 256);
#pragma unroll
  for (int mt = 0; mt < 4; ++mt)
#pragma unroll
    for (int nt = 0; nt < 8; ++nt)
#pragma unroll
      for (int rr = 0; rr < 4; ++rr) {
        int row = i0 + wy + mt * 16 + g * 4 + rr;
        int col = wx + nt * 16 + lr;
        P[(size_t)row * 256 + col] = f2bf(acc[mt][nt][rr]);
      }
}

// combine: agg = bf16((sum_z partial[z]) * deg_inv[row]); 8 elems/thread
__global__ __launch_bounds__(256) void combine_kernel(const short* __restrict__ p, int nsplit,
                                                      const float* __restrict__ deg_inv,
                                                      short* __restrict__ agg) {
  int idx8 = blockIdx.x * 256 + threadIdx.x;  // group of 8 elems
  float s[8];
#pragma unroll
  for (int e = 0; e < 8; ++e) s[e] = 0.f;
  for (int k = 0; k < nsplit; ++k) {
    s8v v = *(const s8v*)(p + (size_t)k * 2097152 + (size_t)idx8 * 8);
#pragma unroll
    for (int e = 0; e < 8; ++e) s[e] += bf2f(v[e]);
  }
  float di = deg_inv[idx8 >> 5];
  s8v o;
#pragma unroll
  for (int e = 0; e < 8; ++e) o[e] = f2bf(s[e] * di);
  *(s8v*)(agg + (size_t)idx8 * 8) = o;
}

// ---------------- tail ----------------
__global__ __launch_bounds__(256) void vec3_kernel(const short* __restrict__ h2,
                                                   const float* __restrict__ o1wl,
                                                   const float* __restrict__ o1wr,
                                                   const float* __restrict__ oscw,
                                                   const float* __restrict__ oscb,
                                                   float* __restrict__ u, float* __restrict__ v,
                                                   float* __restrict__ sc) {
  int row = blockIdx.x * 4 + (threadIdx.x >> 6);
  int lane = threadIdx.x & 63;
  float su = 0.f, sv = 0.f, ss = 0.f;
#pragma unroll
  for (int e = 0; e < 4; ++e) {
    int k = lane * 4 + e;
    float hv = bf2f(h2[row * 256 + k]);
    su += hv * o1wl[k];
    sv += hv * o1wr[k];
    ss += hv * oscw[k];
  }
  for (int o = 1; o < 64; o <<= 1) {
    su += __shfl_xor(su, o);
    sv += __shfl_xor(sv, o);
    ss += __shfl_xor(ss, o);
  }
  if (lane == 0) {
    u[row] = su;
    v[row] = sv;
    sc[row] = ss + oscb[0];
  }
}

__global__ __launch_bounds__(256) void aggv1_kernel(const unsigned long long* __restrict__ Awords,
                                                    const float* __restrict__ u,
                                                    const float* __restrict__ deg_inv,
                                                    const float* __restrict__ v,
                                                    const float* __restrict__ o1bl,
                                                    float* __restrict__ o1) {
  int row = blockIdx.x * 4 + (threadIdx.x >> 6);
  int lane = threadIdx.x & 63;
  float s = 0.f;
#pragma unroll
  for (int wi = 0; wi < 2; ++wi) {
    unsigned long long bits = Awords[row * 128 + wi * 64 + lane];
    int base = (wi * 64 + lane) * 64;
    while (bits) {
      int b = __ffsll(bits) - 1;
      s += u[base + b];
      bits &= bits - 1;
    }
  }
  for (int o = 1; o < 64; o <<= 1) s += __shfl_xor(s, o);
  if (lane == 0) o1[row] = fmaxf(s * deg_inv[row] + o1bl[0] + v[row], 0.f);
}

__global__ __launch_bounds__(256) void aggv2_kernel(const unsigned long long* __restrict__ Awords,
                                                    const float* __restrict__ o1,
                                                    const float* __restrict__ deg_inv,
                                                    const float* __restrict__ o2wl,
                                                    const float* __restrict__ o2bl,
                                                    const float* __restrict__ o2wr,
                                                    const float* __restrict__ sc,
                                                    float* __restrict__ out) {
  int row = blockIdx.x * 4 + (threadIdx.x >> 6);
  int lane = threadIdx.x & 63;
  float s = 0.f;
#pragma unroll
  for (int wi = 0; wi < 2; ++wi) {
    unsigned long long bits = Awords[row * 128 + wi * 64 + lane];
    int base = (wi * 64 + lane) * 64;
    while (bits) {
      int b = __ffsll(bits) - 1;
      s += o1[base + b];
      bits &= bits - 1;
    }
  }
  for (int o = 1; o < 64; o <<= 1) s += __shfl_xor(s, o);
  if (lane == 0) {
    float z = s * deg_inv[row] * o2wl[0] + o2bl[0] + o1[row] * o2wr[0] + sc[row];
    out[row] = 1.f / (1.f + expf(-z));
  }
}

// ---------------- launch ----------------
extern "C" void kernel_launch(void* const* d_in, const int* in_sizes, int n_in,
                              void* d_out, int out_size, void* d_ws, size_t ws_size,
                              hipStream_t stream) {
  (void)in_sizes; (void)n_in; (void)out_size;
  const float* x     = (const float*)d_in[0];
  const float* w_in  = (const float*)d_in[1];
  const float* b_in  = (const float*)d_in[2];
  const float* h1_wl = (const float*)d_in[3];
  const float* h1_bl = (const float*)d_in[4];
  const float* h1_wr = (const float*)d_in[5];
  const float* h2_wl = (const float*)d_in[6];
  const float* h2_bl = (const float*)d_in[7];
  const float* h2_wr = (const float*)d_in[8];
  const float* o1_wl = (const float*)d_in[9];
  const float* o1_bl = (const float*)d_in[10];
  const float* o1_wr = (const float*)d_in[11];
  const float* o2_wl = (const float*)d_in[12];
  const float* o2_bl = (const float*)d_in[13];
  const float* o2_wr = (const float*)d_in[14];
  const float* osc_w = (const float*)d_in[15];
  const float* osc_b = (const float*)d_in[16];
  float* out = (float*)d_out;

  char* ws = (char*)d_ws;
  size_t off = 0;
  auto alloc = [&](size_t bytes) -> char* {
    char* p = ws + off;
    off += (bytes + 255) & ~(size_t)255;
    return p;
  };
  short* xnF   = (short*)alloc(8192 * 128 * 2);  // fragment-major normalized x
  short* xb    = (short*)alloc(8192 * 128 * 2);
  short* w_inT = (short*)alloc(256 * 128 * 2);
  short* w1lT  = (short*)alloc(256 * 256 * 2);
  short* w1rT  = (short*)alloc(256 * 256 * 2);
  short* w2lT  = (short*)alloc(256 * 256 * 2);
  short* w2rT  = (short*)alloc(256 * 256 * 2);
  unsigned int* hist1 = (unsigned int*)alloc(NHC * 4096 * 4);
  unsigned int* hist2 = (unsigned int*)alloc(8192 * 4);
  unsigned int* sel   = (unsigned int*)alloc(256);
  float* deg_inv = (float*)alloc(8192 * 4);
  float* ubuf  = (float*)alloc(8192 * 4);
  float* vbuf  = (float*)alloc(8192 * 4);
  float* scbuf = (float*)alloc(8192 * 4);
  float* o1buf = (float*)alloc(8192 * 4);
  unsigned long long* Awords = (unsigned long long*)alloc((size_t)8192 * 128 * 8);
  unsigned long long* AT     = (unsigned long long*)alloc((size_t)8192 * 128 * 8);
  short* h0  = (short*)alloc((size_t)8192 * 256 * 2);
  short* h1  = (short*)alloc((size_t)8192 * 256 * 2);
  short* h2  = (short*)alloc((size_t)8192 * 256 * 2);
  short* hF  = (short*)alloc((size_t)8192 * 256 * 2);
  short* agg = (short*)alloc((size_t)8192 * 256 * 2);
  // split-K: prefer 8 (512 blocks, 2/CU); bf16 partial slices of 4 MB
  const size_t SLICE = (size_t)8192 * 256 * 2;
  int nsplit = (ws_size >= off + 8 * SLICE + 4096) ? 8
             : (ws_size >= off + 4 * SLICE + 4096) ? 4 : 2;
  short* partials = (short*)alloc((size_t)nsplit * SLICE);
  const int ksplit = 8192 / nsplit;

  hipMemsetAsync(hist1, 0, (NHC * 4096 + 8192) * 4, stream);
  prep_x_kernel<<<128, 256, 0, stream>>>(x, xb, xnF);
  prep_w_kernel<<<1152, 256, 0, stream>>>(w_in, h1_wl, h1_wr, h2_wl, h2_wr,
                                          w_inT, w1lT, w1rT, w2lT, w2rT);
  hist0_kernel<<<512, 256, 0, stream>>>(xnF, hist1);
  scan_kernel<4096, 0><<<1, 256, 0, stream>>>(hist1, sel);
  sim_kernel<1><<<NTRI / 4, 256, 0, stream>>>(xnF, hist2, sel, nullptr, nullptr);
  scan_kernel<8192, 1><<<1, 256, 0, stream>>>(hist2, sel);
  sim_kernel<2><<<NTRI / 4, 256, 0, stream>>>(xnF, nullptr, sel, Awords, AT);
  deg_kernel<<<2048, 256, 0, stream>>>(Awords, deg_inv);

  // h0 = relu(x @ w_in + b_in)
  lin_kernel<false, true, false><<<dim3(128, 4), 256, 0, stream>>>(
      xb, w_inT, 128, nullptr, nullptr, 0, b_in, nullptr, h0);
  // h1 = relu(agg(h0)@h1_wl + h1_bl + h0@h1_wr)
  packB_kernel<<<dim3(128, 4), 256, 0, stream>>>(h0, hF);
  aggA_kernel<<<dim3(64, nsplit), 256, 0, stream>>>(AT, hF, partials, ksplit);
  combine_kernel<<<1024, 256, 0, stream>>>(partials, nsplit, deg_inv, agg);
  lin_kernel<true, true, false><<<dim3(128, 4), 256, 0, stream>>>(
      agg, w1lT, 256, h0, w1rT, 256, h1_bl, nullptr, h1);
  // h2 = relu(agg(h1)@h2_wl + h2_bl + h1@h2_wr + h0)
  packB_kernel<<<dim3(128, 4), 256, 0, stream>>>(h1, hF);
  aggA_kernel<<<dim3(64, nsplit), 256, 0, stream>>>(AT, hF, partials, ksplit);
  combine_kernel<<<1024, 256, 0, stream>>>(partials, nsplit, deg_inv, agg);
  lin_kernel<true, true, true><<<dim3(128, 4), 256, 0, stream>>>(
      agg, w2lT, 256, h1, w2rT, 256, h2_bl, h0, h2);
  // output block
  vec3_kernel<<<2048, 256, 0, stream>>>(h2, o1_wl, o1_wr, osc_w, osc_b, ubuf, vbuf, scbuf);
  aggv1_kernel<<<2048, 256, 0, stream>>>(Awords, ubuf, deg_inv, vbuf, o1_bl, o1buf);
  aggv2_kernel<<<2048, 256, 0, stream>>>(Awords, o1buf, deg_inv, o2_wl, o2_bl, o2_wr, scbuf, out);
}